// Round 12
// baseline (322.887 us; speedup 1.0000x reference)
//
#include <hip/hip_runtime.h>
#include <hip/hip_bf16.h>
#include <cstdint>

// Problem constants
#define PB 4
#define PS 2048
#define PE 1024
#define PH 16
#define PD 64
#define PM (PB * PS)      // 8192 rows

typedef __attribute__((ext_vector_type(8))) _Float16 half8;  // 8 fp16 (4 VGPR)
typedef __attribute__((ext_vector_type(4))) float f32x4;

#define MFMAH __builtin_amdgcn_mfma_f32_16x16x32_f16

#define GLOAD_LDS(gp, lp) __builtin_amdgcn_global_load_lds(                    \
    (const __attribute__((address_space(1))) void*)(gp),                       \
    (__attribute__((address_space(3))) void*)(lp), 16, 0, 0)

// fp32 -> fp16 RNE bit pattern
__device__ inline unsigned short h16(float x) {
    _Float16 h = (_Float16)x;
    unsigned short u;
    __builtin_memcpy(&u, &h, 2);
    return u;
}
// fp16 hi/lo split (exact: x-hi is Sterbenz-exact in fp32)
__device__ inline void splith(float x, unsigned short& h, unsigned short& l) {
    _Float16 hh = (_Float16)x;
    _Float16 ll = (_Float16)(x - (float)hh);
    __builtin_memcpy(&h, &hh, 2);
    __builtin_memcpy(&l, &ll, 2);
}

// ---------------------------------------------------------------------------
// split_all: query -> fp16 hi/lo planes; weights -> single fp16 plane.
// f4 ranges: query 2097152 | Wq/Wk/Wv/Wo 262144 each | Wm1/Wm2 65536 each.
// ---------------------------------------------------------------------------
__global__ __launch_bounds__(256)
void split_all(const float* __restrict__ q,   const float* __restrict__ wq,
               const float* __restrict__ wk,  const float* __restrict__ wv,
               const float* __restrict__ wo,  const float* __restrict__ wm1,
               const float* __restrict__ wm2,
               unsigned short* qhi,  unsigned short* qlo,
               unsigned short* wqh, unsigned short* wkh,
               unsigned short* wvh, unsigned short* woh,
               unsigned short* m1h, unsigned short* m2h)
{
    const int b = blockIdx.x;
    if (b < 8192) {          // query: hi/lo
        const int i = b * 256 + threadIdx.x;
        float4 f = ((const float4*)q)[i];
        ushort4 h, l;
        splith(f.x, h.x, l.x); splith(f.y, h.y, l.y);
        splith(f.z, h.z, l.z); splith(f.w, h.w, l.w);
        ((ushort4*)qhi)[i] = h;
        ((ushort4*)qlo)[i] = l;
        return;
    }
    const float* src; unsigned short* dst; int base;
    if      (b <  9216) { src = wq;  dst = wqh; base = 8192;  }
    else if (b < 10240) { src = wk;  dst = wkh; base = 9216;  }
    else if (b < 11264) { src = wv;  dst = wvh; base = 10240; }
    else if (b < 12288) { src = wo;  dst = woh; base = 11264; }
    else if (b < 12544) { src = wm1; dst = m1h; base = 12288; }
    else                { src = wm2; dst = m2h; base = 12544; }
    const int i = (b - base) * 256 + threadIdx.x;
    float4 f = ((const float4*)src)[i];
    ushort4 h;
    h.x = h16(f.x); h.y = h16(f.y); h.z = h16(f.z); h.w = h16(f.w);
    ((ushort4*)dst)[i] = h;
}

// ---------------------------------------------------------------------------
// Plane-fed 2-term fp16 MFMA NT GEMM (round-11 proven engine, unchanged).
// ---------------------------------------------------------------------------
template<int MODE, bool RELU>
__global__ __launch_bounds__(256, 2)
void gemm_pl(const unsigned short* __restrict__ Ahi,
             const unsigned short* __restrict__ Alo,
             const unsigned short* __restrict__ Bh,
             const float* __restrict__ bias, float* __restrict__ C,
             unsigned short* __restrict__ Ohi, unsigned short* __restrict__ Olo,
             int M, int N, int K,
             const float* __restrict__ attn,
             const float* __restrict__ g0, const float* __restrict__ g1,
             const float* __restrict__ g2, const float* __restrict__ g3,
             const float* __restrict__ asc, const float* __restrict__ abi)
{
    __shared__ int4 ldsq[3072];                 // 48 KB = 3 planes x 16 KB
    char* const lds = (char*)ldsq;

    const int tid  = threadIdx.x;
    const int lane = tid & 63;
    const int w    = tid >> 6;
    const int lq   = lane & 15;
    const int lg   = lane >> 4;
    const int wm   = (w >> 1) * 64;
    const int wn   = (w & 1) * 64;
    const int m0   = blockIdx.x * 128;
    const int n0   = blockIdx.y * 128;

    // staging roles: w0: Ahi c0-15 | w1: Alo c0-15 | w2: B c0-7 | w3: B c8-15
    const unsigned short* const gp =
        (w == 0) ? Ahi + (size_t)m0 * K :
        (w == 1) ? Alo + (size_t)m0 * K :
                   Bh  + (size_t)n0 * K;
    const int pbase = (w == 0) ? 0 : (w == 1) ? 16384 : 32768;
    const int c0    = (w == 3) ? 8 : 0;
    const int cnt   = (w < 2) ? 16 : 8;
    const int scol8 = (((lane & 7) ^ (lane >> 3)) << 3);   // pre-swizzled col
    const int lrow8 = lane >> 3;

    f32x4 acc[4][4];
    #pragma unroll
    for (int mt = 0; mt < 4; ++mt)
        #pragma unroll
        for (int nt = 0; nt < 4; ++nt)
            acc[mt][nt] = (f32x4){0.f, 0.f, 0.f, 0.f};

    for (int k0 = 0; k0 < K; k0 += 64) {
        #pragma unroll
        for (int r = 0; r < 16; ++r) {
            if (r < cnt) {
                const int c = c0 + r;
                GLOAD_LDS(gp + (size_t)(c * 8 + lrow8) * K + k0 + scol8,
                          lds + pbase + c * 1024 + 16 * lane);
            }
        }
        __syncthreads();

        #pragma unroll
        for (int kh = 0; kh < 2; ++kh) {
            half8 afh[4], afl[4];
            #pragma unroll
            for (int mt = 0; mt < 4; ++mt) {
                const int row = wm + 16 * mt + lq;
                const int off = row * 128 + ((kh * 64 + 16 * lg) ^ ((row & 7) << 4));
                afh[mt] = *(const half8*)(lds + off);
                afl[mt] = *(const half8*)(lds + 16384 + off);
            }
            #pragma unroll
            for (int nt = 0; nt < 4; ++nt) {
                const int row = wn + 16 * nt + lq;
                const int off = row * 128 + ((kh * 64 + 16 * lg) ^ ((row & 7) << 4));
                half8 bf = *(const half8*)(lds + 32768 + off);
                #pragma unroll
                for (int mt = 0; mt < 4; ++mt) {
                    acc[mt][nt] = MFMAH(afh[mt], bf, acc[mt][nt], 0, 0, 0);
                    acc[mt][nt] = MFMAH(afl[mt], bf, acc[mt][nt], 0, 0, 0);
                }
            }
        }
        __syncthreads();
    }

    float gain = 0.f, ascv = 0.f, abiv = 0.f;
    if (MODE == 6) {
        gain = 0.25f * (*g0 + *g1 + *g2 + *g3);
        ascv = *asc;
        abiv = *abi;
    }

    #pragma unroll
    for (int nt = 0; nt < 4; ++nt) {
        const int n  = n0 + wn + 16 * nt + lq;
        const float bv = bias[n];
        #pragma unroll
        for (int mt = 0; mt < 4; ++mt) {
            #pragma unroll
            for (int j = 0; j < 4; ++j) {
                const int m = m0 + wm + 16 * mt + 4 * lg + j;
                float v = acc[mt][nt][j] + bv;
                if (RELU) v = fmaxf(v, 0.f);
                if (MODE == 0) {
                    C[(size_t)m * N + n] = v;
                } else if (MODE == 1) {
                    const int b = m >> 11, s = m & 2047;
                    const int h = n >> 6, d = n & 63;
                    C[((size_t)(b * PH + h) * PS + s) * PD + d] = v;
                } else if (MODE == 3) {
                    const int b = m >> 11, s = m & 2047;
                    const int h = n >> 6, d = n & 63;
                    Ohi[((size_t)(b * PH + h) * PS + s) * PD + d] = h16(v);
                } else if (MODE == 4) {
                    const int b = m >> 11;
                    const int h = n >> 6, d = n & 63;
                    const int scol = (m & 2047 & ~63) + ((mt & 1) << 5)
                                   + (lg << 3) + ((mt >> 1) << 2) + j;
                    Ohi[((size_t)(b * PH + h) * PD + d) * PS + scol] = h16(v);
                } else if (MODE == 5) {
                    const size_t idx = (size_t)m * N + n;
                    unsigned short hh, ll;
                    splith(v, hh, ll);
                    Ohi[idx] = hh; Olo[idx] = ll;
                } else { // MODE 6
                    const int b = m >> 11, s = m & 2047;
                    const int h = n >> 6, d = n & 63;
                    const float av = attn[((size_t)(b * PH + h) * PS + s) * PD + d];
                    const float o = (av * ascv + abiv) * (1.f + v * gain);
                    const size_t idx = (size_t)m * N + n;
                    unsigned short hh, ll;
                    splith(o, hh, ll);
                    Ohi[idx] = hh; Olo[idx] = ll;
                }
            }
        }
    }
}

// ---------------------------------------------------------------------------
// fp32-fed fallback GEMM (bf16 3-term internally, round-5 proven skeleton);
// MODE 3/4 emit fp16 single planes for the fp16 flash.
// ---------------------------------------------------------------------------
typedef __attribute__((ext_vector_type(8))) short short8;
#define MFMA16 __builtin_amdgcn_mfma_f32_16x16x32_bf16
__device__ inline unsigned short bf16rn(float x) {
    unsigned u = __builtin_bit_cast(unsigned, x);
    u += 0x7FFFu + ((u >> 16) & 1u);
    return (unsigned short)(u >> 16);
}
__device__ inline float bf16tof(unsigned short h) {
    unsigned u = ((unsigned)h) << 16;
    return __builtin_bit_cast(float, u);
}
__device__ inline void split2(float x, unsigned short& h, unsigned short& l) {
    h = bf16rn(x);
    l = bf16rn(x - bf16tof(h));
}

template<int MODE, bool RELU>
__global__ __launch_bounds__(256, 2)
void gemm_nt(const float* __restrict__ A, const float* __restrict__ Bw,
             const float* __restrict__ bias, float* __restrict__ C,
             unsigned short* __restrict__ Ohi,
             int M, int N, int K,
             const float* __restrict__ attn,
             const float* __restrict__ g0, const float* __restrict__ g1,
             const float* __restrict__ g2, const float* __restrict__ g3,
             const float* __restrict__ asc, const float* __restrict__ abi)
{
    __shared__ int4 ldsq[4096];
    char* const lds = (char*)ldsq;

    const int tid  = threadIdx.x;
    const int lane = tid & 63;
    const int w    = tid >> 6;
    const int lq   = lane & 15;
    const int lg   = lane >> 4;
    const int wm   = (w >> 1) * 64;
    const int wn   = (w & 1) * 64;
    const int m0   = blockIdx.x * 128;
    const int n0   = blockIdx.y * 128;

    const int irow = tid >> 3;
    const int ic8  = (tid & 7) * 8;
    const int woff = (ic8 * 2);

    f32x4 acc[4][4];
    #pragma unroll
    for (int mt = 0; mt < 4; ++mt)
        #pragma unroll
        for (int nt = 0; nt < 4; ++nt)
            acc[mt][nt] = (f32x4){0.f, 0.f, 0.f, 0.f};

    for (int k0 = 0; k0 < K; k0 += 64) {
        #pragma unroll
        for (int mat = 0; mat < 2; ++mat) {
            const float* const src = mat ? Bw : A;
            const int rbase = mat ? n0 : m0;
            const int pbase = mat ? 32768 : 0;
            #pragma unroll
            for (int r = 0; r < 4; ++r) {
                const int row = irow + 32 * r;
                const float* p = src + (size_t)(rbase + row) * K + k0 + ic8;
                float4 f0 = *(const float4*)p;
                float4 f1 = *(const float4*)(p + 4);
                short8 vh, vl;
                {
                    unsigned short h, l;
                    split2(f0.x, h, l); vh[0] = (short)h; vl[0] = (short)l;
                    split2(f0.y, h, l); vh[1] = (short)h; vl[1] = (short)l;
                    split2(f0.z, h, l); vh[2] = (short)h; vl[2] = (short)l;
                    split2(f0.w, h, l); vh[3] = (short)h; vl[3] = (short)l;
                    split2(f1.x, h, l); vh[4] = (short)h; vl[4] = (short)l;
                    split2(f1.y, h, l); vh[5] = (short)h; vl[5] = (short)l;
                    split2(f1.z, h, l); vh[6] = (short)h; vl[6] = (short)l;
                    split2(f1.w, h, l); vh[7] = (short)h; vl[7] = (short)l;
                }
                const int off = row * 128 + (woff ^ ((row & 7) << 4));
                *(short8*)(lds + pbase + off)         = vh;
                *(short8*)(lds + pbase + 16384 + off) = vl;
            }
        }
        __syncthreads();

        #pragma unroll
        for (int kh = 0; kh < 2; ++kh) {
            short8 afh[4], afl[4];
            #pragma unroll
            for (int mt = 0; mt < 4; ++mt) {
                const int row = wm + 16 * mt + lq;
                const int off = row * 128 + ((kh * 64 + 16 * lg) ^ ((row & 7) << 4));
                afh[mt] = *(const short8*)(lds + off);
                afl[mt] = *(const short8*)(lds + 16384 + off);
            }
            #pragma unroll
            for (int nt = 0; nt < 4; ++nt) {
                const int row = wn + 16 * nt + lq;
                const int off = row * 128 + ((kh * 64 + 16 * lg) ^ ((row & 7) << 4));
                short8 bfh = *(const short8*)(lds + 32768 + off);
                short8 bfl = *(const short8*)(lds + 49152 + off);
                #pragma unroll
                for (int mt = 0; mt < 4; ++mt) {
                    acc[mt][nt] = MFMA16(afh[mt], bfh, acc[mt][nt], 0, 0, 0);
                    acc[mt][nt] = MFMA16(afh[mt], bfl, acc[mt][nt], 0, 0, 0);
                    acc[mt][nt] = MFMA16(afl[mt], bfh, acc[mt][nt], 0, 0, 0);
                }
            }
        }
        __syncthreads();
    }

    float gain = 0.f, ascv = 0.f, abiv = 0.f;
    if (MODE == 2) {
        gain = 0.25f * (*g0 + *g1 + *g2 + *g3);
        ascv = *asc;
        abiv = *abi;
    }

    #pragma unroll
    for (int nt = 0; nt < 4; ++nt) {
        const int n  = n0 + wn + 16 * nt + lq;
        const float bv = bias[n];
        #pragma unroll
        for (int mt = 0; mt < 4; ++mt) {
            #pragma unroll
            for (int j = 0; j < 4; ++j) {
                const int m = m0 + wm + 16 * mt + 4 * lg + j;
                float v = acc[mt][nt][j] + bv;
                if (RELU) v = fmaxf(v, 0.f);
                if (MODE == 0) {
                    C[(size_t)m * N + n] = v;
                } else if (MODE == 1) {
                    const int b = m >> 11, s = m & 2047;
                    const int h = n >> 6, d = n & 63;
                    C[((size_t)(b * PH + h) * PS + s) * PD + d] = v;
                } else if (MODE == 3) {
                    const int b = m >> 11, s = m & 2047;
                    const int h = n >> 6, d = n & 63;
                    Ohi[((size_t)(b * PH + h) * PS + s) * PD + d] = h16(v);
                } else if (MODE == 4) {
                    const int b = m >> 11;
                    const int h = n >> 6, d = n & 63;
                    const int scol = (m & 2047 & ~63) + ((mt & 1) << 5)
                                   + (lg << 3) + ((mt >> 1) << 2) + j;
                    Ohi[((size_t)(b * PH + h) * PD + d) * PS + scol] = h16(v);
                } else { // MODE 2
                    const int b = m >> 11, s = m & 2047;
                    const int h = n >> 6, d = n & 63;
                    const float av = attn[((size_t)(b * PH + h) * PS + s) * PD + d];
                    C[(size_t)m * N + n] = (av * ascv + abiv) * (1.f + v * gain);
                }
            }
        }
    }
}

// ---------------------------------------------------------------------------
// MFMA flash attention v8 (fp16): Q single fp16 (QK^T 2 MFMA/mt/u), K and
// V^T single fp16 planes, P fp16, l via MFMA(ones,P). exp2-domain softmax:
// 0.125*log2(e) folded into Q scale, bare v_exp_f32 (=2^x) for P, defer-max
// threshold 8*log2(e). max3-tree pmax reduction. 32KB double-buffer,
// gload_lds staging w/ pre-swizzled source, XCD swizzle. 36 MFMA/tile/wave.
// ---------------------------------------------------------------------------
__global__ __launch_bounds__(256, 2)
void flash_mfma(const float* qf,
                const unsigned short* __restrict__ kf,
                const unsigned short* __restrict__ vtf,
                float* attn)
{
    __shared__ int4 ldsv[2048];                    // 32 KB: 2 bufs x (K8K + V8K)
    char* const ldsb = (char*)ldsv;

    const int tid  = threadIdx.x;
    const int lane = tid & 63;
    const int w    = tid >> 6;
    const int lq   = lane & 15;
    const int lg   = lane >> 4;

    // XCD swizzle: each XCD owns 128 consecutive logical blocks (= 8 bh).
    const int L  = blockIdx.x + (blockIdx.y << 4) + (blockIdx.z << 8);
    const int nL = ((L & 7) << 7) + (L >> 3);
    const int bh = nL >> 4;
    const int q0 = (nL & 15) * 128 + w * 32;

    const size_t kbase = (size_t)bh * PS * PD;   // K rows   [S][D]
    const size_t vbase = (size_t)bh * PD * PS;   // V^T rows [D][S] (permuted)

    const unsigned short* const gp = (w < 2) ? kf + kbase : vtf + vbase;
    const bool isK = (w < 2);
    const int ch0   = (w & 1) * 4;
    const int scol8 = (((lane & 7) ^ (lane >> 3)) << 3);   // pre-swizzled col
    const int lrow8 = lane >> 3;

    auto ISSUE = [&](int kt, int bufn) {
        #pragma unroll
        for (int r = 0; r < 4; ++r) {
            const int c   = ch0 + r;
            const int row = c * 8 + lrow8;
            const size_t goff = isK ? (size_t)(kt + row) * PD + scol8
                                    : (size_t)row * PS + kt + scol8;
            GLOAD_LDS(gp + goff,
                      ldsb + bufn * 16384 + (isK ? 0 : 8192) + c * 1024 + 16 * lane);
        }
    };

    const half8 onesh = {(_Float16)1.f, (_Float16)1.f, (_Float16)1.f,
                         (_Float16)1.f, (_Float16)1.f, (_Float16)1.f,
                         (_Float16)1.f, (_Float16)1.f};

    // ---- Q fragments: scale (1/8)*log2(e) folded in; SINGLE fp16.
    const float QSCALE = 0.125f * 1.4426950408889634f;
    half8 qh[2][2];
    #pragma unroll
    for (int u = 0; u < 2; ++u) {
        const float* qp = qf + ((size_t)bh * PS + q0 + 16 * u + lq) * PD + 8 * lg;
        #pragma unroll
        for (int t = 0; t < 2; ++t)
            #pragma unroll
            for (int b = 0; b < 8; ++b)
                qh[u][t][b] = (_Float16)(qp[t * 32 + b] * QSCALE);
    }

    f32x4 ot[2][4];
    #pragma unroll
    for (int u = 0; u < 2; ++u)
        #pragma unroll
        for (int mt = 0; mt < 4; ++mt)
            ot[u][mt] = (f32x4){0.f, 0.f, 0.f, 0.f};
    f32x4 lacc[2] = {{0.f,0.f,0.f,0.f}, {0.f,0.f,0.f,0.f}};
    float m_run[2] = {-3.0e38f, -3.0e38f};

    ISSUE(0, 0);
    __syncthreads();

    int buf = 0;
    for (int kti = 0; kti < PS / 64; ++kti) {
        const bool pf = (kti + 1 < PS / 64);
        if (pf) ISSUE((kti + 1) * 64, buf ^ 1);

        const char* const L2 = ldsb + buf * 16384;

        // ---- S^T tiles (log2 domain), Q single fp16: 2 MFMA per mt/u
        f32x4 st[2][4];
        #pragma unroll
        for (int mt = 0; mt < 4; ++mt) {
            const int row = 16 * mt + lq;
            const int swz = (row & 7) << 4;
            const char* kr = L2 + row * 128;
            half8 a0 = *(const half8*)(kr + ((16 * lg) ^ swz));
            half8 a1 = *(const half8*)(kr + ((64 + 16 * lg) ^ swz));
            #pragma unroll
            for (int u = 0; u < 2; ++u) {
                f32x4 acc = {0.f, 0.f, 0.f, 0.f};
                acc = MFMAH(a0, qh[u][0], acc, 0, 0, 0);
                acc = MFMAH(a1, qh[u][1], acc, 0, 0, 0);
                st[u][mt] = acc;
            }
        }

        // ---- online softmax (defer-max, log2 domain) + P fp16 + l via MFMA
        half8 pb[2][2];
        #pragma unroll
        for (int u = 0; u < 2; ++u) {
            // max3-tree reduction over the 16 in-lane scores
            float a0 = fmaxf(fmaxf(st[u][0][0], st[u][0][1]), st[u][0][2]);
            float a1 = fmaxf(fmaxf(st[u][0][3], st[u][1][0]), st[u][1][1]);
            float a2 = fmaxf(fmaxf(st[u][1][2], st[u][1][3]), st[u][2][0]);
            float a3 = fmaxf(fmaxf(st[u][2][1], st[u][2][2]), st[u][2][3]);
            float a4 = fmaxf(fmaxf(st[u][3][0], st[u][3][1]), st[u][3][2]);
            float b0 = fmaxf(fmaxf(a0, a1), a2);
            float b1 = fmaxf(fmaxf(a3, a4), st[u][3][3]);
            float pmax = fmaxf(b0, b1);
            pmax = fmaxf(pmax, __shfl_xor(pmax, 16));
            pmax = fmaxf(pmax, __shfl_xor(pmax, 32));
            if (!__all(pmax - m_run[u] <= 11.5415603f)) {  // 8*log2(e)
                float mnew = fmaxf(m_run[u], pmax);
                float corr = exp2f(m_run[u] - mnew);
                m_run[u] = mnew;
                #pragma unroll
                for (int j = 0; j < 4; ++j)
                    lacc[u][j] *= corr;
                #pragma unroll
                for (int mt = 0; mt < 4; ++mt)
                    #pragma unroll
                    for (int j = 0; j < 4; ++j)
                        ot[u][mt][j] *= corr;
            }
            #pragma unroll
            for (int mt = 0; mt < 4; ++mt)
                #pragma unroll
                for (int j = 0; j < 4; ++j)
                    st[u][mt][j] = exp2f(st[u][mt][j] - m_run[u]);
            // pb[u][t][b] = fp16(st[u][(b>>2)*2+t][b&3])
            #pragma unroll
            for (int t = 0; t < 2; ++t)
                #pragma unroll
                for (int b = 0; b < 8; ++b)
                    pb[u][t][b] = (_Float16)st[u][(b >> 2) * 2 + t][b & 3];
            lacc[u] = MFMAH(onesh, pb[u][0], lacc[u], 0, 0, 0);
            lacc[u] = MFMAH(onesh, pb[u][1], lacc[u], 0, 0, 0);
        }

        // ---- O^T += V^T . P^T   (V single fp16, P fp16: 1 MFMA each)
        #pragma unroll
        for (int t = 0; t < 2; ++t) {
            #pragma unroll
            for (int mt = 0; mt < 4; ++mt) {
                const int row = 16 * mt + lq;
                const int swz = (row & 7) << 4;
                const char* vr = L2 + 8192 + row * 128;
                half8 vv = *(const half8*)(vr + ((t * 64 + 16 * lg) ^ swz));
                #pragma unroll
                for (int u = 0; u < 2; ++u)
                    ot[u][mt] = MFMAH(vv, pb[u][t], ot[u][mt], 0, 0, 0);
            }
        }

        __syncthreads();        // drains prefetch vmcnt + protects LDS reuse
        buf ^= 1;
    }

    // ---- epilogue: attn[bh][q0+16u+lq][d], d = 16*mt + 4*lg + j
    #pragma unroll
    for (int u = 0; u < 2; ++u) {
        const float inv = 1.f / lacc[u][0];
        float* op = attn + ((size_t)bh * PS + q0 + 16 * u + lq) * PD + 4 * lg;
        #pragma unroll
        for (int mt = 0; mt < 4; ++mt) {
            float4 o;
            o.x = ot[u][mt][0] * inv; o.y = ot[u][mt][1] * inv;
            o.z = ot[u][mt][2] * inv; o.w = ot[u][mt][3] * inv;
            *(float4*)(op + 16 * mt) = o;
        }
    }
}

// ---------------------------------------------------------------------------
extern "C" void kernel_launch(void* const* d_in, const int* in_sizes, int n_in,
                              void* d_out, int out_size, void* d_ws, size_t ws_size,
                              hipStream_t stream)
{
    const float* query = (const float*)d_in[0];
    const float* Wq  = (const float*)d_in[1];  const float* bq  = (const float*)d_in[2];
    const float* Wk  = (const float*)d_in[3];  const float* bk  = (const float*)d_in[4];
    const float* Wv  = (const float*)d_in[5];  const float* bv  = (const float*)d_in[6];
    const float* Wo  = (const float*)d_in[7];  const float* bo  = (const float*)d_in[8];
    const float* Wm1 = (const float*)d_in[9];  const float* bm1 = (const float*)d_in[10];
    const float* Wm2 = (const float*)d_in[11]; const float* bm2 = (const float*)d_in[12];
    const float* dop = (const float*)d_in[13];
    const float* ser = (const float*)d_in[14];
    const float* nor = (const float*)d_in[15];
    const float* ach = (const float*)d_in[16];
    const float* asc = (const float*)d_in[17];
    const float* abi = (const float*)d_in[18];
    float* out = (float*)d_out;

    char* wsb = (char*)d_ws;
    // Common: qf32 [0,32M), kf fp16 [32M,48M), vtf fp16 [48M,64M)
    float*          qf32 = (float*)wsb;
    unsigned short* kf   = (unsigned short*)(wsb + (32u << 20));
    unsigned short* vtf  = (unsigned short*)(wsb + (48u << 20));

    dim3 blk(256);
    const bool presplit = (ws_size >= 161480704ull);             // 154 MB

    if (presplit) {
        unsigned short* h1hi  = (unsigned short*)(wsb + (64u << 20));  // 4MB
        unsigned short* h1lo  = (unsigned short*)(wsb + (68u << 20));  // 4MB
        unsigned short* afhi  = (unsigned short*)(wsb + (72u << 20));  // 16MB
        unsigned short* aflo  = (unsigned short*)(wsb + (88u << 20));  // 16MB
        unsigned short* qhi   = (unsigned short*)(wsb + (104u << 20)); // 16MB
        unsigned short* qlo   = (unsigned short*)(wsb + (120u << 20)); // 16MB
        unsigned short* wqh   = (unsigned short*)(wsb + (136u << 20)); // 2MB
        unsigned short* wkh   = (unsigned short*)(wsb + (138u << 20));
        unsigned short* wvh   = (unsigned short*)(wsb + (140u << 20));
        unsigned short* woh   = (unsigned short*)(wsb + (142u << 20));
        unsigned short* m1h   = (unsigned short*)(wsb + (144u << 20)); // 0.5MB
        unsigned short* m2h   = (unsigned short*)(wsb + (145u << 20));

        split_all<<<12800, blk, 0, stream>>>(
            query, Wq, Wk, Wv, Wo, Wm1, Wm2,
            qhi, qlo, wqh, wkh, wvh, woh, m1h, m2h);

        gemm_pl<1, false><<<dim3(PM / 128, PE / 128), blk, 0, stream>>>(
            qhi, qlo, wqh, bq, qf32, nullptr, nullptr, PM, PE, PE,
            nullptr, nullptr, nullptr, nullptr, nullptr, nullptr, nullptr);
        gemm_pl<3, false><<<dim3(PM / 128, PE / 128), blk, 0, stream>>>(
            qhi, qlo, wkh, bk, nullptr, kf, nullptr, PM, PE, PE,
            nullptr, nullptr, nullptr, nullptr, nullptr, nullptr, nullptr);
        gemm_pl<4, false><<<dim3(PM / 128, PE / 128), blk, 0, stream>>>(
            qhi, qlo, wvh, bv, nullptr, vtf, nullptr, PM, PE, PE,
            nullptr, nullptr, nullptr, nullptr, nullptr, nullptr, nullptr);
        gemm_pl<5, true><<<dim3(PM / 128, 256 / 128), blk, 0, stream>>>(
            qhi, qlo, m1h, bm1, nullptr, h1hi, h1lo, PM, 256, PE,
            nullptr, nullptr, nullptr, nullptr, nullptr, nullptr, nullptr);

        flash_mfma<<<dim3(PS / 128, PH, PB), blk, 0, stream>>>(
            qf32, kf, vtf, qf32);

        gemm_pl<6, false><<<dim3(PM / 128, PE / 128), blk, 0, stream>>>(
            h1hi, h1lo, m2h, bm2, nullptr, afhi, aflo, PM, PE, 256,
            qf32, dop, ser, nor, ach, asc, abi);
        gemm_pl<0, false><<<dim3(PM / 128, PE / 128), blk, 0, stream>>>(
            afhi, aflo, woh, bo, out, nullptr, nullptr, PM, PE, PE,
            nullptr, nullptr, nullptr, nullptr, nullptr, nullptr, nullptr);
    } else {
        // fallback: fp32-fed bf16 3-term GEMMs + fp16 flash
        float* h1    = (float*)(wsb + (64u << 20));   // 8MB
        float* attnf = (float*)(wsb + (72u << 20));   // 32MB

        gemm_nt<1, false><<<dim3(PM / 128, PE / 128), blk, 0, stream>>>(
            query, Wq, bq, qf32, nullptr, PM, PE, PE,
            nullptr, nullptr, nullptr, nullptr, nullptr, nullptr, nullptr);
        gemm_nt<3, false><<<dim3(PM / 128, PE / 128), blk, 0, stream>>>(
            query, Wk, bk, nullptr, kf, PM, PE, PE,
            nullptr, nullptr, nullptr, nullptr, nullptr, nullptr, nullptr);
        gemm_nt<4, false><<<dim3(PM / 128, PE / 128), blk, 0, stream>>>(
            query, Wv, bv, nullptr, vtf, PM, PE, PE,
            nullptr, nullptr, nullptr, nullptr, nullptr, nullptr, nullptr);
        gemm_nt<0, true><<<dim3(PM / 128, 256 / 128), blk, 0, stream>>>(
            query, Wm1, bm1, h1, nullptr, PM, 256, PE,
            nullptr, nullptr, nullptr, nullptr, nullptr, nullptr, nullptr);

        flash_mfma<<<dim3(PS / 128, PH, PB), blk, 0, stream>>>(
            qf32, kf, vtf, qf32);

        gemm_nt<2, false><<<dim3(PM / 128, PE / 128), blk, 0, stream>>>(
            h1, Wm2, bm2, attnf, nullptr, PM, PE, 256,
            qf32, dop, ser, nor, ach, asc, abi);
        gemm_nt<0, false><<<dim3(PM / 128, PE / 128), blk, 0, stream>>>(
            attnf, Wo, bo, out, nullptr, PM, PE, PE,
            nullptr, nullptr, nullptr, nullptr, nullptr, nullptr, nullptr);
    }
}

// Round 14
// 298.515 us; speedup vs baseline: 1.0816x; 1.0816x over previous
//
#include <hip/hip_runtime.h>
#include <hip/hip_bf16.h>
#include <cstdint>

// Problem constants
#define PB 4
#define PS 2048
#define PE 1024
#define PH 16
#define PD 64
#define PM (PB * PS)      // 8192 rows

typedef __attribute__((ext_vector_type(8))) _Float16 half8;  // 8 fp16 (4 VGPR)
typedef __attribute__((ext_vector_type(4))) float f32x4;

#define MFMAH __builtin_amdgcn_mfma_f32_16x16x32_f16

#define GLOAD_LDS(gp, lp) __builtin_amdgcn_global_load_lds(                    \
    (const __attribute__((address_space(1))) void*)(gp),                       \
    (__attribute__((address_space(3))) void*)(lp), 16, 0, 0)

#if __has_builtin(__builtin_amdgcn_exp2f)
#define FAST_EXP2 1
#else
#define FAST_EXP2 0
#endif

// fp32 -> fp16 RNE bit pattern
__device__ inline unsigned short h16(float x) {
    _Float16 h = (_Float16)x;
    unsigned short u;
    __builtin_memcpy(&u, &h, 2);
    return u;
}
// fp16 hi/lo split (exact: x-hi is Sterbenz-exact in fp32)
__device__ inline void splith(float x, unsigned short& h, unsigned short& l) {
    _Float16 hh = (_Float16)x;
    _Float16 ll = (_Float16)(x - (float)hh);
    __builtin_memcpy(&h, &hh, 2);
    __builtin_memcpy(&l, &ll, 2);
}
// packed fp16 pair via v_cvt_pkrtz_f16_f32; returns the 32-bit word
__device__ inline unsigned pkrtz(float a, float b) {
    auto p = __builtin_amdgcn_cvt_pkrtz(a, b);   // __fp16 ext_vector(2)
    unsigned u;
    __builtin_memcpy(&u, &p, 4);
    return u;
}

// ---------------------------------------------------------------------------
// split_all: query -> fp16 hi/lo planes; weights -> single fp16 plane.
// f4 ranges: query 2097152 | Wq/Wk/Wv/Wo 262144 each | Wm1/Wm2 65536 each.
// ---------------------------------------------------------------------------
__global__ __launch_bounds__(256)
void split_all(const float* __restrict__ q,   const float* __restrict__ wq,
               const float* __restrict__ wk,  const float* __restrict__ wv,
               const float* __restrict__ wo,  const float* __restrict__ wm1,
               const float* __restrict__ wm2,
               unsigned short* qhi,  unsigned short* qlo,
               unsigned short* wqh, unsigned short* wkh,
               unsigned short* wvh, unsigned short* woh,
               unsigned short* m1h, unsigned short* m2h)
{
    const int b = blockIdx.x;
    if (b < 8192) {          // query: hi/lo
        const int i = b * 256 + threadIdx.x;
        float4 f = ((const float4*)q)[i];
        ushort4 h, l;
        splith(f.x, h.x, l.x); splith(f.y, h.y, l.y);
        splith(f.z, h.z, l.z); splith(f.w, h.w, l.w);
        ((ushort4*)qhi)[i] = h;
        ((ushort4*)qlo)[i] = l;
        return;
    }
    const float* src; unsigned short* dst; int base;
    if      (b <  9216) { src = wq;  dst = wqh; base = 8192;  }
    else if (b < 10240) { src = wk;  dst = wkh; base = 9216;  }
    else if (b < 11264) { src = wv;  dst = wvh; base = 10240; }
    else if (b < 12288) { src = wo;  dst = woh; base = 11264; }
    else if (b < 12544) { src = wm1; dst = m1h; base = 12288; }
    else                { src = wm2; dst = m2h; base = 12544; }
    const int i = (b - base) * 256 + threadIdx.x;
    float4 f = ((const float4*)src)[i];
    ushort4 h;
    h.x = h16(f.x); h.y = h16(f.y); h.z = h16(f.z); h.w = h16(f.w);
    ((ushort4*)dst)[i] = h;
}

// ---------------------------------------------------------------------------
// Plane-fed 2-term fp16 MFMA NT GEMM (round-11 proven engine, unchanged).
// ---------------------------------------------------------------------------
template<int MODE, bool RELU>
__global__ __launch_bounds__(256, 2)
void gemm_pl(const unsigned short* __restrict__ Ahi,
             const unsigned short* __restrict__ Alo,
             const unsigned short* __restrict__ Bh,
             const float* __restrict__ bias, float* __restrict__ C,
             unsigned short* __restrict__ Ohi, unsigned short* __restrict__ Olo,
             int M, int N, int K,
             const float* __restrict__ attn,
             const float* __restrict__ g0, const float* __restrict__ g1,
             const float* __restrict__ g2, const float* __restrict__ g3,
             const float* __restrict__ asc, const float* __restrict__ abi)
{
    __shared__ int4 ldsq[3072];                 // 48 KB = 3 planes x 16 KB
    char* const lds = (char*)ldsq;

    const int tid  = threadIdx.x;
    const int lane = tid & 63;
    const int w    = tid >> 6;
    const int lq   = lane & 15;
    const int lg   = lane >> 4;
    const int wm   = (w >> 1) * 64;
    const int wn   = (w & 1) * 64;
    const int m0   = blockIdx.x * 128;
    const int n0   = blockIdx.y * 128;

    // staging roles: w0: Ahi c0-15 | w1: Alo c0-15 | w2: B c0-7 | w3: B c8-15
    const unsigned short* const gp =
        (w == 0) ? Ahi + (size_t)m0 * K :
        (w == 1) ? Alo + (size_t)m0 * K :
                   Bh  + (size_t)n0 * K;
    const int pbase = (w == 0) ? 0 : (w == 1) ? 16384 : 32768;
    const int c0    = (w == 3) ? 8 : 0;
    const int cnt   = (w < 2) ? 16 : 8;
    const int scol8 = (((lane & 7) ^ (lane >> 3)) << 3);   // pre-swizzled col
    const int lrow8 = lane >> 3;

    f32x4 acc[4][4];
    #pragma unroll
    for (int mt = 0; mt < 4; ++mt)
        #pragma unroll
        for (int nt = 0; nt < 4; ++nt)
            acc[mt][nt] = (f32x4){0.f, 0.f, 0.f, 0.f};

    for (int k0 = 0; k0 < K; k0 += 64) {
        #pragma unroll
        for (int r = 0; r < 16; ++r) {
            if (r < cnt) {
                const int c = c0 + r;
                GLOAD_LDS(gp + (size_t)(c * 8 + lrow8) * K + k0 + scol8,
                          lds + pbase + c * 1024 + 16 * lane);
            }
        }
        __syncthreads();

        #pragma unroll
        for (int kh = 0; kh < 2; ++kh) {
            half8 afh[4], afl[4];
            #pragma unroll
            for (int mt = 0; mt < 4; ++mt) {
                const int row = wm + 16 * mt + lq;
                const int off = row * 128 + ((kh * 64 + 16 * lg) ^ ((row & 7) << 4));
                afh[mt] = *(const half8*)(lds + off);
                afl[mt] = *(const half8*)(lds + 16384 + off);
            }
            #pragma unroll
            for (int nt = 0; nt < 4; ++nt) {
                const int row = wn + 16 * nt + lq;
                const int off = row * 128 + ((kh * 64 + 16 * lg) ^ ((row & 7) << 4));
                half8 bf = *(const half8*)(lds + 32768 + off);
                #pragma unroll
                for (int mt = 0; mt < 4; ++mt) {
                    acc[mt][nt] = MFMAH(afh[mt], bf, acc[mt][nt], 0, 0, 0);
                    acc[mt][nt] = MFMAH(afl[mt], bf, acc[mt][nt], 0, 0, 0);
                }
            }
        }
        __syncthreads();
    }

    float gain = 0.f, ascv = 0.f, abiv = 0.f;
    if (MODE == 6) {
        gain = 0.25f * (*g0 + *g1 + *g2 + *g3);
        ascv = *asc;
        abiv = *abi;
    }

    #pragma unroll
    for (int nt = 0; nt < 4; ++nt) {
        const int n  = n0 + wn + 16 * nt + lq;
        const float bv = bias[n];
        #pragma unroll
        for (int mt = 0; mt < 4; ++mt) {
            #pragma unroll
            for (int j = 0; j < 4; ++j) {
                const int m = m0 + wm + 16 * mt + 4 * lg + j;
                float v = acc[mt][nt][j] + bv;
                if (RELU) v = fmaxf(v, 0.f);
                if (MODE == 0) {
                    C[(size_t)m * N + n] = v;
                } else if (MODE == 1) {
                    const int b = m >> 11, s = m & 2047;
                    const int h = n >> 6, d = n & 63;
                    C[((size_t)(b * PH + h) * PS + s) * PD + d] = v;
                } else if (MODE == 3) {
                    const int b = m >> 11, s = m & 2047;
                    const int h = n >> 6, d = n & 63;
                    Ohi[((size_t)(b * PH + h) * PS + s) * PD + d] = h16(v);
                } else if (MODE == 4) {
                    const int b = m >> 11;
                    const int h = n >> 6, d = n & 63;
                    const int scol = (m & 2047 & ~63) + ((mt & 1) << 5)
                                   + (lg << 3) + ((mt >> 1) << 2) + j;
                    Ohi[((size_t)(b * PH + h) * PD + d) * PS + scol] = h16(v);
                } else if (MODE == 5) {
                    const size_t idx = (size_t)m * N + n;
                    unsigned short hh, ll;
                    splith(v, hh, ll);
                    Ohi[idx] = hh; Olo[idx] = ll;
                } else { // MODE 6
                    const int b = m >> 11, s = m & 2047;
                    const int h = n >> 6, d = n & 63;
                    const float av = attn[((size_t)(b * PH + h) * PS + s) * PD + d];
                    const float o = (av * ascv + abiv) * (1.f + v * gain);
                    const size_t idx = (size_t)m * N + n;
                    unsigned short hh, ll;
                    splith(o, hh, ll);
                    Ohi[idx] = hh; Olo[idx] = ll;
                }
            }
        }
    }
}

// ---------------------------------------------------------------------------
// fp32-fed fallback GEMM (bf16 3-term internally, round-5 proven skeleton);
// MODE 3/4 emit fp16 single planes for the fp16 flash.
// ---------------------------------------------------------------------------
typedef __attribute__((ext_vector_type(8))) short short8;
#define MFMA16 __builtin_amdgcn_mfma_f32_16x16x32_bf16
__device__ inline unsigned short bf16rn(float x) {
    unsigned u = __builtin_bit_cast(unsigned, x);
    u += 0x7FFFu + ((u >> 16) & 1u);
    return (unsigned short)(u >> 16);
}
__device__ inline float bf16tof(unsigned short h) {
    unsigned u = ((unsigned)h) << 16;
    return __builtin_bit_cast(float, u);
}
__device__ inline void split2(float x, unsigned short& h, unsigned short& l) {
    h = bf16rn(x);
    l = bf16rn(x - bf16tof(h));
}

template<int MODE, bool RELU>
__global__ __launch_bounds__(256, 2)
void gemm_nt(const float* __restrict__ A, const float* __restrict__ Bw,
             const float* __restrict__ bias, float* __restrict__ C,
             unsigned short* __restrict__ Ohi,
             int M, int N, int K,
             const float* __restrict__ attn,
             const float* __restrict__ g0, const float* __restrict__ g1,
             const float* __restrict__ g2, const float* __restrict__ g3,
             const float* __restrict__ asc, const float* __restrict__ abi)
{
    __shared__ int4 ldsq[4096];
    char* const lds = (char*)ldsq;

    const int tid  = threadIdx.x;
    const int lane = tid & 63;
    const int w    = tid >> 6;
    const int lq   = lane & 15;
    const int lg   = lane >> 4;
    const int wm   = (w >> 1) * 64;
    const int wn   = (w & 1) * 64;
    const int m0   = blockIdx.x * 128;
    const int n0   = blockIdx.y * 128;

    const int irow = tid >> 3;
    const int ic8  = (tid & 7) * 8;
    const int woff = (ic8 * 2);

    f32x4 acc[4][4];
    #pragma unroll
    for (int mt = 0; mt < 4; ++mt)
        #pragma unroll
        for (int nt = 0; nt < 4; ++nt)
            acc[mt][nt] = (f32x4){0.f, 0.f, 0.f, 0.f};

    for (int k0 = 0; k0 < K; k0 += 64) {
        #pragma unroll
        for (int mat = 0; mat < 2; ++mat) {
            const float* const src = mat ? Bw : A;
            const int rbase = mat ? n0 : m0;
            const int pbase = mat ? 32768 : 0;
            #pragma unroll
            for (int r = 0; r < 4; ++r) {
                const int row = irow + 32 * r;
                const float* p = src + (size_t)(rbase + row) * K + k0 + ic8;
                float4 f0 = *(const float4*)p;
                float4 f1 = *(const float4*)(p + 4);
                short8 vh, vl;
                {
                    unsigned short h, l;
                    split2(f0.x, h, l); vh[0] = (short)h; vl[0] = (short)l;
                    split2(f0.y, h, l); vh[1] = (short)h; vl[1] = (short)l;
                    split2(f0.z, h, l); vh[2] = (short)h; vl[2] = (short)l;
                    split2(f0.w, h, l); vh[3] = (short)h; vl[3] = (short)l;
                    split2(f1.x, h, l); vh[4] = (short)h; vl[4] = (short)l;
                    split2(f1.y, h, l); vh[5] = (short)h; vl[5] = (short)l;
                    split2(f1.z, h, l); vh[6] = (short)h; vl[6] = (short)l;
                    split2(f1.w, h, l); vh[7] = (short)h; vl[7] = (short)l;
                }
                const int off = row * 128 + (woff ^ ((row & 7) << 4));
                *(short8*)(lds + pbase + off)         = vh;
                *(short8*)(lds + pbase + 16384 + off) = vl;
            }
        }
        __syncthreads();

        #pragma unroll
        for (int kh = 0; kh < 2; ++kh) {
            short8 afh[4], afl[4];
            #pragma unroll
            for (int mt = 0; mt < 4; ++mt) {
                const int row = wm + 16 * mt + lq;
                const int off = row * 128 + ((kh * 64 + 16 * lg) ^ ((row & 7) << 4));
                afh[mt] = *(const short8*)(lds + off);
                afl[mt] = *(const short8*)(lds + 16384 + off);
            }
            #pragma unroll
            for (int nt = 0; nt < 4; ++nt) {
                const int row = wn + 16 * nt + lq;
                const int off = row * 128 + ((kh * 64 + 16 * lg) ^ ((row & 7) << 4));
                short8 bfh = *(const short8*)(lds + 32768 + off);
                short8 bfl = *(const short8*)(lds + 49152 + off);
                #pragma unroll
                for (int mt = 0; mt < 4; ++mt) {
                    acc[mt][nt] = MFMA16(afh[mt], bfh, acc[mt][nt], 0, 0, 0);
                    acc[mt][nt] = MFMA16(afh[mt], bfl, acc[mt][nt], 0, 0, 0);
                    acc[mt][nt] = MFMA16(afl[mt], bfh, acc[mt][nt], 0, 0, 0);
                }
            }
        }
        __syncthreads();
    }

    float gain = 0.f, ascv = 0.f, abiv = 0.f;
    if (MODE == 2) {
        gain = 0.25f * (*g0 + *g1 + *g2 + *g3);
        ascv = *asc;
        abiv = *abi;
    }

    #pragma unroll
    for (int nt = 0; nt < 4; ++nt) {
        const int n  = n0 + wn + 16 * nt + lq;
        const float bv = bias[n];
        #pragma unroll
        for (int mt = 0; mt < 4; ++mt) {
            #pragma unroll
            for (int j = 0; j < 4; ++j) {
                const int m = m0 + wm + 16 * mt + 4 * lg + j;
                float v = acc[mt][nt][j] + bv;
                if (RELU) v = fmaxf(v, 0.f);
                if (MODE == 0) {
                    C[(size_t)m * N + n] = v;
                } else if (MODE == 1) {
                    const int b = m >> 11, s = m & 2047;
                    const int h = n >> 6, d = n & 63;
                    C[((size_t)(b * PH + h) * PS + s) * PD + d] = v;
                } else if (MODE == 3) {
                    const int b = m >> 11, s = m & 2047;
                    const int h = n >> 6, d = n & 63;
                    Ohi[((size_t)(b * PH + h) * PS + s) * PD + d] = h16(v);
                } else if (MODE == 4) {
                    const int b = m >> 11;
                    const int h = n >> 6, d = n & 63;
                    const int scol = (m & 2047 & ~63) + ((mt & 1) << 5)
                                   + (lg << 3) + ((mt >> 1) << 2) + j;
                    Ohi[((size_t)(b * PH + h) * PD + d) * PS + scol] = h16(v);
                } else { // MODE 2
                    const int b = m >> 11, s = m & 2047;
                    const int h = n >> 6, d = n & 63;
                    const float av = attn[((size_t)(b * PH + h) * PS + s) * PD + d];
                    C[(size_t)m * N + n] = (av * ascv + abiv) * (1.f + v * gain);
                }
            }
        }
    }
}

// ---------------------------------------------------------------------------
// MFMA flash attention v9 (fp16): round-12 structure with the softmax VALU
// fixed: exp via __builtin_amdgcn_exp2f (single v_exp_f32; round-12's exp2f
// lowered to the precise libm path = ~10 VALU ops each, the regression),
// and P pack via v_cvt_pkrtz_f16_f32 (16 ops vs 32 scalar casts).
// Q single fp16, K/V^T single fp16 planes, l via MFMA(ones,P), defer-max,
// XCD swizzle, gload_lds staging w/ pre-swizzled source, 32KB dbuf.
// ---------------------------------------------------------------------------
__global__ __launch_bounds__(256, 2)
void flash_mfma(const float* qf,
                const unsigned short* __restrict__ kf,
                const unsigned short* __restrict__ vtf,
                float* attn)
{
    __shared__ int4 ldsv[2048];                    // 32 KB: 2 bufs x (K8K + V8K)
    char* const ldsb = (char*)ldsv;

    const int tid  = threadIdx.x;
    const int lane = tid & 63;
    const int w    = tid >> 6;
    const int lq   = lane & 15;
    const int lg   = lane >> 4;

    // XCD swizzle: each XCD owns 128 consecutive logical blocks (= 8 bh).
    const int L  = blockIdx.x + (blockIdx.y << 4) + (blockIdx.z << 8);
    const int nL = ((L & 7) << 7) + (L >> 3);
    const int bh = nL >> 4;
    const int q0 = (nL & 15) * 128 + w * 32;

    const size_t kbase = (size_t)bh * PS * PD;   // K rows   [S][D]
    const size_t vbase = (size_t)bh * PD * PS;   // V^T rows [D][S] (permuted)

    const unsigned short* const gp = (w < 2) ? kf + kbase : vtf + vbase;
    const bool isK = (w < 2);
    const int ch0   = (w & 1) * 4;
    const int scol8 = (((lane & 7) ^ (lane >> 3)) << 3);   // pre-swizzled col
    const int lrow8 = lane >> 3;

    auto ISSUE = [&](int kt, int bufn) {
        #pragma unroll
        for (int r = 0; r < 4; ++r) {
            const int c   = ch0 + r;
            const int row = c * 8 + lrow8;
            const size_t goff = isK ? (size_t)(kt + row) * PD + scol8
                                    : (size_t)row * PS + kt + scol8;
            GLOAD_LDS(gp + goff,
                      ldsb + bufn * 16384 + (isK ? 0 : 8192) + c * 1024 + 16 * lane);
        }
    };

    const half8 onesh = {(_Float16)1.f, (_Float16)1.f, (_Float16)1.f,
                         (_Float16)1.f, (_Float16)1.f, (_Float16)1.f,
                         (_Float16)1.f, (_Float16)1.f};

#if FAST_EXP2
    const float QSCALE = 0.125f * 1.4426950408889634f;   // exp2 domain
    const float THR    = 11.5415603f;                    // 8*log2(e)
#define EXP_P(x) __builtin_amdgcn_exp2f(x)
#else
    const float QSCALE = 0.125f;                         // natural domain
    const float THR    = 8.f;
#define EXP_P(x) __expf(x)
#endif

    // ---- Q fragments: SINGLE fp16, scale folded in
    half8 qh[2][2];
    #pragma unroll
    for (int u = 0; u < 2; ++u) {
        const float* qp = qf + ((size_t)bh * PS + q0 + 16 * u + lq) * PD + 8 * lg;
        #pragma unroll
        for (int t = 0; t < 2; ++t)
            #pragma unroll
            for (int b = 0; b < 8; ++b)
                qh[u][t][b] = (_Float16)(qp[t * 32 + b] * QSCALE);
    }

    f32x4 ot[2][4];
    #pragma unroll
    for (int u = 0; u < 2; ++u)
        #pragma unroll
        for (int mt = 0; mt < 4; ++mt)
            ot[u][mt] = (f32x4){0.f, 0.f, 0.f, 0.f};
    f32x4 lacc[2] = {{0.f,0.f,0.f,0.f}, {0.f,0.f,0.f,0.f}};
    float m_run[2] = {-3.0e38f, -3.0e38f};

    ISSUE(0, 0);
    __syncthreads();

    int buf = 0;
    for (int kti = 0; kti < PS / 64; ++kti) {
        const bool pf = (kti + 1 < PS / 64);
        if (pf) ISSUE((kti + 1) * 64, buf ^ 1);

        const char* const L2 = ldsb + buf * 16384;

        // ---- S^T tiles, Q single fp16: 2 MFMA per mt/u
        f32x4 st[2][4];
        #pragma unroll
        for (int mt = 0; mt < 4; ++mt) {
            const int row = 16 * mt + lq;
            const int swz = (row & 7) << 4;
            const char* kr = L2 + row * 128;
            half8 a0 = *(const half8*)(kr + ((16 * lg) ^ swz));
            half8 a1 = *(const half8*)(kr + ((64 + 16 * lg) ^ swz));
            #pragma unroll
            for (int u = 0; u < 2; ++u) {
                f32x4 acc = {0.f, 0.f, 0.f, 0.f};
                acc = MFMAH(a0, qh[u][0], acc, 0, 0, 0);
                acc = MFMAH(a1, qh[u][1], acc, 0, 0, 0);
                st[u][mt] = acc;
            }
        }

        // ---- online softmax (defer-max) + P pack (pkrtz) + l via MFMA
        half8 pb[2][2];
        #pragma unroll
        for (int u = 0; u < 2; ++u) {
            float a0 = fmaxf(fmaxf(st[u][0][0], st[u][0][1]), st[u][0][2]);
            float a1 = fmaxf(fmaxf(st[u][0][3], st[u][1][0]), st[u][1][1]);
            float a2 = fmaxf(fmaxf(st[u][1][2], st[u][1][3]), st[u][2][0]);
            float a3 = fmaxf(fmaxf(st[u][2][1], st[u][2][2]), st[u][2][3]);
            float a4 = fmaxf(fmaxf(st[u][3][0], st[u][3][1]), st[u][3][2]);
            float b0 = fmaxf(fmaxf(a0, a1), a2);
            float b1 = fmaxf(fmaxf(a3, a4), st[u][3][3]);
            float pmax = fmaxf(b0, b1);
            pmax = fmaxf(pmax, __shfl_xor(pmax, 16));
            pmax = fmaxf(pmax, __shfl_xor(pmax, 32));
            if (!__all(pmax - m_run[u] <= THR)) {   // rare: rescale path
                float mnew = fmaxf(m_run[u], pmax);
                float corr = EXP_P(m_run[u] - mnew);
                m_run[u] = mnew;
                #pragma unroll
                for (int j = 0; j < 4; ++j)
                    lacc[u][j] *= corr;
                #pragma unroll
                for (int mt = 0; mt < 4; ++mt)
                    #pragma unroll
                    for (int j = 0; j < 4; ++j)
                        ot[u][mt][j] *= corr;
            }
            #pragma unroll
            for (int mt = 0; mt < 4; ++mt)
                #pragma unroll
                for (int j = 0; j < 4; ++j)
                    st[u][mt][j] = EXP_P(st[u][mt][j] - m_run[u]);
            // pb[u][t] = [st[t][0..3], st[2+t][0..3]] packed fp16 (RTZ)
            #pragma unroll
            for (int t = 0; t < 2; ++t) {
                unsigned w0 = pkrtz(st[u][t][0],     st[u][t][1]);
                unsigned w1 = pkrtz(st[u][t][2],     st[u][t][3]);
                unsigned w2 = pkrtz(st[u][t + 2][0], st[u][t + 2][1]);
                unsigned w3 = pkrtz(st[u][t + 2][2], st[u][t + 2][3]);
                uint4 pw = make_uint4(w0, w1, w2, w3);
                __builtin_memcpy(&pb[u][t], &pw, 16);
            }
            lacc[u] = MFMAH(onesh, pb[u][0], lacc[u], 0, 0, 0);
            lacc[u] = MFMAH(onesh, pb[u][1], lacc[u], 0, 0, 0);
        }

        // ---- O^T += V^T . P^T   (V single fp16, P fp16: 1 MFMA each)
        #pragma unroll
        for (int t = 0; t < 2; ++t) {
            #pragma unroll
            for (int mt = 0; mt < 4; ++mt) {
                const int row = 16 * mt + lq;
                const int swz = (row & 7) << 4;
                const char* vr = L2 + 8192 + row * 128;
                half8 vv = *(const half8*)(vr + ((t * 64 + 16 * lg) ^ swz));
                #pragma unroll
                for (int u = 0; u < 2; ++u)
                    ot[u][mt] = MFMAH(vv, pb[u][t], ot[u][mt], 0, 0, 0);
            }
        }

        __syncthreads();        // drains prefetch vmcnt + protects LDS reuse
        buf ^= 1;
    }

    // ---- epilogue: attn[bh][q0+16u+lq][d], d = 16*mt + 4*lg + j
    #pragma unroll
    for (int u = 0; u < 2; ++u) {
        const float inv = 1.f / lacc[u][0];
        float* op = attn + ((size_t)bh * PS + q0 + 16 * u + lq) * PD + 4 * lg;
        #pragma unroll
        for (int mt = 0; mt < 4; ++mt) {
            float4 o;
            o.x = ot[u][mt][0] * inv; o.y = ot[u][mt][1] * inv;
            o.z = ot[u][mt][2] * inv; o.w = ot[u][mt][3] * inv;
            *(float4*)(op + 16 * mt) = o;
        }
    }
}

// ---------------------------------------------------------------------------
extern "C" void kernel_launch(void* const* d_in, const int* in_sizes, int n_in,
                              void* d_out, int out_size, void* d_ws, size_t ws_size,
                              hipStream_t stream)
{
    const float* query = (const float*)d_in[0];
    const float* Wq  = (const float*)d_in[1];  const float* bq  = (const float*)d_in[2];
    const float* Wk  = (const float*)d_in[3];  const float* bk  = (const float*)d_in[4];
    const float* Wv  = (const float*)d_in[5];  const float* bv  = (const float*)d_in[6];
    const float* Wo  = (const float*)d_in[7];  const float* bo  = (const float*)d_in[8];
    const float* Wm1 = (const float*)d_in[9];  const float* bm1 = (const float*)d_in[10];
    const float* Wm2 = (const float*)d_in[11]; const float* bm2 = (const float*)d_in[12];
    const float* dop = (const float*)d_in[13];
    const float* ser = (const float*)d_in[14];
    const float* nor = (const float*)d_in[15];
    const float* ach = (const float*)d_in[16];
    const float* asc = (const float*)d_in[17];
    const float* abi = (const float*)d_in[18];
    float* out = (float*)d_out;

    char* wsb = (char*)d_ws;
    // Common: qf32 [0,32M), kf fp16 [32M,48M), vtf fp16 [48M,64M)
    float*          qf32 = (float*)wsb;
    unsigned short* kf   = (unsigned short*)(wsb + (32u << 20));
    unsigned short* vtf  = (unsigned short*)(wsb + (48u << 20));

    dim3 blk(256);
    const bool presplit = (ws_size >= 161480704ull);             // 154 MB

    if (presplit) {
        unsigned short* h1hi  = (unsigned short*)(wsb + (64u << 20));  // 4MB
        unsigned short* h1lo  = (unsigned short*)(wsb + (68u << 20));  // 4MB
        unsigned short* afhi  = (unsigned short*)(wsb + (72u << 20));  // 16MB
        unsigned short* aflo  = (unsigned short*)(wsb + (88u << 20));  // 16MB
        unsigned short* qhi   = (unsigned short*)(wsb + (104u << 20)); // 16MB
        unsigned short* qlo   = (unsigned short*)(wsb + (120u << 20)); // 16MB
        unsigned short* wqh   = (unsigned short*)(wsb + (136u << 20)); // 2MB
        unsigned short* wkh   = (unsigned short*)(wsb + (138u << 20));
        unsigned short* wvh   = (unsigned short*)(wsb + (140u << 20));
        unsigned short* woh   = (unsigned short*)(wsb + (142u << 20));
        unsigned short* m1h   = (unsigned short*)(wsb + (144u << 20)); // 0.5MB
        unsigned short* m2h   = (unsigned short*)(wsb + (145u << 20));

        split_all<<<12800, blk, 0, stream>>>(
            query, Wq, Wk, Wv, Wo, Wm1, Wm2,
            qhi, qlo, wqh, wkh, wvh, woh, m1h, m2h);

        gemm_pl<1, false><<<dim3(PM / 128, PE / 128), blk, 0, stream>>>(
            qhi, qlo, wqh, bq, qf32, nullptr, nullptr, PM, PE, PE,
            nullptr, nullptr, nullptr, nullptr, nullptr, nullptr, nullptr);
        gemm_pl<3, false><<<dim3(PM / 128, PE / 128), blk, 0, stream>>>(
            qhi, qlo, wkh, bk, nullptr, kf, nullptr, PM, PE, PE,
            nullptr, nullptr, nullptr, nullptr, nullptr, nullptr, nullptr);
        gemm_pl<4, false><<<dim3(PM / 128, PE / 128), blk, 0, stream>>>(
            qhi, qlo, wvh, bv, nullptr, vtf, nullptr, PM, PE, PE,
            nullptr, nullptr, nullptr, nullptr, nullptr, nullptr, nullptr);
        gemm_pl<5, true><<<dim3(PM / 128, 256 / 128), blk, 0, stream>>>(
            qhi, qlo, m1h, bm1, nullptr, h1hi, h1lo, PM, 256, PE,
            nullptr, nullptr, nullptr, nullptr, nullptr, nullptr, nullptr);

        flash_mfma<<<dim3(PS / 128, PH, PB), blk, 0, stream>>>(
            qf32, kf, vtf, qf32);

        gemm_pl<6, false><<<dim3(PM / 128, PE / 128), blk, 0, stream>>>(
            h1hi, h1lo, m2h, bm2, nullptr, afhi, aflo, PM, PE, 256,
            qf32, dop, ser, nor, ach, asc, abi);
        gemm_pl<0, false><<<dim3(PM / 128, PE / 128), blk, 0, stream>>>(
            afhi, aflo, woh, bo, out, nullptr, nullptr, PM, PE, PE,
            nullptr, nullptr, nullptr, nullptr, nullptr, nullptr, nullptr);
    } else {
        // fallback: fp32-fed bf16 3-term GEMMs + fp16 flash
        float* h1    = (float*)(wsb + (64u << 20));   // 8MB
        float* attnf = (float*)(wsb + (72u << 20));   // 32MB

        gemm_nt<1, false><<<dim3(PM / 128, PE / 128), blk, 0, stream>>>(
            query, Wq, bq, qf32, nullptr, PM, PE, PE,
            nullptr, nullptr, nullptr, nullptr, nullptr, nullptr, nullptr);
        gemm_nt<3, false><<<dim3(PM / 128, PE / 128), blk, 0, stream>>>(
            query, Wk, bk, nullptr, kf, PM, PE, PE,
            nullptr, nullptr, nullptr, nullptr, nullptr, nullptr, nullptr);
        gemm_nt<4, false><<<dim3(PM / 128, PE / 128), blk, 0, stream>>>(
            query, Wv, bv, nullptr, vtf, PM, PE, PE,
            nullptr, nullptr, nullptr, nullptr, nullptr, nullptr, nullptr);
        gemm_nt<0, true><<<dim3(PM / 128, 256 / 128), blk, 0, stream>>>(
            query, Wm1, bm1, h1, nullptr, PM, 256, PE,
            nullptr, nullptr, nullptr, nullptr, nullptr, nullptr, nullptr);

        flash_mfma<<<dim3(PS / 128, PH, PB), blk, 0, stream>>>(
            qf32, kf, vtf, qf32);

        gemm_nt<2, false><<<dim3(PM / 128, PE / 128), blk, 0, stream>>>(
            h1, Wm2, bm2, attnf, nullptr, PM, PE, 256,
            qf32, dop, ser, nor, ach, asc, abi);
        gemm_nt<0, false><<<dim3(PM / 128, PE / 128), blk, 0, stream>>>(
            attnf, Wo, bo, out, nullptr, PM, PE, PE,
            nullptr, nullptr, nullptr, nullptr, nullptr, nullptr, nullptr);
    }
}

// Round 15
// 228.381 us; speedup vs baseline: 1.4138x; 1.3071x over previous
//
#include <hip/hip_runtime.h>
#include <hip/hip_bf16.h>
#include <cstdint>

// Problem constants
#define PB 4
#define PS 2048
#define PE 1024
#define PH 16
#define PD 64
#define PM (PB * PS)      // 8192 rows

typedef __attribute__((ext_vector_type(8))) _Float16 half8;  // 8 fp16 (4 VGPR)
typedef __attribute__((ext_vector_type(4))) float f32x4;

#define MFMAH __builtin_amdgcn_mfma_f32_16x16x32_f16

#define GLOAD_LDS(gp, lp) __builtin_amdgcn_global_load_lds(                    \
    (const __attribute__((address_space(1))) void*)(gp),                       \
    (__attribute__((address_space(3))) void*)(lp), 16, 0, 0)

#if __has_builtin(__builtin_amdgcn_exp2f)
#define FAST_EXP2 1
#else
#define FAST_EXP2 0
#endif

// fp32 -> fp16 RNE bit pattern
__device__ inline unsigned short h16(float x) {
    _Float16 h = (_Float16)x;
    unsigned short u;
    __builtin_memcpy(&u, &h, 2);
    return u;
}
// packed fp16 pair via v_cvt_pkrtz_f16_f32; returns the 32-bit word
__device__ inline unsigned pkrtz(float a, float b) {
    auto p = __builtin_amdgcn_cvt_pkrtz(a, b);   // __fp16 ext_vector(2)
    unsigned u;
    __builtin_memcpy(&u, &p, 4);
    return u;
}

// ---------------------------------------------------------------------------
// split_all: all 7 fp32 operands -> single fp16 planes, one launch.
// f4 ranges: query 2097152 | Wq/Wk/Wv/Wo 262144 each | Wm1/Wm2 65536 each.
// ---------------------------------------------------------------------------
__global__ __launch_bounds__(256)
void split_all(const float* __restrict__ q,   const float* __restrict__ wq,
               const float* __restrict__ wk,  const float* __restrict__ wv,
               const float* __restrict__ wo,  const float* __restrict__ wm1,
               const float* __restrict__ wm2,
               unsigned short* qh,  unsigned short* wqh, unsigned short* wkh,
               unsigned short* wvh, unsigned short* woh,
               unsigned short* m1h, unsigned short* m2h)
{
    const int b = blockIdx.x;
    const float* src; unsigned short* dst; int base;
    if      (b <  8192) { src = q;   dst = qh;  base = 0;     }
    else if (b <  9216) { src = wq;  dst = wqh; base = 8192;  }
    else if (b < 10240) { src = wk;  dst = wkh; base = 9216;  }
    else if (b < 11264) { src = wv;  dst = wvh; base = 10240; }
    else if (b < 12288) { src = wo;  dst = woh; base = 11264; }
    else if (b < 12544) { src = wm1; dst = m1h; base = 12288; }
    else                { src = wm2; dst = m2h; base = 12544; }
    const int i = (b - base) * 256 + threadIdx.x;
    float4 f = ((const float4*)src)[i];
    ushort4 h;
    h.x = h16(f.x); h.y = h16(f.y); h.z = h16(f.z); h.w = h16(f.w);
    ((ushort4*)dst)[i] = h;
}

// ---------------------------------------------------------------------------
// Plane-fed single-fp16 MFMA NT GEMM v3:
// A and B single fp16 planes [rows][K]. 1 MFMA per (mt,nt,kh) = 32/wave/step.
// Double-buffered LDS (2 bufs x [A16K + B16K] = 64KB), flash-v5 skeleton:
// ISSUE(next buf) -> compute(cur) -> one barrier. BK=64.
// 128x128 tile, 4 waves (2x2) of 64x64; lane(lq,lg) owns
// C[16mt+4lg+j][16nt+lq] per 16x16 subtile. XOR swizzle byte^(row&7)<<4,
// staged via global_load_lds with pre-swizzled per-lane source.
// MODE 0: fp32 C[m*N+n]            (optional RELU)
// MODE 1: fp32 at BHSD index       (Q projection)
// MODE 3: fp16 single at BHSD index        (K projection)
// MODE 4: fp16 single at BHDS + PV seq permutation (V^T)
// MODE 5: fp16 single plane [M][N] (h1, with RELU)
// MODE 6: neuromod combine -> fp16 single plane [M][N] (attnf)
// ---------------------------------------------------------------------------
template<int MODE, bool RELU>
__global__ __launch_bounds__(256, 2)
void gemm_pl(const unsigned short* __restrict__ Ah,
             const unsigned short* __restrict__ Bh,
             const float* __restrict__ bias, float* __restrict__ C,
             unsigned short* __restrict__ Oh,
             int M, int N, int K,
             const float* __restrict__ attn,
             const float* __restrict__ g0, const float* __restrict__ g1,
             const float* __restrict__ g2, const float* __restrict__ g3,
             const float* __restrict__ asc, const float* __restrict__ abi)
{
    __shared__ int4 ldsq[4096];                 // 64 KB = 2 bufs x 32 KB
    char* const lds = (char*)ldsq;

    const int tid  = threadIdx.x;
    const int lane = tid & 63;
    const int w    = tid >> 6;
    const int lq   = lane & 15;
    const int lg   = lane >> 4;
    const int wm   = (w >> 1) * 64;
    const int wn   = (w & 1) * 64;
    const int m0   = blockIdx.x * 128;
    const int n0   = blockIdx.y * 128;

    // staging roles: w0: A c0-7 | w1: A c8-15 | w2: B c0-7 | w3: B c8-15
    const unsigned short* const gp =
        (w < 2) ? Ah + (size_t)m0 * K : Bh + (size_t)n0 * K;
    const int pb    = (w < 2) ? 0 : 16384;
    const int ch0   = (w & 1) * 8;
    const int scol8 = (((lane & 7) ^ (lane >> 3)) << 3);   // pre-swizzled col
    const int lrow8 = lane >> 3;

    auto ISSUE = [&](int k0, int bufn) {
        #pragma unroll
        for (int r = 0; r < 8; ++r) {
            const int c   = ch0 + r;
            const int row = c * 8 + lrow8;
            GLOAD_LDS(gp + (size_t)row * K + k0 + scol8,
                      lds + bufn * 32768 + pb + c * 1024 + 16 * lane);
        }
    };

    f32x4 acc[4][4];
    #pragma unroll
    for (int mt = 0; mt < 4; ++mt)
        #pragma unroll
        for (int nt = 0; nt < 4; ++nt)
            acc[mt][nt] = (f32x4){0.f, 0.f, 0.f, 0.f};

    ISSUE(0, 0);
    __syncthreads();

    int buf = 0;
    for (int k0 = 0; k0 < K; k0 += 64) {
        if (k0 + 64 < K) ISSUE(k0 + 64, buf ^ 1);

        const char* const L = lds + buf * 32768;
        #pragma unroll
        for (int kh = 0; kh < 2; ++kh) {
            half8 af[4];
            #pragma unroll
            for (int mt = 0; mt < 4; ++mt) {
                const int row = wm + 16 * mt + lq;
                const int off = row * 128 + ((kh * 64 + 16 * lg) ^ ((row & 7) << 4));
                af[mt] = *(const half8*)(L + off);
            }
            #pragma unroll
            for (int nt = 0; nt < 4; ++nt) {
                const int row = wn + 16 * nt + lq;
                const int off = row * 128 + ((kh * 64 + 16 * lg) ^ ((row & 7) << 4));
                half8 bf = *(const half8*)(L + 16384 + off);
                #pragma unroll
                for (int mt = 0; mt < 4; ++mt)
                    acc[mt][nt] = MFMAH(af[mt], bf, acc[mt][nt], 0, 0, 0);
            }
        }
        __syncthreads();        // drains prefetch vmcnt + protects LDS reuse
        buf ^= 1;
    }

    float gain = 0.f, ascv = 0.f, abiv = 0.f;
    if (MODE == 6) {
        gain = 0.25f * (*g0 + *g1 + *g2 + *g3);
        ascv = *asc;
        abiv = *abi;
    }

    #pragma unroll
    for (int nt = 0; nt < 4; ++nt) {
        const int n  = n0 + wn + 16 * nt + lq;
        const float bv = bias[n];
        #pragma unroll
        for (int mt = 0; mt < 4; ++mt) {
            #pragma unroll
            for (int j = 0; j < 4; ++j) {
                const int m = m0 + wm + 16 * mt + 4 * lg + j;
                float v = acc[mt][nt][j] + bv;
                if (RELU) v = fmaxf(v, 0.f);
                if (MODE == 0) {
                    C[(size_t)m * N + n] = v;
                } else if (MODE == 1) {
                    const int b = m >> 11, s = m & 2047;
                    const int h = n >> 6, d = n & 63;
                    C[((size_t)(b * PH + h) * PS + s) * PD + d] = v;
                } else if (MODE == 3) {
                    const int b = m >> 11, s = m & 2047;
                    const int h = n >> 6, d = n & 63;
                    Oh[((size_t)(b * PH + h) * PS + s) * PD + d] = h16(v);
                } else if (MODE == 4) {
                    const int b = m >> 11;
                    const int h = n >> 6, d = n & 63;
                    const int scol = (m & 2047 & ~63) + ((mt & 1) << 5)
                                   + (lg << 3) + ((mt >> 1) << 2) + j;
                    Oh[((size_t)(b * PH + h) * PD + d) * PS + scol] = h16(v);
                } else if (MODE == 5) {
                    Oh[(size_t)m * N + n] = h16(v);
                } else { // MODE 6
                    const int b = m >> 11, s = m & 2047;
                    const int h = n >> 6, d = n & 63;
                    const float av = attn[((size_t)(b * PH + h) * PS + s) * PD + d];
                    const float o = (av * ascv + abiv) * (1.f + v * gain);
                    Oh[(size_t)m * N + n] = h16(o);
                }
            }
        }
    }
}

// ---------------------------------------------------------------------------
// fp32-fed fallback GEMM (bf16 3-term internally, round-5 proven skeleton);
// MODE 3/4 emit fp16 single planes for the fp16 flash.
// ---------------------------------------------------------------------------
typedef __attribute__((ext_vector_type(8))) short short8;
#define MFMA16 __builtin_amdgcn_mfma_f32_16x16x32_bf16
__device__ inline unsigned short bf16rn(float x) {
    unsigned u = __builtin_bit_cast(unsigned, x);
    u += 0x7FFFu + ((u >> 16) & 1u);
    return (unsigned short)(u >> 16);
}
__device__ inline float bf16tof(unsigned short h) {
    unsigned u = ((unsigned)h) << 16;
    return __builtin_bit_cast(float, u);
}
__device__ inline void split2(float x, unsigned short& h, unsigned short& l) {
    h = bf16rn(x);
    l = bf16rn(x - bf16tof(h));
}

template<int MODE, bool RELU>
__global__ __launch_bounds__(256, 2)
void gemm_nt(const float* __restrict__ A, const float* __restrict__ Bw,
             const float* __restrict__ bias, float* __restrict__ C,
             unsigned short* __restrict__ Ohi,
             int M, int N, int K,
             const float* __restrict__ attn,
             const float* __restrict__ g0, const float* __restrict__ g1,
             const float* __restrict__ g2, const float* __restrict__ g3,
             const float* __restrict__ asc, const float* __restrict__ abi)
{
    __shared__ int4 ldsq[4096];
    char* const lds = (char*)ldsq;

    const int tid  = threadIdx.x;
    const int lane = tid & 63;
    const int w    = tid >> 6;
    const int lq   = lane & 15;
    const int lg   = lane >> 4;
    const int wm   = (w >> 1) * 64;
    const int wn   = (w & 1) * 64;
    const int m0   = blockIdx.x * 128;
    const int n0   = blockIdx.y * 128;

    const int irow = tid >> 3;
    const int ic8  = (tid & 7) * 8;
    const int woff = (ic8 * 2);

    f32x4 acc[4][4];
    #pragma unroll
    for (int mt = 0; mt < 4; ++mt)
        #pragma unroll
        for (int nt = 0; nt < 4; ++nt)
            acc[mt][nt] = (f32x4){0.f, 0.f, 0.f, 0.f};

    for (int k0 = 0; k0 < K; k0 += 64) {
        #pragma unroll
        for (int mat = 0; mat < 2; ++mat) {
            const float* const src = mat ? Bw : A;
            const int rbase = mat ? n0 : m0;
            const int pbase = mat ? 32768 : 0;
            #pragma unroll
            for (int r = 0; r < 4; ++r) {
                const int row = irow + 32 * r;
                const float* p = src + (size_t)(rbase + row) * K + k0 + ic8;
                float4 f0 = *(const float4*)p;
                float4 f1 = *(const float4*)(p + 4);
                short8 vh, vl;
                {
                    unsigned short h, l;
                    split2(f0.x, h, l); vh[0] = (short)h; vl[0] = (short)l;
                    split2(f0.y, h, l); vh[1] = (short)h; vl[1] = (short)l;
                    split2(f0.z, h, l); vh[2] = (short)h; vl[2] = (short)l;
                    split2(f0.w, h, l); vh[3] = (short)h; vl[3] = (short)l;
                    split2(f1.x, h, l); vh[4] = (short)h; vl[4] = (short)l;
                    split2(f1.y, h, l); vh[5] = (short)h; vl[5] = (short)l;
                    split2(f1.z, h, l); vh[6] = (short)h; vl[6] = (short)l;
                    split2(f1.w, h, l); vh[7] = (short)h; vl[7] = (short)l;
                }
                const int off = row * 128 + (woff ^ ((row & 7) << 4));
                *(short8*)(lds + pbase + off)         = vh;
                *(short8*)(lds + pbase + 16384 + off) = vl;
            }
        }
        __syncthreads();

        #pragma unroll
        for (int kh = 0; kh < 2; ++kh) {
            short8 afh[4], afl[4];
            #pragma unroll
            for (int mt = 0; mt < 4; ++mt) {
                const int row = wm + 16 * mt + lq;
                const int off = row * 128 + ((kh * 64 + 16 * lg) ^ ((row & 7) << 4));
                afh[mt] = *(const short8*)(lds + off);
                afl[mt] = *(const short8*)(lds + 16384 + off);
            }
            #pragma unroll
            for (int nt = 0; nt < 4; ++nt) {
                const int row = wn + 16 * nt + lq;
                const int off = row * 128 + ((kh * 64 + 16 * lg) ^ ((row & 7) << 4));
                short8 bfh = *(const short8*)(lds + 32768 + off);
                short8 bfl = *(const short8*)(lds + 49152 + off);
                #pragma unroll
                for (int mt = 0; mt < 4; ++mt) {
                    acc[mt][nt] = MFMA16(afh[mt], bfh, acc[mt][nt], 0, 0, 0);
                    acc[mt][nt] = MFMA16(afh[mt], bfl, acc[mt][nt], 0, 0, 0);
                    acc[mt][nt] = MFMA16(afl[mt], bfh, acc[mt][nt], 0, 0, 0);
                }
            }
        }
        __syncthreads();
    }

    float gain = 0.f, ascv = 0.f, abiv = 0.f;
    if (MODE == 2) {
        gain = 0.25f * (*g0 + *g1 + *g2 + *g3);
        ascv = *asc;
        abiv = *abi;
    }

    #pragma unroll
    for (int nt = 0; nt < 4; ++nt) {
        const int n  = n0 + wn + 16 * nt + lq;
        const float bv = bias[n];
        #pragma unroll
        for (int mt = 0; mt < 4; ++mt) {
            #pragma unroll
            for (int j = 0; j < 4; ++j) {
                const int m = m0 + wm + 16 * mt + 4 * lg + j;
                float v = acc[mt][nt][j] + bv;
                if (RELU) v = fmaxf(v, 0.f);
                if (MODE == 0) {
                    C[(size_t)m * N + n] = v;
                } else if (MODE == 1) {
                    const int b = m >> 11, s = m & 2047;
                    const int h = n >> 6, d = n & 63;
                    C[((size_t)(b * PH + h) * PS + s) * PD + d] = v;
                } else if (MODE == 3) {
                    const int b = m >> 11, s = m & 2047;
                    const int h = n >> 6, d = n & 63;
                    Ohi[((size_t)(b * PH + h) * PS + s) * PD + d] = h16(v);
                } else if (MODE == 4) {
                    const int b = m >> 11;
                    const int h = n >> 6, d = n & 63;
                    const int scol = (m & 2047 & ~63) + ((mt & 1) << 5)
                                   + (lg << 3) + ((mt >> 1) << 2) + j;
                    Ohi[((size_t)(b * PH + h) * PD + d) * PS + scol] = h16(v);
                } else { // MODE 2
                    const int b = m >> 11, s = m & 2047;
                    const int h = n >> 6, d = n & 63;
                    const float av = attn[((size_t)(b * PH + h) * PS + s) * PD + d];
                    C[(size_t)m * N + n] = (av * ascv + abiv) * (1.f + v * gain);
                }
            }
        }
    }
}

// ---------------------------------------------------------------------------
// MFMA flash attention v9 (unchanged from round 14 — 98us, proven):
// Q single fp16 (QK^T 2 MFMA/mt/u), K/V^T single fp16 planes, P fp16 via
// v_cvt_pkrtz, exp via __builtin_amdgcn_exp2f, l via MFMA(ones,P),
// defer-max, XCD swizzle, gload_lds staging w/ pre-swizzled source.
// ---------------------------------------------------------------------------
__global__ __launch_bounds__(256, 2)
void flash_mfma(const float* qf,
                const unsigned short* __restrict__ kf,
                const unsigned short* __restrict__ vtf,
                float* attn)
{
    __shared__ int4 ldsv[2048];                    // 32 KB: 2 bufs x (K8K + V8K)
    char* const ldsb = (char*)ldsv;

    const int tid  = threadIdx.x;
    const int lane = tid & 63;
    const int w    = tid >> 6;
    const int lq   = lane & 15;
    const int lg   = lane >> 4;

    // XCD swizzle: each XCD owns 128 consecutive logical blocks (= 8 bh).
    const int L  = blockIdx.x + (blockIdx.y << 4) + (blockIdx.z << 8);
    const int nL = ((L & 7) << 7) + (L >> 3);
    const int bh = nL >> 4;
    const int q0 = (nL & 15) * 128 + w * 32;

    const size_t kbase = (size_t)bh * PS * PD;   // K rows   [S][D]
    const size_t vbase = (size_t)bh * PD * PS;   // V^T rows [D][S] (permuted)

    const unsigned short* const gp = (w < 2) ? kf + kbase : vtf + vbase;
    const bool isK = (w < 2);
    const int ch0   = (w & 1) * 4;
    const int scol8 = (((lane & 7) ^ (lane >> 3)) << 3);   // pre-swizzled col
    const int lrow8 = lane >> 3;

    auto ISSUE = [&](int kt, int bufn) {
        #pragma unroll
        for (int r = 0; r < 4; ++r) {
            const int c   = ch0 + r;
            const int row = c * 8 + lrow8;
            const size_t goff = isK ? (size_t)(kt + row) * PD + scol8
                                    : (size_t)row * PS + kt + scol8;
            GLOAD_LDS(gp + goff,
                      ldsb + bufn * 16384 + (isK ? 0 : 8192) + c * 1024 + 16 * lane);
        }
    };

    const half8 onesh = {(_Float16)1.f, (_Float16)1.f, (_Float16)1.f,
                         (_Float16)1.f, (_Float16)1.f, (_Float16)1.f,
                         (_Float16)1.f, (_Float16)1.f};

#if FAST_EXP2
    const float QSCALE = 0.125f * 1.4426950408889634f;   // exp2 domain
    const float THR    = 11.5415603f;                    // 8*log2(e)
#define EXP_P(x) __builtin_amdgcn_exp2f(x)
#else
    const float QSCALE = 0.125f;                         // natural domain
    const float THR    = 8.f;
#define EXP_P(x) __expf(x)
#endif

    // ---- Q fragments: SINGLE fp16, scale folded in
    half8 qh[2][2];
    #pragma unroll
    for (int u = 0; u < 2; ++u) {
        const float* qp = qf + ((size_t)bh * PS + q0 + 16 * u + lq) * PD + 8 * lg;
        #pragma unroll
        for (int t = 0; t < 2; ++t)
            #pragma unroll
            for (int b = 0; b < 8; ++b)
                qh[u][t][b] = (_Float16)(qp[t * 32 + b] * QSCALE);
    }

    f32x4 ot[2][4];
    #pragma unroll
    for (int u = 0; u < 2; ++u)
        #pragma unroll
        for (int mt = 0; mt < 4; ++mt)
            ot[u][mt] = (f32x4){0.f, 0.f, 0.f, 0.f};
    f32x4 lacc[2] = {{0.f,0.f,0.f,0.f}, {0.f,0.f,0.f,0.f}};
    float m_run[2] = {-3.0e38f, -3.0e38f};

    ISSUE(0, 0);
    __syncthreads();

    int buf = 0;
    for (int kti = 0; kti < PS / 64; ++kti) {
        const bool pf = (kti + 1 < PS / 64);
        if (pf) ISSUE((kti + 1) * 64, buf ^ 1);

        const char* const L2 = ldsb + buf * 16384;

        // ---- S^T tiles, Q single fp16: 2 MFMA per mt/u
        f32x4 st[2][4];
        #pragma unroll
        for (int mt = 0; mt < 4; ++mt) {
            const int row = 16 * mt + lq;
            const int swz = (row & 7) << 4;
            const char* kr = L2 + row * 128;
            half8 a0 = *(const half8*)(kr + ((16 * lg) ^ swz));
            half8 a1 = *(const half8*)(kr + ((64 + 16 * lg) ^ swz));
            #pragma unroll
            for (int u = 0; u < 2; ++u) {
                f32x4 acc = {0.f, 0.f, 0.f, 0.f};
                acc = MFMAH(a0, qh[u][0], acc, 0, 0, 0);
                acc = MFMAH(a1, qh[u][1], acc, 0, 0, 0);
                st[u][mt] = acc;
            }
        }

        // ---- online softmax (defer-max) + P pack (pkrtz) + l via MFMA
        half8 pb[2][2];
        #pragma unroll
        for (int u = 0; u < 2; ++u) {
            float a0 = fmaxf(fmaxf(st[u][0][0], st[u][0][1]), st[u][0][2]);
            float a1 = fmaxf(fmaxf(st[u][0][3], st[u][1][0]), st[u][1][1]);
            float a2 = fmaxf(fmaxf(st[u][1][2], st[u][1][3]), st[u][2][0]);
            float a3 = fmaxf(fmaxf(st[u][2][1], st[u][2][2]), st[u][2][3]);
            float a4 = fmaxf(fmaxf(st[u][3][0], st[u][3][1]), st[u][3][2]);
            float b0 = fmaxf(fmaxf(a0, a1), a2);
            float b1 = fmaxf(fmaxf(a3, a4), st[u][3][3]);
            float pmax = fmaxf(b0, b1);
            pmax = fmaxf(pmax, __shfl_xor(pmax, 16));
            pmax = fmaxf(pmax, __shfl_xor(pmax, 32));
            if (!__all(pmax - m_run[u] <= THR)) {   // rare: rescale path
                float mnew = fmaxf(m_run[u], pmax);
                float corr = EXP_P(m_run[u] - mnew);
                m_run[u] = mnew;
                #pragma unroll
                for (int j = 0; j < 4; ++j)
                    lacc[u][j] *= corr;
                #pragma unroll
                for (int mt = 0; mt < 4; ++mt)
                    #pragma unroll
                    for (int j = 0; j < 4; ++j)
                        ot[u][mt][j] *= corr;
            }
            #pragma unroll
            for (int mt = 0; mt < 4; ++mt)
                #pragma unroll
                for (int j = 0; j < 4; ++j)
                    st[u][mt][j] = EXP_P(st[u][mt][j] - m_run[u]);
            #pragma unroll
            for (int t = 0; t < 2; ++t) {
                unsigned w0 = pkrtz(st[u][t][0],     st[u][t][1]);
                unsigned w1 = pkrtz(st[u][t][2],     st[u][t][3]);
                unsigned w2 = pkrtz(st[u][t + 2][0], st[u][t + 2][1]);
                unsigned w3 = pkrtz(st[u][t + 2][2], st[u][t + 2][3]);
                uint4 pw = make_uint4(w0, w1, w2, w3);
                __builtin_memcpy(&pb[u][t], &pw, 16);
            }
            lacc[u] = MFMAH(onesh, pb[u][0], lacc[u], 0, 0, 0);
            lacc[u] = MFMAH(onesh, pb[u][1], lacc[u], 0, 0, 0);
        }

        // ---- O^T += V^T . P^T   (V single fp16, P fp16: 1 MFMA each)
        #pragma unroll
        for (int t = 0; t < 2; ++t) {
            #pragma unroll
            for (int mt = 0; mt < 4; ++mt) {
                const int row = 16 * mt + lq;
                const int swz = (row & 7) << 4;
                const char* vr = L2 + 8192 + row * 128;
                half8 vv = *(const half8*)(vr + ((t * 64 + 16 * lg) ^ swz));
                #pragma unroll
                for (int u = 0; u < 2; ++u)
                    ot[u][mt] = MFMAH(vv, pb[u][t], ot[u][mt], 0, 0, 0);
            }
        }

        __syncthreads();        // drains prefetch vmcnt + protects LDS reuse
        buf ^= 1;
    }

    // ---- epilogue: attn[bh][q0+16u+lq][d], d = 16*mt + 4*lg + j
    #pragma unroll
    for (int u = 0; u < 2; ++u) {
        const float inv = 1.f / lacc[u][0];
        float* op = attn + ((size_t)bh * PS + q0 + 16 * u + lq) * PD + 4 * lg;
        #pragma unroll
        for (int mt = 0; mt < 4; ++mt) {
            float4 o;
            o.x = ot[u][mt][0] * inv; o.y = ot[u][mt][1] * inv;
            o.z = ot[u][mt][2] * inv; o.w = ot[u][mt][3] * inv;
            *(float4*)(op + 16 * mt) = o;
        }
    }
}

// ---------------------------------------------------------------------------
extern "C" void kernel_launch(void* const* d_in, const int* in_sizes, int n_in,
                              void* d_out, int out_size, void* d_ws, size_t ws_size,
                              hipStream_t stream)
{
    const float* query = (const float*)d_in[0];
    const float* Wq  = (const float*)d_in[1];  const float* bq  = (const float*)d_in[2];
    const float* Wk  = (const float*)d_in[3];  const float* bk  = (const float*)d_in[4];
    const float* Wv  = (const float*)d_in[5];  const float* bv  = (const float*)d_in[6];
    const float* Wo  = (const float*)d_in[7];  const float* bo  = (const float*)d_in[8];
    const float* Wm1 = (const float*)d_in[9];  const float* bm1 = (const float*)d_in[10];
    const float* Wm2 = (const float*)d_in[11]; const float* bm2 = (const float*)d_in[12];
    const float* dop = (const float*)d_in[13];
    const float* ser = (const float*)d_in[14];
    const float* nor = (const float*)d_in[15];
    const float* ach = (const float*)d_in[16];
    const float* asc = (const float*)d_in[17];
    const float* abi = (const float*)d_in[18];
    float* out = (float*)d_out;

    char* wsb = (char*)d_ws;
    // Common: qf32 [0,32M), kf fp16 [32M,48M), vtf fp16 [48M,64M)
    float*          qf32 = (float*)wsb;
    unsigned short* kf   = (unsigned short*)(wsb + (32u << 20));
    unsigned short* vtf  = (unsigned short*)(wsb + (48u << 20));

    dim3 blk(256);
    const bool presplit = (ws_size >= 161480704ull);             // 154 MB

    if (presplit) {
        unsigned short* h1h   = (unsigned short*)(wsb + (64u << 20));  // 4MB
        unsigned short* afh   = (unsigned short*)(wsb + (72u << 20));  // 16MB
        unsigned short* qh    = (unsigned short*)(wsb + (104u << 20)); // 16MB
        unsigned short* wqh   = (unsigned short*)(wsb + (136u << 20)); // 2MB
        unsigned short* wkh   = (unsigned short*)(wsb + (138u << 20));
        unsigned short* wvh   = (unsigned short*)(wsb + (140u << 20));
        unsigned short* woh   = (unsigned short*)(wsb + (142u << 20));
        unsigned short* m1h   = (unsigned short*)(wsb + (144u << 20)); // 0.5MB
        unsigned short* m2h   = (unsigned short*)(wsb + (145u << 20));

        split_all<<<12800, blk, 0, stream>>>(
            query, Wq, Wk, Wv, Wo, Wm1, Wm2,
            qh, wqh, wkh, wvh, woh, m1h, m2h);

        gemm_pl<1, false><<<dim3(PM / 128, PE / 128), blk, 0, stream>>>(
            qh, wqh, bq, qf32, nullptr, PM, PE, PE,
            nullptr, nullptr, nullptr, nullptr, nullptr, nullptr, nullptr);
        gemm_pl<3, false><<<dim3(PM / 128, PE / 128), blk, 0, stream>>>(
            qh, wkh, bk, nullptr, kf, PM, PE, PE,
            nullptr, nullptr, nullptr, nullptr, nullptr, nullptr, nullptr);
        gemm_pl<4, false><<<dim3(PM / 128, PE / 128), blk, 0, stream>>>(
            qh, wvh, bv, nullptr, vtf, PM, PE, PE,
            nullptr, nullptr, nullptr, nullptr, nullptr, nullptr, nullptr);
        gemm_pl<5, true><<<dim3(PM / 128, 256 / 128), blk, 0, stream>>>(
            qh, m1h, bm1, nullptr, h1h, PM, 256, PE,
            nullptr, nullptr, nullptr, nullptr, nullptr, nullptr, nullptr);

        flash_mfma<<<dim3(PS / 128, PH, PB), blk, 0, stream>>>(
            qf32, kf, vtf, qf32);

        gemm_pl<6, false><<<dim3(PM / 128, PE / 128), blk, 0, stream>>>(
            h1h, m2h, bm2, nullptr, afh, PM, PE, 256,
            qf32, dop, ser, nor, ach, asc, abi);
        gemm_pl<0, false><<<dim3(PM / 128, PE / 128), blk, 0, stream>>>(
            afh, woh, bo, out, nullptr, PM, PE, PE,
            nullptr, nullptr, nullptr, nullptr, nullptr, nullptr, nullptr);
    } else {
        // fallback: fp32-fed bf16 3-term GEMMs + fp16 flash
        float* h1    = (float*)(wsb + (64u << 20));   // 8MB
        float* attnf = (float*)(wsb + (72u << 20));   // 32MB

        gemm_nt<1, false><<<dim3(PM / 128, PE / 128), blk, 0, stream>>>(
            query, Wq, bq, qf32, nullptr, PM, PE, PE,
            nullptr, nullptr, nullptr, nullptr, nullptr, nullptr, nullptr);
        gemm_nt<3, false><<<dim3(PM / 128, PE / 128), blk, 0, stream>>>(
            query, Wk, bk, nullptr, kf, PM, PE, PE,
            nullptr, nullptr, nullptr, nullptr, nullptr, nullptr, nullptr);
        gemm_nt<4, false><<<dim3(PM / 128, PE / 128), blk, 0, stream>>>(
            query, Wv, bv, nullptr, vtf, PM, PE, PE,
            nullptr, nullptr, nullptr, nullptr, nullptr, nullptr, nullptr);
        gemm_nt<0, true><<<dim3(PM / 128, 256 / 128), blk, 0, stream>>>(
            query, Wm1, bm1, h1, nullptr, PM, 256, PE,
            nullptr, nullptr, nullptr, nullptr, nullptr, nullptr, nullptr);

        flash_mfma<<<dim3(PS / 128, PH, PB), blk, 0, stream>>>(
            qf32, kf, vtf, qf32);

        gemm_nt<2, false><<<dim3(PM / 128, PE / 128), blk, 0, stream>>>(
            h1, Wm2, bm2, attnf, nullptr, PM, PE, 256,
            qf32, dop, ser, nor, ach, asc, abi);
        gemm_nt<0, false><<<dim3(PM / 128, PE / 128), blk, 0, stream>>>(
            attnf, Wo, bo, out, nullptr, PM, PE, PE,
            nullptr, nullptr, nullptr, nullptr, nullptr, nullptr, nullptr);
    }
}

// Round 16
// 223.394 us; speedup vs baseline: 1.4454x; 1.0223x over previous
//
#include <hip/hip_runtime.h>
#include <hip/hip_bf16.h>
#include <cstdint>

// Problem constants
#define PB 4
#define PS 2048
#define PE 1024
#define PH 16
#define PD 64
#define PM (PB * PS)      // 8192 rows

typedef __attribute__((ext_vector_type(8))) _Float16 half8;  // 8 fp16 (4 VGPR)
typedef __attribute__((ext_vector_type(4))) float f32x4;

#define MFMAH __builtin_amdgcn_mfma_f32_16x16x32_f16

#define GLOAD_LDS(gp, lp) __builtin_amdgcn_global_load_lds(                    \
    (const __attribute__((address_space(1))) void*)(gp),                       \
    (__attribute__((address_space(3))) void*)(lp), 16, 0, 0)

#if __has_builtin(__builtin_amdgcn_exp2f)
#define FAST_EXP2 1
#else
#define FAST_EXP2 0
#endif

// fp32 -> fp16 RNE bit pattern
__device__ inline unsigned short h16(float x) {
    _Float16 h = (_Float16)x;
    unsigned short u;
    __builtin_memcpy(&u, &h, 2);
    return u;
}
// packed fp16 pair via v_cvt_pkrtz_f16_f32; returns the 32-bit word
__device__ inline unsigned pkrtz(float a, float b) {
    auto p = __builtin_amdgcn_cvt_pkrtz(a, b);   // __fp16 ext_vector(2)
    unsigned u;
    __builtin_memcpy(&u, &p, 4);
    return u;
}

// ---------------------------------------------------------------------------
// split_all: all 7 fp32 operands -> single fp16 planes, one launch.
// f4 ranges: query 2097152 | Wq/Wk/Wv/Wo 262144 each | Wm1/Wm2 65536 each.
// ---------------------------------------------------------------------------
__global__ __launch_bounds__(256)
void split_all(const float* __restrict__ q,   const float* __restrict__ wq,
               const float* __restrict__ wk,  const float* __restrict__ wv,
               const float* __restrict__ wo,  const float* __restrict__ wm1,
               const float* __restrict__ wm2,
               unsigned short* qh,  unsigned short* wqh, unsigned short* wkh,
               unsigned short* wvh, unsigned short* woh,
               unsigned short* m1h, unsigned short* m2h)
{
    const int b = blockIdx.x;
    const float* src; unsigned short* dst; int base;
    if      (b <  8192) { src = q;   dst = qh;  base = 0;     }
    else if (b <  9216) { src = wq;  dst = wqh; base = 8192;  }
    else if (b < 10240) { src = wk;  dst = wkh; base = 9216;  }
    else if (b < 11264) { src = wv;  dst = wvh; base = 10240; }
    else if (b < 12288) { src = wo;  dst = woh; base = 11264; }
    else if (b < 12544) { src = wm1; dst = m1h; base = 12288; }
    else                { src = wm2; dst = m2h; base = 12544; }
    const int i = (b - base) * 256 + threadIdx.x;
    float4 f = ((const float4*)src)[i];
    ushort4 h;
    h.x = h16(f.x); h.y = h16(f.y); h.z = h16(f.z); h.w = h16(f.w);
    ((ushort4*)dst)[i] = h;
}

// ---------------------------------------------------------------------------
// Fused QKV projection: one 128x128 tile computes Q, K and V outputs.
// 512 threads = 8 waves (wr=w>>2 in 0..1 rows 64, wc=w&3 cols 32/output).
// Per K-step (BK=64): stage A + Wq + Wk + Wv tiles (4 x 16KB planes) into
// double-buffered 128KB LDS via global_load_lds w/ pre-swizzled source;
// ISSUE(next) -> 48 MFMA/wave -> one barrier (flash-v5 skeleton).
// acc[3][4][2] f32x4 = 96 VGPR. Epilogues: Q fp32 BHSD, K fp16 BHSD,
// V fp16 BHDS with PV seq permutation (in-tile row = 16mt+4lg+j).
// ---------------------------------------------------------------------------
__global__ __launch_bounds__(512, 2)
void gemm_qkv(const unsigned short* __restrict__ Ah,
              const unsigned short* __restrict__ Wqh,
              const unsigned short* __restrict__ Wkh,
              const unsigned short* __restrict__ Wvh,
              const float* __restrict__ bq, const float* __restrict__ bk,
              const float* __restrict__ bv,
              float* __restrict__ qf32, unsigned short* __restrict__ kf,
              unsigned short* __restrict__ vtf)
{
    __shared__ int4 ldsq[8192];                 // 128 KB = 2 bufs x 4 planes
    char* const lds = (char*)ldsq;
    const int K = PE;

    const int tid  = threadIdx.x;
    const int lane = tid & 63;
    const int w    = tid >> 6;
    const int lq   = lane & 15;
    const int lg   = lane >> 4;
    const int wr   = w >> 2;                    // 0..1 (64-row half)
    const int wc   = w & 3;                     // 0..3 (32-col quarter)
    const int m0   = blockIdx.x * 128;
    const int n0   = blockIdx.y * 128;

    // staging: wave w stages plane w>>1 (0:A 1:Wq 2:Wk 3:Wv), half (w&1)
    const int plane = w >> 1;
    const unsigned short* const gp =
        (plane == 0) ? Ah  + (size_t)m0 * K :
        (plane == 1) ? Wqh + (size_t)n0 * K :
        (plane == 2) ? Wkh + (size_t)n0 * K :
                       Wvh + (size_t)n0 * K;
    const int pbase = plane * 16384;
    const int ch0   = (w & 1) * 8;
    const int scol8 = (((lane & 7) ^ (lane >> 3)) << 3);   // pre-swizzled col
    const int lrow8 = lane >> 3;

    auto ISSUE = [&](int k0, int bufn) {
        #pragma unroll
        for (int r = 0; r < 8; ++r) {
            const int c   = ch0 + r;
            const int row = c * 8 + lrow8;
            GLOAD_LDS(gp + (size_t)row * K + k0 + scol8,
                      lds + bufn * 65536 + pbase + c * 1024 + 16 * lane);
        }
    };

    f32x4 acc[3][4][2];
    #pragma unroll
    for (int o = 0; o < 3; ++o)
        #pragma unroll
        for (int mt = 0; mt < 4; ++mt)
            #pragma unroll
            for (int nt = 0; nt < 2; ++nt)
                acc[o][mt][nt] = (f32x4){0.f, 0.f, 0.f, 0.f};

    ISSUE(0, 0);
    __syncthreads();

    int buf = 0;
    for (int k0 = 0; k0 < K; k0 += 64) {
        if (k0 + 64 < K) ISSUE(k0 + 64, buf ^ 1);

        const char* const L = lds + buf * 65536;
        #pragma unroll
        for (int kh = 0; kh < 2; ++kh) {
            half8 af[4];
            #pragma unroll
            for (int mt = 0; mt < 4; ++mt) {
                const int row = 64 * wr + 16 * mt + lq;
                const int off = row * 128 + ((kh * 64 + 16 * lg) ^ ((row & 7) << 4));
                af[mt] = *(const half8*)(L + off);
            }
            #pragma unroll
            for (int o = 0; o < 3; ++o) {
                #pragma unroll
                for (int nt = 0; nt < 2; ++nt) {
                    const int row = 32 * wc + 16 * nt + lq;
                    const int off = row * 128 + ((kh * 64 + 16 * lg) ^ ((row & 7) << 4));
                    half8 bf = *(const half8*)(L + 16384 * (o + 1) + off);
                    #pragma unroll
                    for (int mt = 0; mt < 4; ++mt)
                        acc[o][mt][nt] = MFMAH(af[mt], bf, acc[o][mt][nt], 0, 0, 0);
                }
            }
        }
        __syncthreads();        // drains prefetch vmcnt + protects LDS reuse
        buf ^= 1;
    }

    // ---- epilogues
    #pragma unroll
    for (int nt = 0; nt < 2; ++nt) {
        const int n = n0 + 32 * wc + 16 * nt + lq;
        const int h = n >> 6, d = n & 63;
        const float bqv = bq[n], bkv = bk[n], bvv = bv[n];
        #pragma unroll
        for (int mt = 0; mt < 4; ++mt) {
            #pragma unroll
            for (int j = 0; j < 4; ++j) {
                const int m = m0 + 64 * wr + 16 * mt + 4 * lg + j;
                const int b = m >> 11, s = m & 2047;
                // Q: fp32 BHSD
                qf32[((size_t)(b * PH + h) * PS + s) * PD + d] =
                    acc[0][mt][nt][j] + bqv;
                // K: fp16 BHSD
                kf[((size_t)(b * PH + h) * PS + s) * PD + d] =
                    h16(acc[1][mt][nt][j] + bkv);
                // V^T: fp16 BHDS with PV permutation (in-tile r = 16mt+4lg+j)
                const int scol = (s & ~63) + ((mt & 1) << 5) + (lg << 3)
                               + ((mt >> 1) << 2) + j;
                vtf[((size_t)(b * PH + h) * PD + d) * PS + scol] =
                    h16(acc[2][mt][nt][j] + bvv);
            }
        }
    }
}

// ---------------------------------------------------------------------------
// Plane-fed single-fp16 MFMA NT GEMM (round-15 proven engine, unchanged).
// MODE 0: fp32 C[m*N+n] (optional RELU) | MODE 5: fp16 plane [M][N] (RELU)
// MODE 6: neuromod combine -> fp16 plane [M][N]
// ---------------------------------------------------------------------------
template<int MODE, bool RELU>
__global__ __launch_bounds__(256, 2)
void gemm_pl(const unsigned short* __restrict__ Ah,
             const unsigned short* __restrict__ Bh,
             const float* __restrict__ bias, float* __restrict__ C,
             unsigned short* __restrict__ Oh,
             int M, int N, int K,
             const float* __restrict__ attn,
             const float* __restrict__ g0, const float* __restrict__ g1,
             const float* __restrict__ g2, const float* __restrict__ g3,
             const float* __restrict__ asc, const float* __restrict__ abi)
{
    __shared__ int4 ldsq[4096];                 // 64 KB = 2 bufs x 32 KB
    char* const lds = (char*)ldsq;

    const int tid  = threadIdx.x;
    const int lane = tid & 63;
    const int w    = tid >> 6;
    const int lq   = lane & 15;
    const int lg   = lane >> 4;
    const int wm   = (w >> 1) * 64;
    const int wn   = (w & 1) * 64;
    const int m0   = blockIdx.x * 128;
    const int n0   = blockIdx.y * 128;

    const unsigned short* const gp =
        (w < 2) ? Ah + (size_t)m0 * K : Bh + (size_t)n0 * K;
    const int pb    = (w < 2) ? 0 : 16384;
    const int ch0   = (w & 1) * 8;
    const int scol8 = (((lane & 7) ^ (lane >> 3)) << 3);
    const int lrow8 = lane >> 3;

    auto ISSUE = [&](int k0, int bufn) {
        #pragma unroll
        for (int r = 0; r < 8; ++r) {
            const int c   = ch0 + r;
            const int row = c * 8 + lrow8;
            GLOAD_LDS(gp + (size_t)row * K + k0 + scol8,
                      lds + bufn * 32768 + pb + c * 1024 + 16 * lane);
        }
    };

    f32x4 acc[4][4];
    #pragma unroll
    for (int mt = 0; mt < 4; ++mt)
        #pragma unroll
        for (int nt = 0; nt < 4; ++nt)
            acc[mt][nt] = (f32x4){0.f, 0.f, 0.f, 0.f};

    ISSUE(0, 0);
    __syncthreads();

    int buf = 0;
    for (int k0 = 0; k0 < K; k0 += 64) {
        if (k0 + 64 < K) ISSUE(k0 + 64, buf ^ 1);

        const char* const L = lds + buf * 32768;
        #pragma unroll
        for (int kh = 0; kh < 2; ++kh) {
            half8 af[4];
            #pragma unroll
            for (int mt = 0; mt < 4; ++mt) {
                const int row = wm + 16 * mt + lq;
                const int off = row * 128 + ((kh * 64 + 16 * lg) ^ ((row & 7) << 4));
                af[mt] = *(const half8*)(L + off);
            }
            #pragma unroll
            for (int nt = 0; nt < 4; ++nt) {
                const int row = wn + 16 * nt + lq;
                const int off = row * 128 + ((kh * 64 + 16 * lg) ^ ((row & 7) << 4));
                half8 bf = *(const half8*)(L + 16384 + off);
                #pragma unroll
                for (int mt = 0; mt < 4; ++mt)
                    acc[mt][nt] = MFMAH(af[mt], bf, acc[mt][nt], 0, 0, 0);
            }
        }
        __syncthreads();
        buf ^= 1;
    }

    float gain = 0.f, ascv = 0.f, abiv = 0.f;
    if (MODE == 6) {
        gain = 0.25f * (*g0 + *g1 + *g2 + *g3);
        ascv = *asc;
        abiv = *abi;
    }

    #pragma unroll
    for (int nt = 0; nt < 4; ++nt) {
        const int n  = n0 + wn + 16 * nt + lq;
        const float bv = bias[n];
        #pragma unroll
        for (int mt = 0; mt < 4; ++mt) {
            #pragma unroll
            for (int j = 0; j < 4; ++j) {
                const int m = m0 + wm + 16 * mt + 4 * lg + j;
                float v = acc[mt][nt][j] + bv;
                if (RELU) v = fmaxf(v, 0.f);
                if (MODE == 0) {
                    C[(size_t)m * N + n] = v;
                } else if (MODE == 5) {
                    Oh[(size_t)m * N + n] = h16(v);
                } else { // MODE 6
                    const int b = m >> 11, s = m & 2047;
                    const int h = n >> 6, d = n & 63;
                    const float av = attn[((size_t)(b * PH + h) * PS + s) * PD + d];
                    const float o = (av * ascv + abiv) * (1.f + v * gain);
                    Oh[(size_t)m * N + n] = h16(o);
                }
            }
        }
    }
}

// ---------------------------------------------------------------------------
// fp32-fed fallback GEMM (bf16 3-term internally, round-5 proven skeleton);
// MODE 3/4 emit fp16 single planes for the fp16 flash.
// ---------------------------------------------------------------------------
typedef __attribute__((ext_vector_type(8))) short short8;
#define MFMA16 __builtin_amdgcn_mfma_f32_16x16x32_bf16
__device__ inline unsigned short bf16rn(float x) {
    unsigned u = __builtin_bit_cast(unsigned, x);
    u += 0x7FFFu + ((u >> 16) & 1u);
    return (unsigned short)(u >> 16);
}
__device__ inline float bf16tof(unsigned short h) {
    unsigned u = ((unsigned)h) << 16;
    return __builtin_bit_cast(float, u);
}
__device__ inline void split2(float x, unsigned short& h, unsigned short& l) {
    h = bf16rn(x);
    l = bf16rn(x - bf16tof(h));
}

template<int MODE, bool RELU>
__global__ __launch_bounds__(256, 2)
void gemm_nt(const float* __restrict__ A, const float* __restrict__ Bw,
             const float* __restrict__ bias, float* __restrict__ C,
             unsigned short* __restrict__ Ohi,
             int M, int N, int K,
             const float* __restrict__ attn,
             const float* __restrict__ g0, const float* __restrict__ g1,
             const float* __restrict__ g2, const float* __restrict__ g3,
             const float* __restrict__ asc, const float* __restrict__ abi)
{
    __shared__ int4 ldsq[4096];
    char* const lds = (char*)ldsq;

    const int tid  = threadIdx.x;
    const int lane = tid & 63;
    const int w    = tid >> 6;
    const int lq   = lane & 15;
    const int lg   = lane >> 4;
    const int wm   = (w >> 1) * 64;
    const int wn   = (w & 1) * 64;
    const int m0   = blockIdx.x * 128;
    const int n0   = blockIdx.y * 128;

    const int irow = tid >> 3;
    const int ic8  = (tid & 7) * 8;
    const int woff = (ic8 * 2);

    f32x4 acc[4][4];
    #pragma unroll
    for (int mt = 0; mt < 4; ++mt)
        #pragma unroll
        for (int nt = 0; nt < 4; ++nt)
            acc[mt][nt] = (f32x4){0.f, 0.f, 0.f, 0.f};

    for (int k0 = 0; k0 < K; k0 += 64) {
        #pragma unroll
        for (int mat = 0; mat < 2; ++mat) {
            const float* const src = mat ? Bw : A;
            const int rbase = mat ? n0 : m0;
            const int pbase = mat ? 32768 : 0;
            #pragma unroll
            for (int r = 0; r < 4; ++r) {
                const int row = irow + 32 * r;
                const float* p = src + (size_t)(rbase + row) * K + k0 + ic8;
                float4 f0 = *(const float4*)p;
                float4 f1 = *(const float4*)(p + 4);
                short8 vh, vl;
                {
                    unsigned short h, l;
                    split2(f0.x, h, l); vh[0] = (short)h; vl[0] = (short)l;
                    split2(f0.y, h, l); vh[1] = (short)h; vl[1] = (short)l;
                    split2(f0.z, h, l); vh[2] = (short)h; vl[2] = (short)l;
                    split2(f0.w, h, l); vh[3] = (short)h; vl[3] = (short)l;
                    split2(f1.x, h, l); vh[4] = (short)h; vl[4] = (short)l;
                    split2(f1.y, h, l); vh[5] = (short)h; vl[5] = (short)l;
                    split2(f1.z, h, l); vh[6] = (short)h; vl[6] = (short)l;
                    split2(f1.w, h, l); vh[7] = (short)h; vl[7] = (short)l;
                }
                const int off = row * 128 + (woff ^ ((row & 7) << 4));
                *(short8*)(lds + pbase + off)         = vh;
                *(short8*)(lds + pbase + 16384 + off) = vl;
            }
        }
        __syncthreads();

        #pragma unroll
        for (int kh = 0; kh < 2; ++kh) {
            short8 afh[4], afl[4];
            #pragma unroll
            for (int mt = 0; mt < 4; ++mt) {
                const int row = wm + 16 * mt + lq;
                const int off = row * 128 + ((kh * 64 + 16 * lg) ^ ((row & 7) << 4));
                afh[mt] = *(const short8*)(lds + off);
                afl[mt] = *(const short8*)(lds + 16384 + off);
            }
            #pragma unroll
            for (int nt = 0; nt < 4; ++nt) {
                const int row = wn + 16 * nt + lq;
                const int off = row * 128 + ((kh * 64 + 16 * lg) ^ ((row & 7) << 4));
                short8 bfh = *(const short8*)(lds + 32768 + off);
                short8 bfl = *(const short8*)(lds + 49152 + off);
                #pragma unroll
                for (int mt = 0; mt < 4; ++mt) {
                    acc[mt][nt] = MFMA16(afh[mt], bfh, acc[mt][nt], 0, 0, 0);
                    acc[mt][nt] = MFMA16(afh[mt], bfl, acc[mt][nt], 0, 0, 0);
                    acc[mt][nt] = MFMA16(afl[mt], bfh, acc[mt][nt], 0, 0, 0);
                }
            }
        }
        __syncthreads();
    }

    float gain = 0.f, ascv = 0.f, abiv = 0.f;
    if (MODE == 2) {
        gain = 0.25f * (*g0 + *g1 + *g2 + *g3);
        ascv = *asc;
        abiv = *abi;
    }

    #pragma unroll
    for (int nt = 0; nt < 4; ++nt) {
        const int n  = n0 + wn + 16 * nt + lq;
        const float bv = bias[n];
        #pragma unroll
        for (int mt = 0; mt < 4; ++mt) {
            #pragma unroll
            for (int j = 0; j < 4; ++j) {
                const int m = m0 + wm + 16 * mt + 4 * lg + j;
                float v = acc[mt][nt][j] + bv;
                if (RELU) v = fmaxf(v, 0.f);
                if (MODE == 0) {
                    C[(size_t)m * N + n] = v;
                } else if (MODE == 1) {
                    const int b = m >> 11, s = m & 2047;
                    const int h = n >> 6, d = n & 63;
                    C[((size_t)(b * PH + h) * PS + s) * PD + d] = v;
                } else if (MODE == 3) {
                    const int b = m >> 11, s = m & 2047;
                    const int h = n >> 6, d = n & 63;
                    Ohi[((size_t)(b * PH + h) * PS + s) * PD + d] = h16(v);
                } else if (MODE == 4) {
                    const int b = m >> 11;
                    const int h = n >> 6, d = n & 63;
                    const int scol = (m & 2047 & ~63) + ((mt & 1) << 5)
                                   + (lg << 3) + ((mt >> 1) << 2) + j;
                    Ohi[((size_t)(b * PH + h) * PD + d) * PS + scol] = h16(v);
                } else { // MODE 2
                    const int b = m >> 11, s = m & 2047;
                    const int h = n >> 6, d = n & 63;
                    const float av = attn[((size_t)(b * PH + h) * PS + s) * PD + d];
                    C[(size_t)m * N + n] = (av * ascv + abiv) * (1.f + v * gain);
                }
            }
        }
    }
}

// ---------------------------------------------------------------------------
// MFMA flash attention v9 (unchanged from round 14 — 98us, proven):
// Q single fp16 (QK^T 2 MFMA/mt/u), K/V^T single fp16 planes, P fp16 via
// v_cvt_pkrtz, exp via __builtin_amdgcn_exp2f, l via MFMA(ones,P),
// defer-max, XCD swizzle, gload_lds staging w/ pre-swizzled source.
// ---------------------------------------------------------------------------
__global__ __launch_bounds__(256, 2)
void flash_mfma(const float* qf,
                const unsigned short* __restrict__ kf,
                const unsigned short* __restrict__ vtf,
                float* attn)
{
    __shared__ int4 ldsv[2048];                    // 32 KB: 2 bufs x (K8K + V8K)
    char* const ldsb = (char*)ldsv;

    const int tid  = threadIdx.x;
    const int lane = tid & 63;
    const int w    = tid >> 6;
    const int lq   = lane & 15;
    const int lg   = lane >> 4;

    // XCD swizzle: each XCD owns 128 consecutive logical blocks (= 8 bh).
    const int L  = blockIdx.x + (blockIdx.y << 4) + (blockIdx.z << 8);
    const int nL = ((L & 7) << 7) + (L >> 3);
    const int bh = nL >> 4;
    const int q0 = (nL & 15) * 128 + w * 32;

    const size_t kbase = (size_t)bh * PS * PD;   // K rows   [S][D]
    const size_t vbase = (size_t)bh * PD * PS;   // V^T rows [D][S] (permuted)

    const unsigned short* const gp = (w < 2) ? kf + kbase : vtf + vbase;
    const bool isK = (w < 2);
    const int ch0   = (w & 1) * 4;
    const int scol8 = (((lane & 7) ^ (lane >> 3)) << 3);   // pre-swizzled col
    const int lrow8 = lane >> 3;

    auto ISSUE = [&](int kt, int bufn) {
        #pragma unroll
        for (int r = 0; r < 4; ++r) {
            const int c   = ch0 + r;
            const int row = c * 8 + lrow8;
            const size_t goff = isK ? (size_t)(kt + row) * PD + scol8
                                    : (size_t)row * PS + kt + scol8;
            GLOAD_LDS(gp + goff,
                      ldsb + bufn * 16384 + (isK ? 0 : 8192) + c * 1024 + 16 * lane);
        }
    };

    const half8 onesh = {(_Float16)1.f, (_Float16)1.f, (_Float16)1.f,
                         (_Float16)1.f, (_Float16)1.f, (_Float16)1.f,
                         (_Float16)1.f, (_Float16)1.f};

#if FAST_EXP2
    const float QSCALE = 0.125f * 1.4426950408889634f;   // exp2 domain
    const float THR    = 11.5415603f;                    // 8*log2(e)
#define EXP_P(x) __builtin_amdgcn_exp2f(x)
#else
    const float QSCALE = 0.125f;                         // natural domain
    const float THR    = 8.f;
#define EXP_P(x) __expf(x)
#endif

    // ---- Q fragments: SINGLE fp16, scale folded in
    half8 qh[2][2];
    #pragma unroll
    for (int u = 0; u < 2; ++u) {
        const float* qp = qf + ((size_t)bh * PS + q0 + 16 * u + lq) * PD + 8 * lg;
        #pragma unroll
        for (int t = 0; t < 2; ++t)
            #pragma unroll
            for (int b = 0; b < 8; ++b)
                qh[u][t][b] = (_Float16)(qp[t * 32 + b] * QSCALE);
    }

    f32x4 ot[2][4];
    #pragma unroll
    for (int u = 0; u < 2; ++u)
        #pragma unroll
        for (int mt = 0; mt < 4; ++mt)
            ot[u][mt] = (f32x4){0.f, 0.f, 0.f, 0.f};
    f32x4 lacc[2] = {{0.f,0.f,0.f,0.f}, {0.f,0.f,0.f,0.f}};
    float m_run[2] = {-3.0e38f, -3.0e38f};

    ISSUE(0, 0);
    __syncthreads();

    int buf = 0;
    for (int kti = 0; kti < PS / 64; ++kti) {
        const bool pf = (kti + 1 < PS / 64);
        if (pf) ISSUE((kti + 1) * 64, buf ^ 1);

        const char* const L2 = ldsb + buf * 16384;

        // ---- S^T tiles, Q single fp16: 2 MFMA per mt/u
        f32x4 st[2][4];
        #pragma unroll
        for (int mt = 0; mt < 4; ++mt) {
            const int row = 16 * mt + lq;
            const int swz = (row & 7) << 4;
            const char* kr = L2 + row * 128;
            half8 a0 = *(const half8*)(kr + ((16 * lg) ^ swz));
            half8 a1 = *(const half8*)(kr + ((64 + 16 * lg) ^ swz));
            #pragma unroll
            for (int u = 0; u < 2; ++u) {
                f32x4 acc = {0.f, 0.f, 0.f, 0.f};
                acc = MFMAH(a0, qh[u][0], acc, 0, 0, 0);
                acc = MFMAH(a1, qh[u][1], acc, 0, 0, 0);
                st[u][mt] = acc;
            }
        }

        // ---- online softmax (defer-max) + P pack (pkrtz) + l via MFMA
        half8 pb[2][2];
        #pragma unroll
        for (int u = 0; u < 2; ++u) {
            float a0 = fmaxf(fmaxf(st[u][0][0], st[u][0][1]), st[u][0][2]);
            float a1 = fmaxf(fmaxf(st[u][0][3], st[u][1][0]), st[u][1][1]);
            float a2 = fmaxf(fmaxf(st[u][1][2], st[u][1][3]), st[u][2][0]);
            float a3 = fmaxf(fmaxf(st[u][2][1], st[u][2][2]), st[u][2][3]);
            float a4 = fmaxf(fmaxf(st[u][3][0], st[u][3][1]), st[u][3][2]);
            float b0 = fmaxf(fmaxf(a0, a1), a2);
            float b1 = fmaxf(fmaxf(a3, a4), st[u][3][3]);
            float pmax = fmaxf(b0, b1);
            pmax = fmaxf(pmax, __shfl_xor(pmax, 16));
            pmax = fmaxf(pmax, __shfl_xor(pmax, 32));
            if (!__all(pmax - m_run[u] <= THR)) {   // rare: rescale path
                float mnew = fmaxf(m_run[u], pmax);
                float corr = EXP_P(m_run[u] - mnew);
                m_run[u] = mnew;
                #pragma unroll
                for (int j = 0; j < 4; ++j)
                    lacc[u][j] *= corr;
                #pragma unroll
                for (int mt = 0; mt < 4; ++mt)
                    #pragma unroll
                    for (int j = 0; j < 4; ++j)
                        ot[u][mt][j] *= corr;
            }
            #pragma unroll
            for (int mt = 0; mt < 4; ++mt)
                #pragma unroll
                for (int j = 0; j < 4; ++j)
                    st[u][mt][j] = EXP_P(st[u][mt][j] - m_run[u]);
            #pragma unroll
            for (int t = 0; t < 2; ++t) {
                unsigned w0 = pkrtz(st[u][t][0],     st[u][t][1]);
                unsigned w1 = pkrtz(st[u][t][2],     st[u][t][3]);
                unsigned w2 = pkrtz(st[u][t + 2][0], st[u][t + 2][1]);
                unsigned w3 = pkrtz(st[u][t + 2][2], st[u][t + 2][3]);
                uint4 pw = make_uint4(w0, w1, w2, w3);
                __builtin_memcpy(&pb[u][t], &pw, 16);
            }
            lacc[u] = MFMAH(onesh, pb[u][0], lacc[u], 0, 0, 0);
            lacc[u] = MFMAH(onesh, pb[u][1], lacc[u], 0, 0, 0);
        }

        // ---- O^T += V^T . P^T   (V single fp16, P fp16: 1 MFMA each)
        #pragma unroll
        for (int t = 0; t < 2; ++t) {
            #pragma unroll
            for (int mt = 0; mt < 4; ++mt) {
                const int row = 16 * mt + lq;
                const int swz = (row & 7) << 4;
                const char* vr = L2 + 8192 + row * 128;
                half8 vv = *(const half8*)(vr + ((t * 64 + 16 * lg) ^ swz));
                #pragma unroll
                for (int u = 0; u < 2; ++u)
                    ot[u][mt] = MFMAH(vv, pb[u][t], ot[u][mt], 0, 0, 0);
            }
        }

        __syncthreads();        // drains prefetch vmcnt + protects LDS reuse
        buf ^= 1;
    }

    // ---- epilogue: attn[bh][q0+16u+lq][d], d = 16*mt + 4*lg + j
    #pragma unroll
    for (int u = 0; u < 2; ++u) {
        const float inv = 1.f / lacc[u][0];
        float* op = attn + ((size_t)bh * PS + q0 + 16 * u + lq) * PD + 4 * lg;
        #pragma unroll
        for (int mt = 0; mt < 4; ++mt) {
            float4 o;
            o.x = ot[u][mt][0] * inv; o.y = ot[u][mt][1] * inv;
            o.z = ot[u][mt][2] * inv; o.w = ot[u][mt][3] * inv;
            *(float4*)(op + 16 * mt) = o;
        }
    }
}

// ---------------------------------------------------------------------------
extern "C" void kernel_launch(void* const* d_in, const int* in_sizes, int n_in,
                              void* d_out, int out_size, void* d_ws, size_t ws_size,
                              hipStream_t stream)
{
    const float* query = (const float*)d_in[0];
    const float* Wq  = (const float*)d_in[1];  const float* bq  = (const float*)d_in[2];
    const float* Wk  = (const float*)d_in[3];  const float* bk  = (const float*)d_in[4];
    const float* Wv  = (const float*)d_in[5];  const float* bv  = (const float*)d_in[6];
    const float* Wo  = (const float*)d_in[7];  const float* bo  = (const float*)d_in[8];
    const float* Wm1 = (const float*)d_in[9];  const float* bm1 = (const float*)d_in[10];
    const float* Wm2 = (const float*)d_in[11]; const float* bm2 = (const float*)d_in[12];
    const float* dop = (const float*)d_in[13];
    const float* ser = (const float*)d_in[14];
    const float* nor = (const float*)d_in[15];
    const float* ach = (const float*)d_in[16];
    const float* asc = (const float*)d_in[17];
    const float* abi = (const float*)d_in[18];
    float* out = (float*)d_out;

    char* wsb = (char*)d_ws;
    // Common: qf32 [0,32M), kf fp16 [32M,48M), vtf fp16 [48M,64M)
    float*          qf32 = (float*)wsb;
    unsigned short* kf   = (unsigned short*)(wsb + (32u << 20));
    unsigned short* vtf  = (unsigned short*)(wsb + (48u << 20));

    dim3 blk(256);
    const bool presplit = (ws_size >= 161480704ull);             // 154 MB

    if (presplit) {
        unsigned short* h1h   = (unsigned short*)(wsb + (64u << 20));  // 4MB
        unsigned short* afh   = (unsigned short*)(wsb + (72u << 20));  // 16MB
        unsigned short* qh    = (unsigned short*)(wsb + (104u << 20)); // 16MB
        unsigned short* wqh   = (unsigned short*)(wsb + (136u << 20)); // 2MB
        unsigned short* wkh   = (unsigned short*)(wsb + (138u << 20));
        unsigned short* wvh   = (unsigned short*)(wsb + (140u << 20));
        unsigned short* woh   = (unsigned short*)(wsb + (142u << 20));
        unsigned short* m1h   = (unsigned short*)(wsb + (144u << 20)); // 0.5MB
        unsigned short* m2h   = (unsigned short*)(wsb + (145u << 20));

        split_all<<<12800, blk, 0, stream>>>(
            query, Wq, Wk, Wv, Wo, Wm1, Wm2,
            qh, wqh, wkh, wvh, woh, m1h, m2h);

        // Fused Q/K/V projections (A staged once for all three)
        gemm_qkv<<<dim3(PM / 128, PE / 128), dim3(512), 0, stream>>>(
            qh, wqh, wkh, wvh, bq, bk, bv, qf32, kf, vtf);

        gemm_pl<5, true><<<dim3(PM / 128, 256 / 128), blk, 0, stream>>>(
            qh, m1h, bm1, nullptr, h1h, PM, 256, PE,
            nullptr, nullptr, nullptr, nullptr, nullptr, nullptr, nullptr);

        flash_mfma<<<dim3(PS / 128, PH, PB), blk, 0, stream>>>(
            qf32, kf, vtf, qf32);

        gemm_pl<6, false><<<dim3(PM / 128, PE / 128), blk, 0, stream>>>(
            h1h, m2h, bm2, nullptr, afh, PM, PE, 256,
            qf32, dop, ser, nor, ach, asc, abi);
        gemm_pl<0, false><<<dim3(PM / 128, PE / 128), blk, 0, stream>>>(
            afh, woh, bo, out, nullptr, PM, PE, PE,
            nullptr, nullptr, nullptr, nullptr, nullptr, nullptr, nullptr);
    } else {
        // fallback: fp32-fed bf16 3-term GEMMs + fp16 flash
        float* h1    = (float*)(wsb + (64u << 20));   // 8MB
        float* attnf = (float*)(wsb + (72u << 20));   // 32MB

        gemm_nt<1, false><<<dim3(PM / 128, PE / 128), blk, 0, stream>>>(
            query, Wq, bq, qf32, nullptr, PM, PE, PE,
            nullptr, nullptr, nullptr, nullptr, nullptr, nullptr, nullptr);
        gemm_nt<3, false><<<dim3(PM / 128, PE / 128), blk, 0, stream>>>(
            query, Wk, bk, nullptr, kf, PM, PE, PE,
            nullptr, nullptr, nullptr, nullptr, nullptr, nullptr, nullptr);
        gemm_nt<4, false><<<dim3(PM / 128, PE / 128), blk, 0, stream>>>(
            query, Wv, bv, nullptr, vtf, PM, PE, PE,
            nullptr, nullptr, nullptr, nullptr, nullptr, nullptr, nullptr);
        gemm_nt<0, true><<<dim3(PM / 128, 256 / 128), blk, 0, stream>>>(
            query, Wm1, bm1, h1, nullptr, PM, 256, PE,
            nullptr, nullptr, nullptr, nullptr, nullptr, nullptr, nullptr);

        flash_mfma<<<dim3(PS / 128, PH, PB), blk, 0, stream>>>(
            qf32, kf, vtf, qf32);

        gemm_nt<2, false><<<dim3(PM / 128, PE / 128), blk, 0, stream>>>(
            h1, Wm2, bm2, attnf, nullptr, PM, PE, 256,
            qf32, dop, ser, nor, ach, asc, abi);
        gemm_nt<0, false><<<dim3(PM / 128, PE / 128), blk, 0, stream>>>(
            attnf, Wo, bo, out, nullptr, PM, PE, PE,
            nullptr, nullptr, nullptr, nullptr, nullptr, nullptr, nullptr);
    }
}

// Round 17
// 213.595 us; speedup vs baseline: 1.5117x; 1.0459x over previous
//
#include <hip/hip_runtime.h>
#include <hip/hip_bf16.h>
#include <cstdint>

// Problem constants
#define PB 4
#define PS 2048
#define PE 1024
#define PH 16
#define PD 64
#define PM (PB * PS)      // 8192 rows

typedef __attribute__((ext_vector_type(8))) _Float16 half8;  // 8 fp16 (4 VGPR)
typedef __attribute__((ext_vector_type(4))) float f32x4;

#define MFMAH __builtin_amdgcn_mfma_f32_16x16x32_f16

#define GLOAD_LDS(gp, lp) __builtin_amdgcn_global_load_lds(                    \
    (const __attribute__((address_space(1))) void*)(gp),                       \
    (__attribute__((address_space(3))) void*)(lp), 16, 0, 0)

#if __has_builtin(__builtin_amdgcn_exp2f)
#define FAST_EXP2 1
#define QSC (0.125f * 1.4426950408889634f)   // exp2 domain
#define FTHR 11.5415603f                     // 8*log2(e)
#define EXP_P(x) __builtin_amdgcn_exp2f(x)
#else
#define FAST_EXP2 0
#define QSC 0.125f
#define FTHR 8.f
#define EXP_P(x) __expf(x)
#endif

// fp32 -> fp16 RNE bit pattern
__device__ inline unsigned short h16(float x) {
    _Float16 h = (_Float16)x;
    unsigned short u;
    __builtin_memcpy(&u, &h, 2);
    return u;
}
// packed fp16 pair via v_cvt_pkrtz_f16_f32; returns the 32-bit word
__device__ inline unsigned pkrtz(float a, float b) {
    auto p = __builtin_amdgcn_cvt_pkrtz(a, b);   // __fp16 ext_vector(2)
    unsigned u;
    __builtin_memcpy(&u, &p, 4);
    return u;
}

// ---------------------------------------------------------------------------
// split_all: all 7 fp32 operands -> single fp16 planes, one launch.
// ---------------------------------------------------------------------------
__global__ __launch_bounds__(256)
void split_all(const float* __restrict__ q,   const float* __restrict__ wq,
               const float* __restrict__ wk,  const float* __restrict__ wv,
               const float* __restrict__ wo,  const float* __restrict__ wm1,
               const float* __restrict__ wm2,
               unsigned short* qh,  unsigned short* wqh, unsigned short* wkh,
               unsigned short* wvh, unsigned short* woh,
               unsigned short* m1h, unsigned short* m2h)
{
    const int b = blockIdx.x;
    const float* src; unsigned short* dst; int base;
    if      (b <  8192) { src = q;   dst = qh;  base = 0;     }
    else if (b <  9216) { src = wq;  dst = wqh; base = 8192;  }
    else if (b < 10240) { src = wk;  dst = wkh; base = 9216;  }
    else if (b < 11264) { src = wv;  dst = wvh; base = 10240; }
    else if (b < 12288) { src = wo;  dst = woh; base = 11264; }
    else if (b < 12544) { src = wm1; dst = m1h; base = 12288; }
    else                { src = wm2; dst = m2h; base = 12544; }
    const int i = (b - base) * 256 + threadIdx.x;
    float4 f = ((const float4*)src)[i];
    ushort4 h;
    h.x = h16(f.x); h.y = h16(f.y); h.z = h16(f.z); h.w = h16(f.w);
    ((ushort4*)dst)[i] = h;
}

// ---------------------------------------------------------------------------
// Fused QKV projection (round-16): 512 threads, 128KB dbuf LDS, stages A
// once for Q/K/V. Epilogues: Q fp16 PRE-SCALED (QSC folded) at BHSD,
// K fp16 BHSD, V fp16 BHDS with PV seq permutation.
// ---------------------------------------------------------------------------
__global__ __launch_bounds__(512, 2)
void gemm_qkv(const unsigned short* __restrict__ Ah,
              const unsigned short* __restrict__ Wqh,
              const unsigned short* __restrict__ Wkh,
              const unsigned short* __restrict__ Wvh,
              const float* __restrict__ bq, const float* __restrict__ bk,
              const float* __restrict__ bv,
              unsigned short* __restrict__ qh16, unsigned short* __restrict__ kf,
              unsigned short* __restrict__ vtf)
{
    __shared__ int4 ldsq[8192];                 // 128 KB = 2 bufs x 4 planes
    char* const lds = (char*)ldsq;
    const int K = PE;

    const int tid  = threadIdx.x;
    const int lane = tid & 63;
    const int w    = tid >> 6;
    const int lq   = lane & 15;
    const int lg   = lane >> 4;
    const int wr   = w >> 2;
    const int wc   = w & 3;
    const int m0   = blockIdx.x * 128;
    const int n0   = blockIdx.y * 128;

    const int plane = w >> 1;
    const unsigned short* const gp =
        (plane == 0) ? Ah  + (size_t)m0 * K :
        (plane == 1) ? Wqh + (size_t)n0 * K :
        (plane == 2) ? Wkh + (size_t)n0 * K :
                       Wvh + (size_t)n0 * K;
    const int pbase = plane * 16384;
    const int ch0   = (w & 1) * 8;
    const int scol8 = (((lane & 7) ^ (lane >> 3)) << 3);
    const int lrow8 = lane >> 3;

    auto ISSUE = [&](int k0, int bufn) {
        #pragma unroll
        for (int r = 0; r < 8; ++r) {
            const int c   = ch0 + r;
            const int row = c * 8 + lrow8;
            GLOAD_LDS(gp + (size_t)row * K + k0 + scol8,
                      lds + bufn * 65536 + pbase + c * 1024 + 16 * lane);
        }
    };

    f32x4 acc[3][4][2];
    #pragma unroll
    for (int o = 0; o < 3; ++o)
        #pragma unroll
        for (int mt = 0; mt < 4; ++mt)
            #pragma unroll
            for (int nt = 0; nt < 2; ++nt)
                acc[o][mt][nt] = (f32x4){0.f, 0.f, 0.f, 0.f};

    ISSUE(0, 0);
    __syncthreads();

    int buf = 0;
    for (int k0 = 0; k0 < K; k0 += 64) {
        if (k0 + 64 < K) ISSUE(k0 + 64, buf ^ 1);

        const char* const L = lds + buf * 65536;
        #pragma unroll
        for (int kh = 0; kh < 2; ++kh) {
            half8 af[4];
            #pragma unroll
            for (int mt = 0; mt < 4; ++mt) {
                const int row = 64 * wr + 16 * mt + lq;
                const int off = row * 128 + ((kh * 64 + 16 * lg) ^ ((row & 7) << 4));
                af[mt] = *(const half8*)(L + off);
            }
            #pragma unroll
            for (int o = 0; o < 3; ++o) {
                #pragma unroll
                for (int nt = 0; nt < 2; ++nt) {
                    const int row = 32 * wc + 16 * nt + lq;
                    const int off = row * 128 + ((kh * 64 + 16 * lg) ^ ((row & 7) << 4));
                    half8 bf = *(const half8*)(L + 16384 * (o + 1) + off);
                    #pragma unroll
                    for (int mt = 0; mt < 4; ++mt)
                        acc[o][mt][nt] = MFMAH(af[mt], bf, acc[o][mt][nt], 0, 0, 0);
                }
            }
        }
        __syncthreads();
        buf ^= 1;
    }

    #pragma unroll
    for (int nt = 0; nt < 2; ++nt) {
        const int n = n0 + 32 * wc + 16 * nt + lq;
        const int h = n >> 6, d = n & 63;
        const float bqv = bq[n], bkv = bk[n], bvv = bv[n];
        #pragma unroll
        for (int mt = 0; mt < 4; ++mt) {
            #pragma unroll
            for (int j = 0; j < 4; ++j) {
                const int m = m0 + 64 * wr + 16 * mt + 4 * lg + j;
                const int b = m >> 11, s = m & 2047;
                // Q: fp16 pre-scaled BHSD
                qh16[((size_t)(b * PH + h) * PS + s) * PD + d] =
                    h16((acc[0][mt][nt][j] + bqv) * QSC);
                // K: fp16 BHSD
                kf[((size_t)(b * PH + h) * PS + s) * PD + d] =
                    h16(acc[1][mt][nt][j] + bkv);
                // V^T: fp16 BHDS with PV permutation (in-tile r = 16mt+4lg+j)
                const int scol = (s & ~63) + ((mt & 1) << 5) + (lg << 3)
                               + ((mt >> 1) << 2) + j;
                vtf[((size_t)(b * PH + h) * PD + d) * PS + scol] =
                    h16(acc[2][mt][nt][j] + bvv);
            }
        }
    }
}

// ---------------------------------------------------------------------------
// Plane-fed single-fp16 MFMA NT GEMM (round-15 proven engine, unchanged).
// MODE 0: fp32 C[m*N+n] (optional RELU) | MODE 5: fp16 plane [M][N] (RELU)
// MODE 6: neuromod combine -> fp16 plane [M][N]
// ---------------------------------------------------------------------------
template<int MODE, bool RELU>
__global__ __launch_bounds__(256, 2)
void gemm_pl(const unsigned short* __restrict__ Ah,
             const unsigned short* __restrict__ Bh,
             const float* __restrict__ bias, float* __restrict__ C,
             unsigned short* __restrict__ Oh,
             int M, int N, int K,
             const float* __restrict__ attn,
             const float* __restrict__ g0, const float* __restrict__ g1,
             const float* __restrict__ g2, const float* __restrict__ g3,
             const float* __restrict__ asc, const float* __restrict__ abi)
{
    __shared__ int4 ldsq[4096];                 // 64 KB = 2 bufs x 32 KB
    char* const lds = (char*)ldsq;

    const int tid  = threadIdx.x;
    const int lane = tid & 63;
    const int w    = tid >> 6;
    const int lq   = lane & 15;
    const int lg   = lane >> 4;
    const int wm   = (w >> 1) * 64;
    const int wn   = (w & 1) * 64;
    const int m0   = blockIdx.x * 128;
    const int n0   = blockIdx.y * 128;

    const unsigned short* const gp =
        (w < 2) ? Ah + (size_t)m0 * K : Bh + (size_t)n0 * K;
    const int pb    = (w < 2) ? 0 : 16384;
    const int ch0   = (w & 1) * 8;
    const int scol8 = (((lane & 7) ^ (lane >> 3)) << 3);
    const int lrow8 = lane >> 3;

    auto ISSUE = [&](int k0, int bufn) {
        #pragma unroll
        for (int r = 0; r < 8; ++r) {
            const int c   = ch0 + r;
            const int row = c * 8 + lrow8;
            GLOAD_LDS(gp + (size_t)row * K + k0 + scol8,
                      lds + bufn * 32768 + pb + c * 1024 + 16 * lane);
        }
    };

    f32x4 acc[4][4];
    #pragma unroll
    for (int mt = 0; mt < 4; ++mt)
        #pragma unroll
        for (int nt = 0; nt < 4; ++nt)
            acc[mt][nt] = (f32x4){0.f, 0.f, 0.f, 0.f};

    ISSUE(0, 0);
    __syncthreads();

    int buf = 0;
    for (int k0 = 0; k0 < K; k0 += 64) {
        if (k0 + 64 < K) ISSUE(k0 + 64, buf ^ 1);

        const char* const L = lds + buf * 32768;
        #pragma unroll
        for (int kh = 0; kh < 2; ++kh) {
            half8 af[4];
            #pragma unroll
            for (int mt = 0; mt < 4; ++mt) {
                const int row = wm + 16 * mt + lq;
                const int off = row * 128 + ((kh * 64 + 16 * lg) ^ ((row & 7) << 4));
                af[mt] = *(const half8*)(L + off);
            }
            #pragma unroll
            for (int nt = 0; nt < 4; ++nt) {
                const int row = wn + 16 * nt + lq;
                const int off = row * 128 + ((kh * 64 + 16 * lg) ^ ((row & 7) << 4));
                half8 bf = *(const half8*)(L + 16384 + off);
                #pragma unroll
                for (int mt = 0; mt < 4; ++mt)
                    acc[mt][nt] = MFMAH(af[mt], bf, acc[mt][nt], 0, 0, 0);
            }
        }
        __syncthreads();
        buf ^= 1;
    }

    float gain = 0.f, ascv = 0.f, abiv = 0.f;
    if (MODE == 6) {
        gain = 0.25f * (*g0 + *g1 + *g2 + *g3);
        ascv = *asc;
        abiv = *abi;
    }

    #pragma unroll
    for (int nt = 0; nt < 4; ++nt) {
        const int n  = n0 + wn + 16 * nt + lq;
        const float bv = bias[n];
        #pragma unroll
        for (int mt = 0; mt < 4; ++mt) {
            #pragma unroll
            for (int j = 0; j < 4; ++j) {
                const int m = m0 + wm + 16 * mt + 4 * lg + j;
                float v = acc[mt][nt][j] + bv;
                if (RELU) v = fmaxf(v, 0.f);
                if (MODE == 0) {
                    C[(size_t)m * N + n] = v;
                } else if (MODE == 5) {
                    Oh[(size_t)m * N + n] = h16(v);
                } else { // MODE 6
                    const int b = m >> 11, s = m & 2047;
                    const int h = n >> 6, d = n & 63;
                    const float av = attn[((size_t)(b * PH + h) * PS + s) * PD + d];
                    const float o = (av * ascv + abiv) * (1.f + v * gain);
                    Oh[(size_t)m * N + n] = h16(o);
                }
            }
        }
    }
}

// ---------------------------------------------------------------------------
// fp32-fed fallback GEMM (bf16 3-term internally, round-5 proven skeleton);
// MODE 1 emits PRE-SCALED fp16 Q; MODE 3/4 emit fp16 planes.
// ---------------------------------------------------------------------------
typedef __attribute__((ext_vector_type(8))) short short8;
#define MFMA16 __builtin_amdgcn_mfma_f32_16x16x32_bf16
__device__ inline unsigned short bf16rn(float x) {
    unsigned u = __builtin_bit_cast(unsigned, x);
    u += 0x7FFFu + ((u >> 16) & 1u);
    return (unsigned short)(u >> 16);
}
__device__ inline float bf16tof(unsigned short h) {
    unsigned u = ((unsigned)h) << 16;
    return __builtin_bit_cast(float, u);
}
__device__ inline void split2(float x, unsigned short& h, unsigned short& l) {
    h = bf16rn(x);
    l = bf16rn(x - bf16tof(h));
}

template<int MODE, bool RELU>
__global__ __launch_bounds__(256, 2)
void gemm_nt(const float* __restrict__ A, const float* __restrict__ Bw,
             const float* __restrict__ bias, float* __restrict__ C,
             unsigned short* __restrict__ Ohi,
             int M, int N, int K,
             const float* __restrict__ attn,
             const float* __restrict__ g0, const float* __restrict__ g1,
             const float* __restrict__ g2, const float* __restrict__ g3,
             const float* __restrict__ asc, const float* __restrict__ abi)
{
    __shared__ int4 ldsq[4096];
    char* const lds = (char*)ldsq;

    const int tid  = threadIdx.x;
    const int lane = tid & 63;
    const int w    = tid >> 6;
    const int lq   = lane & 15;
    const int lg   = lane >> 4;
    const int wm   = (w >> 1) * 64;
    const int wn   = (w & 1) * 64;
    const int m0   = blockIdx.x * 128;
    const int n0   = blockIdx.y * 128;

    const int irow = tid >> 3;
    const int ic8  = (tid & 7) * 8;
    const int woff = (ic8 * 2);

    f32x4 acc[4][4];
    #pragma unroll
    for (int mt = 0; mt < 4; ++mt)
        #pragma unroll
        for (int nt = 0; nt < 4; ++nt)
            acc[mt][nt] = (f32x4){0.f, 0.f, 0.f, 0.f};

    for (int k0 = 0; k0 < K; k0 += 64) {
        #pragma unroll
        for (int mat = 0; mat < 2; ++mat) {
            const float* const src = mat ? Bw : A;
            const int rbase = mat ? n0 : m0;
            const int pbase = mat ? 32768 : 0;
            #pragma unroll
            for (int r = 0; r < 4; ++r) {
                const int row = irow + 32 * r;
                const float* p = src + (size_t)(rbase + row) * K + k0 + ic8;
                float4 f0 = *(const float4*)p;
                float4 f1 = *(const float4*)(p + 4);
                short8 vh, vl;
                {
                    unsigned short h, l;
                    split2(f0.x, h, l); vh[0] = (short)h; vl[0] = (short)l;
                    split2(f0.y, h, l); vh[1] = (short)h; vl[1] = (short)l;
                    split2(f0.z, h, l); vh[2] = (short)h; vl[2] = (short)l;
                    split2(f0.w, h, l); vh[3] = (short)h; vl[3] = (short)l;
                    split2(f1.x, h, l); vh[4] = (short)h; vl[4] = (short)l;
                    split2(f1.y, h, l); vh[5] = (short)h; vl[5] = (short)l;
                    split2(f1.z, h, l); vh[6] = (short)h; vl[6] = (short)l;
                    split2(f1.w, h, l); vh[7] = (short)h; vl[7] = (short)l;
                }
                const int off = row * 128 + (woff ^ ((row & 7) << 4));
                *(short8*)(lds + pbase + off)         = vh;
                *(short8*)(lds + pbase + 16384 + off) = vl;
            }
        }
        __syncthreads();

        #pragma unroll
        for (int kh = 0; kh < 2; ++kh) {
            short8 afh[4], afl[4];
            #pragma unroll
            for (int mt = 0; mt < 4; ++mt) {
                const int row = wm + 16 * mt + lq;
                const int off = row * 128 + ((kh * 64 + 16 * lg) ^ ((row & 7) << 4));
                afh[mt] = *(const short8*)(lds + off);
                afl[mt] = *(const short8*)(lds + 16384 + off);
            }
            #pragma unroll
            for (int nt = 0; nt < 4; ++nt) {
                const int row = wn + 16 * nt + lq;
                const int off = row * 128 + ((kh * 64 + 16 * lg) ^ ((row & 7) << 4));
                short8 bfh = *(const short8*)(lds + 32768 + off);
                short8 bfl = *(const short8*)(lds + 49152 + off);
                #pragma unroll
                for (int mt = 0; mt < 4; ++mt) {
                    acc[mt][nt] = MFMA16(afh[mt], bfh, acc[mt][nt], 0, 0, 0);
                    acc[mt][nt] = MFMA16(afh[mt], bfl, acc[mt][nt], 0, 0, 0);
                    acc[mt][nt] = MFMA16(afl[mt], bfh, acc[mt][nt], 0, 0, 0);
                }
            }
        }
        __syncthreads();
    }

    float gain = 0.f, ascv = 0.f, abiv = 0.f;
    if (MODE == 2) {
        gain = 0.25f * (*g0 + *g1 + *g2 + *g3);
        ascv = *asc;
        abiv = *abi;
    }

    #pragma unroll
    for (int nt = 0; nt < 4; ++nt) {
        const int n  = n0 + wn + 16 * nt + lq;
        const float bv = bias[n];
        #pragma unroll
        for (int mt = 0; mt < 4; ++mt) {
            #pragma unroll
            for (int j = 0; j < 4; ++j) {
                const int m = m0 + wm + 16 * mt + 4 * lg + j;
                float v = acc[mt][nt][j] + bv;
                if (RELU) v = fmaxf(v, 0.f);
                if (MODE == 0) {
                    C[(size_t)m * N + n] = v;
                } else if (MODE == 1) {
                    const int b = m >> 11, s = m & 2047;
                    const int h = n >> 6, d = n & 63;
                    Ohi[((size_t)(b * PH + h) * PS + s) * PD + d] = h16(v * QSC);
                } else if (MODE == 3) {
                    const int b = m >> 11, s = m & 2047;
                    const int h = n >> 6, d = n & 63;
                    Ohi[((size_t)(b * PH + h) * PS + s) * PD + d] = h16(v);
                } else if (MODE == 4) {
                    const int b = m >> 11;
                    const int h = n >> 6, d = n & 63;
                    const int scol = (m & 2047 & ~63) + ((mt & 1) << 5)
                                   + (lg << 3) + ((mt >> 1) << 2) + j;
                    Ohi[((size_t)(b * PH + h) * PD + d) * PS + scol] = h16(v);
                } else { // MODE 2
                    const int b = m >> 11, s = m & 2047;
                    const int h = n >> 6, d = n & 63;
                    const float av = attn[((size_t)(b * PH + h) * PS + s) * PD + d];
                    C[(size_t)m * N + n] = (av * ascv + abiv) * (1.f + v * gain);
                }
            }
        }
    }
}

// ---------------------------------------------------------------------------
// MFMA flash attention v10: round-14 engine with (a) 4 blocks/CU
// (VGPR 64 <= 128 cap, LDS 32KB -> no spill risk) and (b) Q read as a
// pre-scaled fp16 plane (4 half8 vector loads replace 64 scalar fp32
// loads + muls; numerics identical — conversion moved to QKV epilogue).
// ---------------------------------------------------------------------------
__global__ __launch_bounds__(256, 4)
void flash_mfma(const unsigned short* __restrict__ qh16,
                const unsigned short* __restrict__ kf,
                const unsigned short* __restrict__ vtf,
                float* attn)
{
    __shared__ int4 ldsv[2048];                    // 32 KB: 2 bufs x (K8K + V8K)
    char* const ldsb = (char*)ldsv;

    const int tid  = threadIdx.x;
    const int lane = tid & 63;
    const int w    = tid >> 6;
    const int lq   = lane & 15;
    const int lg   = lane >> 4;

    // XCD swizzle: each XCD owns 128 consecutive logical blocks (= 8 bh).
    const int L  = blockIdx.x + (blockIdx.y << 4) + (blockIdx.z << 8);
    const int nL = ((L & 7) << 7) + (L >> 3);
    const int bh = nL >> 4;
    const int q0 = (nL & 15) * 128 + w * 32;

    const size_t kbase = (size_t)bh * PS * PD;   // K rows   [S][D]
    const size_t vbase = (size_t)bh * PD * PS;   // V^T rows [D][S] (permuted)

    const unsigned short* const gp = (w < 2) ? kf + kbase : vtf + vbase;
    const bool isK = (w < 2);
    const int ch0   = (w & 1) * 4;
    const int scol8 = (((lane & 7) ^ (lane >> 3)) << 3);   // pre-swizzled col
    const int lrow8 = lane >> 3;

    auto ISSUE = [&](int kt, int bufn) {
        #pragma unroll
        for (int r = 0; r < 4; ++r) {
            const int c   = ch0 + r;
            const int row = c * 8 + lrow8;
            const size_t goff = isK ? (size_t)(kt + row) * PD + scol8
                                    : (size_t)row * PS + kt + scol8;
            GLOAD_LDS(gp + goff,
                      ldsb + bufn * 16384 + (isK ? 0 : 8192) + c * 1024 + 16 * lane);
        }
    };

    const half8 onesh = {(_Float16)1.f, (_Float16)1.f, (_Float16)1.f,
                         (_Float16)1.f, (_Float16)1.f, (_Float16)1.f,
                         (_Float16)1.f, (_Float16)1.f};

    // ---- Q fragments: pre-scaled fp16 plane, direct vector loads
    half8 qh[2][2];
    #pragma unroll
    for (int u = 0; u < 2; ++u) {
        const unsigned short* qp =
            qh16 + ((size_t)bh * PS + q0 + 16 * u + lq) * PD + 8 * lg;
        qh[u][0] = *(const half8*)(qp);
        qh[u][1] = *(const half8*)(qp + 32);
    }

    f32x4 ot[2][4];
    #pragma unroll
    for (int u = 0; u < 2; ++u)
        #pragma unroll
        for (int mt = 0; mt < 4; ++mt)
            ot[u][mt] = (f32x4){0.f, 0.f, 0.f, 0.f};
    f32x4 lacc[2] = {{0.f,0.f,0.f,0.f}, {0.f,0.f,0.f,0.f}};
    float m_run[2] = {-3.0e38f, -3.0e38f};

    ISSUE(0, 0);
    __syncthreads();

    int buf = 0;
    for (int kti = 0; kti < PS / 64; ++kti) {
        const bool pf = (kti + 1 < PS / 64);
        if (pf) ISSUE((kti + 1) * 64, buf ^ 1);

        const char* const L2 = ldsb + buf * 16384;

        // ---- S^T tiles, Q single fp16: 2 MFMA per mt/u
        f32x4 st[2][4];
        #pragma unroll
        for (int mt = 0; mt < 4; ++mt) {
            const int row = 16 * mt + lq;
            const int swz = (row & 7) << 4;
            const char* kr = L2 + row * 128;
            half8 a0 = *(const half8*)(kr + ((16 * lg) ^ swz));
            half8 a1 = *(const half8*)(kr + ((64 + 16 * lg) ^ swz));
            #pragma unroll
            for (int u = 0; u < 2; ++u) {
                f32x4 acc = {0.f, 0.f, 0.f, 0.f};
                acc = MFMAH(a0, qh[u][0], acc, 0, 0, 0);
                acc = MFMAH(a1, qh[u][1], acc, 0, 0, 0);
                st[u][mt] = acc;
            }
        }

        // ---- online softmax (defer-max) + P pack (pkrtz) + l via MFMA
        half8 pb[2][2];
        #pragma unroll
        for (int u = 0; u < 2; ++u) {
            float a0 = fmaxf(fmaxf(st[u][0][0], st[u][0][1]), st[u][0][2]);
            float a1 = fmaxf(fmaxf(st[u][0][3], st[u][1][0]), st[u][1][1]);
            float a2 = fmaxf(fmaxf(st[u][1][2], st[u][1][3]), st[u][2][0]);
            float a3 = fmaxf(fmaxf(st[u][2][1], st[u][2][2]), st[u][2][3]);
            float a4 = fmaxf(fmaxf(st[u][3][0], st[u][3][1]), st[u][3][2]);
            float b0 = fmaxf(fmaxf(a0, a1), a2);
            float b1 = fmaxf(fmaxf(a3, a4), st[u][3][3]);
            float pmax = fmaxf(b0, b1);
            pmax = fmaxf(pmax, __shfl_xor(pmax, 16));
            pmax = fmaxf(pmax, __shfl_xor(pmax, 32));
            if (!__all(pmax - m_run[u] <= FTHR)) {   // rare: rescale path
                float mnew = fmaxf(m_run[u], pmax);
                float corr = EXP_P(m_run[u] - mnew);
                m_run[u] = mnew;
                #pragma unroll
                for (int j = 0; j < 4; ++j)
                    lacc[u][j] *= corr;
                #pragma unroll
                for (int mt = 0; mt < 4; ++mt)
                    #pragma unroll
                    for (int j = 0; j < 4; ++j)
                        ot[u][mt][j] *= corr;
            }
            #pragma unroll
            for (int mt = 0; mt < 4; ++mt)
                #pragma unroll
                for (int j = 0; j < 4; ++j)
                    st[u][mt][j] = EXP_P(st[u][mt][j] - m_run[u]);
            #pragma unroll
            for (int t = 0; t < 2; ++t) {
                unsigned w0 = pkrtz(st[u][t][0],     st[u][t][1]);
                unsigned w1 = pkrtz(st[u][t][2],     st[u][t][3]);
                unsigned w2 = pkrtz(st[u][t + 2][0], st[u][t + 2][1]);
                unsigned w3 = pkrtz(st[u][t + 2][2], st[u][t + 2][3]);
                uint4 pw = make_uint4(w0, w1, w2, w3);
                __builtin_memcpy(&pb[u][t], &pw, 16);
            }
            lacc[u] = MFMAH(onesh, pb[u][0], lacc[u], 0, 0, 0);
            lacc[u] = MFMAH(onesh, pb[u][1], lacc[u], 0, 0, 0);
        }

        // ---- O^T += V^T . P^T   (V single fp16, P fp16: 1 MFMA each)
        #pragma unroll
        for (int t = 0; t < 2; ++t) {
            #pragma unroll
            for (int mt = 0; mt < 4; ++mt) {
                const int row = 16 * mt + lq;
                const int swz = (row & 7) << 4;
                const char* vr = L2 + 8192 + row * 128;
                half8 vv = *(const half8*)(vr + ((t * 64 + 16 * lg) ^ swz));
                #pragma unroll
                for (int u = 0; u < 2; ++u)
                    ot[u][mt] = MFMAH(vv, pb[u][t], ot[u][mt], 0, 0, 0);
            }
        }

        __syncthreads();        // drains prefetch vmcnt + protects LDS reuse
        buf ^= 1;
    }

    // ---- epilogue: attn[bh][q0+16u+lq][d], d = 16*mt + 4*lg + j
    #pragma unroll
    for (int u = 0; u < 2; ++u) {
        const float inv = 1.f / lacc[u][0];
        float* op = attn + ((size_t)bh * PS + q0 + 16 * u + lq) * PD + 4 * lg;
        #pragma unroll
        for (int mt = 0; mt < 4; ++mt) {
            float4 o;
            o.x = ot[u][mt][0] * inv; o.y = ot[u][mt][1] * inv;
            o.z = ot[u][mt][2] * inv; o.w = ot[u][mt][3] * inv;
            *(float4*)(op + 16 * mt) = o;
        }
    }
}

// ---------------------------------------------------------------------------
extern "C" void kernel_launch(void* const* d_in, const int* in_sizes, int n_in,
                              void* d_out, int out_size, void* d_ws, size_t ws_size,
                              hipStream_t stream)
{
    const float* query = (const float*)d_in[0];
    const float* Wq  = (const float*)d_in[1];  const float* bq  = (const float*)d_in[2];
    const float* Wk  = (const float*)d_in[3];  const float* bk  = (const float*)d_in[4];
    const float* Wv  = (const float*)d_in[5];  const float* bv  = (const float*)d_in[6];
    const float* Wo  = (const float*)d_in[7];  const float* bo  = (const float*)d_in[8];
    const float* Wm1 = (const float*)d_in[9];  const float* bm1 = (const float*)d_in[10];
    const float* Wm2 = (const float*)d_in[11]; const float* bm2 = (const float*)d_in[12];
    const float* dop = (const float*)d_in[13];
    const float* ser = (const float*)d_in[14];
    const float* nor = (const float*)d_in[15];
    const float* ach = (const float*)d_in[16];
    const float* asc = (const float*)d_in[17];
    const float* abi = (const float*)d_in[18];
    float* out = (float*)d_out;

    char* wsb = (char*)d_ws;
    // Common: attn fp32 [0,32M), kf fp16 [32M,48M), vtf fp16 [48M,64M)
    float*          attnb = (float*)wsb;
    unsigned short* kf    = (unsigned short*)(wsb + (32u << 20));
    unsigned short* vtf   = (unsigned short*)(wsb + (48u << 20));

    dim3 blk(256);
    const bool presplit = (ws_size >= 161480704ull);             // 154 MB

    if (presplit) {
        unsigned short* h1h   = (unsigned short*)(wsb + (64u << 20));  // 4MB
        unsigned short* afh   = (unsigned short*)(wsb + (72u << 20));  // 16MB
        unsigned short* qh16  = (unsigned short*)(wsb + (88u << 20));  // 16MB
        unsigned short* qh    = (unsigned short*)(wsb + (104u << 20)); // 16MB
        unsigned short* wqh   = (unsigned short*)(wsb + (136u << 20)); // 2MB
        unsigned short* wkh   = (unsigned short*)(wsb + (138u << 20));
        unsigned short* wvh   = (unsigned short*)(wsb + (140u << 20));
        unsigned short* woh   = (unsigned short*)(wsb + (142u << 20));
        unsigned short* m1h   = (unsigned short*)(wsb + (144u << 20)); // 0.5MB
        unsigned short* m2h   = (unsigned short*)(wsb + (145u << 20));

        split_all<<<12800, blk, 0, stream>>>(
            query, Wq, Wk, Wv, Wo, Wm1, Wm2,
            qh, wqh, wkh, wvh, woh, m1h, m2h);

        // Fused Q/K/V projections (A staged once); Q emitted fp16 pre-scaled
        gemm_qkv<<<dim3(PM / 128, PE / 128), dim3(512), 0, stream>>>(
            qh, wqh, wkh, wvh, bq, bk, bv, qh16, kf, vtf);

        gemm_pl<5, true><<<dim3(PM / 128, 256 / 128), blk, 0, stream>>>(
            qh, m1h, bm1, nullptr, h1h, PM, 256, PE,
            nullptr, nullptr, nullptr, nullptr, nullptr, nullptr, nullptr);

        flash_mfma<<<dim3(PS / 128, PH, PB), blk, 0, stream>>>(
            qh16, kf, vtf, attnb);

        gemm_pl<6, false><<<dim3(PM / 128, PE / 128), blk, 0, stream>>>(
            h1h, m2h, bm2, nullptr, afh, PM, PE, 256,
            attnb, dop, ser, nor, ach, asc, abi);
        gemm_pl<0, false><<<dim3(PM / 128, PE / 128), blk, 0, stream>>>(
            afh, woh, bo, out, nullptr, PM, PE, PE,
            nullptr, nullptr, nullptr, nullptr, nullptr, nullptr, nullptr);
    } else {
        // fallback: fp32-fed bf16 3-term GEMMs + fp16 flash.
        // qh16 overlays the attnf region (dead until after flash).
        float* h1    = (float*)(wsb + (64u << 20));   // 8MB
        float* attnf = (float*)(wsb + (72u << 20));   // 32MB
        unsigned short* qh16 = (unsigned short*)(wsb + (72u << 20)); // 16MB

        gemm_nt<1, false><<<dim3(PM / 128, PE / 128), blk, 0, stream>>>(
            query, Wq, bq, nullptr, qh16, PM, PE, PE,
            nullptr, nullptr, nullptr, nullptr, nullptr, nullptr, nullptr);
        gemm_nt<3, false><<<dim3(PM / 128, PE / 128), blk, 0, stream>>>(
            query, Wk, bk, nullptr, kf, PM, PE, PE,
            nullptr, nullptr, nullptr, nullptr, nullptr, nullptr, nullptr);
        gemm_nt<4, false><<<dim3(PM / 128, PE / 128), blk, 0, stream>>>(
            query, Wv, bv, nullptr, vtf, PM, PE, PE,
            nullptr, nullptr, nullptr, nullptr, nullptr, nullptr, nullptr);
        gemm_nt<0, true><<<dim3(PM / 128, 256 / 128), blk, 0, stream>>>(
            query, Wm1, bm1, h1, nullptr, PM, 256, PE,
            nullptr, nullptr, nullptr, nullptr, nullptr, nullptr, nullptr);

        flash_mfma<<<dim3(PS / 128, PH, PB), blk, 0, stream>>>(
            qh16, kf, vtf, attnb);

        gemm_nt<2, false><<<dim3(PM / 128, PE / 128), blk, 0, stream>>>(
            h1, Wm2, bm2, attnf, nullptr, PM, PE, 256,
            attnb, dop, ser, nor, ach, asc, abi);
        gemm_nt<0, false><<<dim3(PM / 128, PE / 128), blk, 0, stream>>>(
            attnf, Wo, bo, out, nullptr, PM, PE, PE,
            nullptr, nullptr, nullptr, nullptr, nullptr, nullptr, nullptr);
    }
}

// Round 18
// 207.697 us; speedup vs baseline: 1.5546x; 1.0284x over previous
//
#include <hip/hip_runtime.h>
#include <hip/hip_bf16.h>
#include <cstdint>

// Problem constants
#define PB 4
#define PS 2048
#define PE 1024
#define PH 16
#define PD 64
#define PM (PB * PS)      // 8192 rows

typedef __attribute__((ext_vector_type(8))) _Float16 half8;  // 8 fp16 (4 VGPR)
typedef __attribute__((ext_vector_type(4))) float f32x4;

#define MFMAH __builtin_amdgcn_mfma_f32_16x16x32_f16

#define GLOAD_LDS(gp, lp) __builtin_amdgcn_global_load_lds(                    \
    (const __attribute__((address_space(1))) void*)(gp),                       \
    (__attribute__((address_space(3))) void*)(lp), 16, 0, 0)

#if __has_builtin(__builtin_amdgcn_exp2f)
#define FAST_EXP2 1
#define QSC (0.125f * 1.4426950408889634f)   // exp2 domain
#define FTHR 11.5415603f                     // 8*log2(e)
#define EXP_P(x) __builtin_amdgcn_exp2f(x)
#else
#define FAST_EXP2 0
#define QSC 0.125f
#define FTHR 8.f
#define EXP_P(x) __expf(x)
#endif

// fp32 -> fp16 RNE bit pattern
__device__ inline unsigned short h16(float x) {
    _Float16 h = (_Float16)x;
    unsigned short u;
    __builtin_memcpy(&u, &h, 2);
    return u;
}
__device__ inline float f16tof(unsigned short u) {
    _Float16 h;
    __builtin_memcpy(&h, &u, 2);
    return (float)h;
}
// packed fp16 pair via v_cvt_pkrtz_f16_f32; returns the 32-bit word
__device__ inline unsigned pkrtz(float a, float b) {
    auto p = __builtin_amdgcn_cvt_pkrtz(a, b);   // __fp16 ext_vector(2)
    unsigned u;
    __builtin_memcpy(&u, &p, 4);
    return u;
}

// ---------------------------------------------------------------------------
// split_all: all 7 fp32 operands -> single fp16 planes, one launch.
// ---------------------------------------------------------------------------
__global__ __launch_bounds__(256)
void split_all(const float* __restrict__ q,   const float* __restrict__ wq,
               const float* __restrict__ wk,  const float* __restrict__ wv,
               const float* __restrict__ wo,  const float* __restrict__ wm1,
               const float* __restrict__ wm2,
               unsigned short* qh,  unsigned short* wqh, unsigned short* wkh,
               unsigned short* wvh, unsigned short* woh,
               unsigned short* m1h, unsigned short* m2h)
{
    const int b = blockIdx.x;
    const float* src; unsigned short* dst; int base;
    if      (b <  8192) { src = q;   dst = qh;  base = 0;     }
    else if (b <  9216) { src = wq;  dst = wqh; base = 8192;  }
    else if (b < 10240) { src = wk;  dst = wkh; base = 9216;  }
    else if (b < 11264) { src = wv;  dst = wvh; base = 10240; }
    else if (b < 12288) { src = wo;  dst = woh; base = 11264; }
    else if (b < 12544) { src = wm1; dst = m1h; base = 12288; }
    else                { src = wm2; dst = m2h; base = 12544; }
    const int i = (b - base) * 256 + threadIdx.x;
    float4 f = ((const float4*)src)[i];
    ushort4 h;
    h.x = h16(f.x); h.y = h16(f.y); h.z = h16(f.z); h.w = h16(f.w);
    ((ushort4*)dst)[i] = h;
}

// ---------------------------------------------------------------------------
// Fused QKV projection (round-16 proven): 512 threads, 128KB dbuf LDS,
// stages A once for Q/K/V. Epilogues: Q fp16 PRE-SCALED at BHSD, K fp16
// BHSD, V fp16 BHDS with PV seq permutation.
// ---------------------------------------------------------------------------
__global__ __launch_bounds__(512, 2)
void gemm_qkv(const unsigned short* __restrict__ Ah,
              const unsigned short* __restrict__ Wqh,
              const unsigned short* __restrict__ Wkh,
              const unsigned short* __restrict__ Wvh,
              const float* __restrict__ bq, const float* __restrict__ bk,
              const float* __restrict__ bv,
              unsigned short* __restrict__ qh16, unsigned short* __restrict__ kf,
              unsigned short* __restrict__ vtf)
{
    __shared__ int4 ldsq[8192];                 // 128 KB = 2 bufs x 4 planes
    char* const lds = (char*)ldsq;
    const int K = PE;

    const int tid  = threadIdx.x;
    const int lane = tid & 63;
    const int w    = tid >> 6;
    const int lq   = lane & 15;
    const int lg   = lane >> 4;
    const int wr   = w >> 2;
    const int wc   = w & 3;
    const int m0   = blockIdx.x * 128;
    const int n0   = blockIdx.y * 128;

    const int plane = w >> 1;
    const unsigned short* const gp =
        (plane == 0) ? Ah  + (size_t)m0 * K :
        (plane == 1) ? Wqh + (size_t)n0 * K :
        (plane == 2) ? Wkh + (size_t)n0 * K :
                       Wvh + (size_t)n0 * K;
    const int pbase = plane * 16384;
    const int ch0   = (w & 1) * 8;
    const int scol8 = (((lane & 7) ^ (lane >> 3)) << 3);
    const int lrow8 = lane >> 3;

    auto ISSUE = [&](int k0, int bufn) {
        #pragma unroll
        for (int r = 0; r < 8; ++r) {
            const int c   = ch0 + r;
            const int row = c * 8 + lrow8;
            GLOAD_LDS(gp + (size_t)row * K + k0 + scol8,
                      lds + bufn * 65536 + pbase + c * 1024 + 16 * lane);
        }
    };

    f32x4 acc[3][4][2];
    #pragma unroll
    for (int o = 0; o < 3; ++o)
        #pragma unroll
        for (int mt = 0; mt < 4; ++mt)
            #pragma unroll
            for (int nt = 0; nt < 2; ++nt)
                acc[o][mt][nt] = (f32x4){0.f, 0.f, 0.f, 0.f};

    ISSUE(0, 0);
    __syncthreads();

    int buf = 0;
    for (int k0 = 0; k0 < K; k0 += 64) {
        if (k0 + 64 < K) ISSUE(k0 + 64, buf ^ 1);

        const char* const L = lds + buf * 65536;
        #pragma unroll
        for (int kh = 0; kh < 2; ++kh) {
            half8 af[4];
            #pragma unroll
            for (int mt = 0; mt < 4; ++mt) {
                const int row = 64 * wr + 16 * mt + lq;
                const int off = row * 128 + ((kh * 64 + 16 * lg) ^ ((row & 7) << 4));
                af[mt] = *(const half8*)(L + off);
            }
            #pragma unroll
            for (int o = 0; o < 3; ++o) {
                #pragma unroll
                for (int nt = 0; nt < 2; ++nt) {
                    const int row = 32 * wc + 16 * nt + lq;
                    const int off = row * 128 + ((kh * 64 + 16 * lg) ^ ((row & 7) << 4));
                    half8 bf = *(const half8*)(L + 16384 * (o + 1) + off);
                    #pragma unroll
                    for (int mt = 0; mt < 4; ++mt)
                        acc[o][mt][nt] = MFMAH(af[mt], bf, acc[o][mt][nt], 0, 0, 0);
                }
            }
        }
        __syncthreads();
        buf ^= 1;
    }

    #pragma unroll
    for (int nt = 0; nt < 2; ++nt) {
        const int n = n0 + 32 * wc + 16 * nt + lq;
        const int h = n >> 6, d = n & 63;
        const float bqv = bq[n], bkv = bk[n], bvv = bv[n];
        #pragma unroll
        for (int mt = 0; mt < 4; ++mt) {
            #pragma unroll
            for (int j = 0; j < 4; ++j) {
                const int m = m0 + 64 * wr + 16 * mt + 4 * lg + j;
                const int b = m >> 11, s = m & 2047;
                qh16[((size_t)(b * PH + h) * PS + s) * PD + d] =
                    h16((acc[0][mt][nt][j] + bqv) * QSC);
                kf[((size_t)(b * PH + h) * PS + s) * PD + d] =
                    h16(acc[1][mt][nt][j] + bkv);
                const int scol = (s & ~63) + ((mt & 1) << 5) + (lg << 3)
                               + ((mt >> 1) << 2) + j;
                vtf[((size_t)(b * PH + h) * PD + d) * PS + scol] =
                    h16(acc[2][mt][nt][j] + bvv);
            }
        }
    }
}

// ---------------------------------------------------------------------------
// Plane-fed single-fp16 MFMA NT GEMM (round-15 proven engine, unchanged).
// MODE 0: fp32 C[m*N+n] (optional RELU) | MODE 5: fp16 plane [M][N]
// ---------------------------------------------------------------------------
template<int MODE, bool RELU>
__global__ __launch_bounds__(256, 2)
void gemm_pl(const unsigned short* __restrict__ Ah,
             const unsigned short* __restrict__ Bh,
             const float* __restrict__ bias, float* __restrict__ C,
             unsigned short* __restrict__ Oh,
             int M, int N, int K)
{
    __shared__ int4 ldsq[4096];                 // 64 KB = 2 bufs x 32 KB
    char* const lds = (char*)ldsq;

    const int tid  = threadIdx.x;
    const int lane = tid & 63;
    const int w    = tid >> 6;
    const int lq   = lane & 15;
    const int lg   = lane >> 4;
    const int wm   = (w >> 1) * 64;
    const int wn   = (w & 1) * 64;
    const int m0   = blockIdx.x * 128;
    const int n0   = blockIdx.y * 128;

    const unsigned short* const gp =
        (w < 2) ? Ah + (size_t)m0 * K : Bh + (size_t)n0 * K;
    const int pb    = (w < 2) ? 0 : 16384;
    const int ch0   = (w & 1) * 8;
    const int scol8 = (((lane & 7) ^ (lane >> 3)) << 3);
    const int lrow8 = lane >> 3;

    auto ISSUE = [&](int k0, int bufn) {
        #pragma unroll
        for (int r = 0; r < 8; ++r) {
            const int c   = ch0 + r;
            const int row = c * 8 + lrow8;
            GLOAD_LDS(gp + (size_t)row * K + k0 + scol8,
                      lds + bufn * 32768 + pb + c * 1024 + 16 * lane);
        }
    };

    f32x4 acc[4][4];
    #pragma unroll
    for (int mt = 0; mt < 4; ++mt)
        #pragma unroll
        for (int nt = 0; nt < 4; ++nt)
            acc[mt][nt] = (f32x4){0.f, 0.f, 0.f, 0.f};

    ISSUE(0, 0);
    __syncthreads();

    int buf = 0;
    for (int k0 = 0; k0 < K; k0 += 64) {
        if (k0 + 64 < K) ISSUE(k0 + 64, buf ^ 1);

        const char* const L = lds + buf * 32768;
        #pragma unroll
        for (int kh = 0; kh < 2; ++kh) {
            half8 af[4];
            #pragma unroll
            for (int mt = 0; mt < 4; ++mt) {
                const int row = wm + 16 * mt + lq;
                const int off = row * 128 + ((kh * 64 + 16 * lg) ^ ((row & 7) << 4));
                af[mt] = *(const half8*)(L + off);
            }
            #pragma unroll
            for (int nt = 0; nt < 4; ++nt) {
                const int row = wn + 16 * nt + lq;
                const int off = row * 128 + ((kh * 64 + 16 * lg) ^ ((row & 7) << 4));
                half8 bf = *(const half8*)(L + 16384 + off);
                #pragma unroll
                for (int mt = 0; mt < 4; ++mt)
                    acc[mt][nt] = MFMAH(af[mt], bf, acc[mt][nt], 0, 0, 0);
            }
        }
        __syncthreads();
        buf ^= 1;
    }

    #pragma unroll
    for (int nt = 0; nt < 4; ++nt) {
        const int n  = n0 + wn + 16 * nt + lq;
        const float bv = bias[n];
        #pragma unroll
        for (int mt = 0; mt < 4; ++mt) {
            #pragma unroll
            for (int j = 0; j < 4; ++j) {
                const int m = m0 + wm + 16 * mt + 4 * lg + j;
                float v = acc[mt][nt][j] + bv;
                if (RELU) v = fmaxf(v, 0.f);
                if (MODE == 0) {
                    C[(size_t)m * N + n] = v;
                } else { // MODE 5
                    Oh[(size_t)m * N + n] = h16(v);
                }
            }
        }
    }
}

// ---------------------------------------------------------------------------
// fp32-fed fallback GEMM (bf16 3-term internally, round-5 proven skeleton);
// MODE 1 emits PRE-SCALED fp16 Q; MODE 3/4 emit fp16 planes.
// ---------------------------------------------------------------------------
typedef __attribute__((ext_vector_type(8))) short short8;
#define MFMA16 __builtin_amdgcn_mfma_f32_16x16x32_bf16
__device__ inline unsigned short bf16rn(float x) {
    unsigned u = __builtin_bit_cast(unsigned, x);
    u += 0x7FFFu + ((u >> 16) & 1u);
    return (unsigned short)(u >> 16);
}
__device__ inline float bf16tof(unsigned short h) {
    unsigned u = ((unsigned)h) << 16;
    return __builtin_bit_cast(float, u);
}
__device__ inline void split2(float x, unsigned short& h, unsigned short& l) {
    h = bf16rn(x);
    l = bf16rn(x - bf16tof(h));
}

template<int MODE, bool RELU>
__global__ __launch_bounds__(256, 2)
void gemm_nt(const float* __restrict__ A, const float* __restrict__ Bw,
             const float* __restrict__ bias, float* __restrict__ C,
             unsigned short* __restrict__ Ohi,
             int M, int N, int K,
             const float* __restrict__ attn,
             const float* __restrict__ g0, const float* __restrict__ g1,
             const float* __restrict__ g2, const float* __restrict__ g3,
             const float* __restrict__ asc, const float* __restrict__ abi)
{
    __shared__ int4 ldsq[4096];
    char* const lds = (char*)ldsq;

    const int tid  = threadIdx.x;
    const int lane = tid & 63;
    const int w    = tid >> 6;
    const int lq   = lane & 15;
    const int lg   = lane >> 4;
    const int wm   = (w >> 1) * 64;
    const int wn   = (w & 1) * 64;
    const int m0   = blockIdx.x * 128;
    const int n0   = blockIdx.y * 128;

    const int irow = tid >> 3;
    const int ic8  = (tid & 7) * 8;
    const int woff = (ic8 * 2);

    f32x4 acc[4][4];
    #pragma unroll
    for (int mt = 0; mt < 4; ++mt)
        #pragma unroll
        for (int nt = 0; nt < 4; ++nt)
            acc[mt][nt] = (f32x4){0.f, 0.f, 0.f, 0.f};

    for (int k0 = 0; k0 < K; k0 += 64) {
        #pragma unroll
        for (int mat = 0; mat < 2; ++mat) {
            const float* const src = mat ? Bw : A;
            const int rbase = mat ? n0 : m0;
            const int pbase = mat ? 32768 : 0;
            #pragma unroll
            for (int r = 0; r < 4; ++r) {
                const int row = irow + 32 * r;
                const float* p = src + (size_t)(rbase + row) * K + k0 + ic8;
                float4 f0 = *(const float4*)p;
                float4 f1 = *(const float4*)(p + 4);
                short8 vh, vl;
                {
                    unsigned short h, l;
                    split2(f0.x, h, l); vh[0] = (short)h; vl[0] = (short)l;
                    split2(f0.y, h, l); vh[1] = (short)h; vl[1] = (short)l;
                    split2(f0.z, h, l); vh[2] = (short)h; vl[2] = (short)l;
                    split2(f0.w, h, l); vh[3] = (short)h; vl[3] = (short)l;
                    split2(f1.x, h, l); vh[4] = (short)h; vl[4] = (short)l;
                    split2(f1.y, h, l); vh[5] = (short)h; vl[5] = (short)l;
                    split2(f1.z, h, l); vh[6] = (short)h; vl[6] = (short)l;
                    split2(f1.w, h, l); vh[7] = (short)h; vl[7] = (short)l;
                }
                const int off = row * 128 + (woff ^ ((row & 7) << 4));
                *(short8*)(lds + pbase + off)         = vh;
                *(short8*)(lds + pbase + 16384 + off) = vl;
            }
        }
        __syncthreads();

        #pragma unroll
        for (int kh = 0; kh < 2; ++kh) {
            short8 afh[4], afl[4];
            #pragma unroll
            for (int mt = 0; mt < 4; ++mt) {
                const int row = wm + 16 * mt + lq;
                const int off = row * 128 + ((kh * 64 + 16 * lg) ^ ((row & 7) << 4));
                afh[mt] = *(const short8*)(lds + off);
                afl[mt] = *(const short8*)(lds + 16384 + off);
            }
            #pragma unroll
            for (int nt = 0; nt < 4; ++nt) {
                const int row = wn + 16 * nt + lq;
                const int off = row * 128 + ((kh * 64 + 16 * lg) ^ ((row & 7) << 4));
                short8 bfh = *(const short8*)(lds + 32768 + off);
                short8 bfl = *(const short8*)(lds + 49152 + off);
                #pragma unroll
                for (int mt = 0; mt < 4; ++mt) {
                    acc[mt][nt] = MFMA16(afh[mt], bfh, acc[mt][nt], 0, 0, 0);
                    acc[mt][nt] = MFMA16(afh[mt], bfl, acc[mt][nt], 0, 0, 0);
                    acc[mt][nt] = MFMA16(afl[mt], bfh, acc[mt][nt], 0, 0, 0);
                }
            }
        }
        __syncthreads();
    }

    float gain = 0.f, ascv = 0.f, abiv = 0.f;
    if (MODE == 2) {
        gain = 0.25f * (*g0 + *g1 + *g2 + *g3);
        ascv = *asc;
        abiv = *abi;
    }

    #pragma unroll
    for (int nt = 0; nt < 4; ++nt) {
        const int n  = n0 + wn + 16 * nt + lq;
        const float bv = bias[n];
        #pragma unroll
        for (int mt = 0; mt < 4; ++mt) {
            #pragma unroll
            for (int j = 0; j < 4; ++j) {
                const int m = m0 + wm + 16 * mt + 4 * lg + j;
                float v = acc[mt][nt][j] + bv;
                if (RELU) v = fmaxf(v, 0.f);
                if (MODE == 0) {
                    C[(size_t)m * N + n] = v;
                } else if (MODE == 1) {
                    const int b = m >> 11, s = m & 2047;
                    const int h = n >> 6, d = n & 63;
                    Ohi[((size_t)(b * PH + h) * PS + s) * PD + d] = h16(v * QSC);
                } else if (MODE == 3) {
                    const int b = m >> 11, s = m & 2047;
                    const int h = n >> 6, d = n & 63;
                    Ohi[((size_t)(b * PH + h) * PS + s) * PD + d] = h16(v);
                } else if (MODE == 4) {
                    const int b = m >> 11;
                    const int h = n >> 6, d = n & 63;
                    const int scol = (m & 2047 & ~63) + ((mt & 1) << 5)
                                   + (lg << 3) + ((mt >> 1) << 2) + j;
                    Ohi[((size_t)(b * PH + h) * PD + d) * PS + scol] = h16(v);
                } else { // MODE 2
                    const int b = m >> 11, s = m & 2047;
                    const int h = n >> 6, d = n & 63;
                    const float av = attn[((size_t)(b * PH + h) * PS + s) * PD + d];
                    C[(size_t)m * N + n] = (av * ascv + abiv) * (1.f + v * gain);
                }
            }
        }
    }
}

// ---------------------------------------------------------------------------
// MFMA flash attention v11 = v10 engine, FUSE template:
// FUSE=1: epilogue applies the neuromod combine — reads modh fp16 [M][E]
//         and scalars, writes fp16 attnf plane [M][E] (Wo's A input).
// FUSE=0: round-17 behavior (fp32 attn BHSD) for the fallback path.
// ---------------------------------------------------------------------------
template<int FUSE>
__global__ __launch_bounds__(256, 4)
void flash_mfma(const unsigned short* __restrict__ qh16,
                const unsigned short* __restrict__ kf,
                const unsigned short* __restrict__ vtf,
                const unsigned short* __restrict__ modh,
                const float* __restrict__ g0, const float* __restrict__ g1,
                const float* __restrict__ g2, const float* __restrict__ g3,
                const float* __restrict__ asc, const float* __restrict__ abi,
                unsigned short* __restrict__ afh, float* __restrict__ attn)
{
    __shared__ int4 ldsv[2048];                    // 32 KB: 2 bufs x (K8K + V8K)
    char* const ldsb = (char*)ldsv;

    const int tid  = threadIdx.x;
    const int lane = tid & 63;
    const int w    = tid >> 6;
    const int lq   = lane & 15;
    const int lg   = lane >> 4;

    // XCD swizzle: each XCD owns 128 consecutive logical blocks (= 8 bh).
    const int L  = blockIdx.x + (blockIdx.y << 4) + (blockIdx.z << 8);
    const int nL = ((L & 7) << 7) + (L >> 3);
    const int bh = nL >> 4;
    const int q0 = (nL & 15) * 128 + w * 32;

    const size_t kbase = (size_t)bh * PS * PD;   // K rows   [S][D]
    const size_t vbase = (size_t)bh * PD * PS;   // V^T rows [D][S] (permuted)

    const unsigned short* const gp = (w < 2) ? kf + kbase : vtf + vbase;
    const bool isK = (w < 2);
    const int ch0   = (w & 1) * 4;
    const int scol8 = (((lane & 7) ^ (lane >> 3)) << 3);   // pre-swizzled col
    const int lrow8 = lane >> 3;

    auto ISSUE = [&](int kt, int bufn) {
        #pragma unroll
        for (int r = 0; r < 4; ++r) {
            const int c   = ch0 + r;
            const int row = c * 8 + lrow8;
            const size_t goff = isK ? (size_t)(kt + row) * PD + scol8
                                    : (size_t)row * PS + kt + scol8;
            GLOAD_LDS(gp + goff,
                      ldsb + bufn * 16384 + (isK ? 0 : 8192) + c * 1024 + 16 * lane);
        }
    };

    const half8 onesh = {(_Float16)1.f, (_Float16)1.f, (_Float16)1.f,
                         (_Float16)1.f, (_Float16)1.f, (_Float16)1.f,
                         (_Float16)1.f, (_Float16)1.f};

    // ---- Q fragments: pre-scaled fp16 plane, direct vector loads
    half8 qh[2][2];
    #pragma unroll
    for (int u = 0; u < 2; ++u) {
        const unsigned short* qp =
            qh16 + ((size_t)bh * PS + q0 + 16 * u + lq) * PD + 8 * lg;
        qh[u][0] = *(const half8*)(qp);
        qh[u][1] = *(const half8*)(qp + 32);
    }

    f32x4 ot[2][4];
    #pragma unroll
    for (int u = 0; u < 2; ++u)
        #pragma unroll
        for (int mt = 0; mt < 4; ++mt)
            ot[u][mt] = (f32x4){0.f, 0.f, 0.f, 0.f};
    f32x4 lacc[2] = {{0.f,0.f,0.f,0.f}, {0.f,0.f,0.f,0.f}};
    float m_run[2] = {-3.0e38f, -3.0e38f};

    ISSUE(0, 0);
    __syncthreads();

    int buf = 0;
    for (int kti = 0; kti < PS / 64; ++kti) {
        const bool pf = (kti + 1 < PS / 64);
        if (pf) ISSUE((kti + 1) * 64, buf ^ 1);

        const char* const L2 = ldsb + buf * 16384;

        // ---- S^T tiles, Q single fp16: 2 MFMA per mt/u
        f32x4 st[2][4];
        #pragma unroll
        for (int mt = 0; mt < 4; ++mt) {
            const int row = 16 * mt + lq;
            const int swz = (row & 7) << 4;
            const char* kr = L2 + row * 128;
            half8 a0 = *(const half8*)(kr + ((16 * lg) ^ swz));
            half8 a1 = *(const half8*)(kr + ((64 + 16 * lg) ^ swz));
            #pragma unroll
            for (int u = 0; u < 2; ++u) {
                f32x4 acc = {0.f, 0.f, 0.f, 0.f};
                acc = MFMAH(a0, qh[u][0], acc, 0, 0, 0);
                acc = MFMAH(a1, qh[u][1], acc, 0, 0, 0);
                st[u][mt] = acc;
            }
        }

        // ---- online softmax (defer-max) + P pack (pkrtz) + l via MFMA
        half8 pb[2][2];
        #pragma unroll
        for (int u = 0; u < 2; ++u) {
            float a0 = fmaxf(fmaxf(st[u][0][0], st[u][0][1]), st[u][0][2]);
            float a1 = fmaxf(fmaxf(st[u][0][3], st[u][1][0]), st[u][1][1]);
            float a2 = fmaxf(fmaxf(st[u][1][2], st[u][1][3]), st[u][2][0]);
            float a3 = fmaxf(fmaxf(st[u][2][1], st[u][2][2]), st[u][2][3]);
            float a4 = fmaxf(fmaxf(st[u][3][0], st[u][3][1]), st[u][3][2]);
            float b0 = fmaxf(fmaxf(a0, a1), a2);
            float b1 = fmaxf(fmaxf(a3, a4), st[u][3][3]);
            float pmax = fmaxf(b0, b1);
            pmax = fmaxf(pmax, __shfl_xor(pmax, 16));
            pmax = fmaxf(pmax, __shfl_xor(pmax, 32));
            if (!__all(pmax - m_run[u] <= FTHR)) {   // rare: rescale path
                float mnew = fmaxf(m_run[u], pmax);
                float corr = EXP_P(m_run[u] - mnew);
                m_run[u] = mnew;
                #pragma unroll
                for (int j = 0; j < 4; ++j)
                    lacc[u][j] *= corr;
                #pragma unroll
                for (int mt = 0; mt < 4; ++mt)
                    #pragma unroll
                    for (int j = 0; j < 4; ++j)
                        ot[u][mt][j] *= corr;
            }
            #pragma unroll
            for (int mt = 0; mt < 4; ++mt)
                #pragma unroll
                for (int j = 0; j < 4; ++j)
                    st[u][mt][j] = EXP_P(st[u][mt][j] - m_run[u]);
            #pragma unroll
            for (int t = 0; t < 2; ++t) {
                unsigned w0 = pkrtz(st[u][t][0],     st[u][t][1]);
                unsigned w1 = pkrtz(st[u][t][2],     st[u][t][3]);
                unsigned w2 = pkrtz(st[u][t + 2][0], st[u][t + 2][1]);
                unsigned w3 = pkrtz(st[u][t + 2][2], st[u][t + 2][3]);
                uint4 pw = make_uint4(w0, w1, w2, w3);
                __builtin_memcpy(&pb[u][t], &pw, 16);
            }
            lacc[u] = MFMAH(onesh, pb[u][0], lacc[u], 0, 0, 0);
            lacc[u] = MFMAH(onesh, pb[u][1], lacc[u], 0, 0, 0);
        }

        // ---- O^T += V^T . P^T   (V single fp16, P fp16: 1 MFMA each)
        #pragma unroll
        for (int t = 0; t < 2; ++t) {
            #pragma unroll
            for (int mt = 0; mt < 4; ++mt) {
                const int row = 16 * mt + lq;
                const int swz = (row & 7) << 4;
                const char* vr = L2 + 8192 + row * 128;
                half8 vv = *(const half8*)(vr + ((t * 64 + 16 * lg) ^ swz));
                #pragma unroll
                for (int u = 0; u < 2; ++u)
                    ot[u][mt] = MFMAH(vv, pb[u][t], ot[u][mt], 0, 0, 0);
            }
        }

        __syncthreads();        // drains prefetch vmcnt + protects LDS reuse
        buf ^= 1;
    }

    // ---- epilogue
    if (FUSE) {
        const float gain = 0.25f * (*g0 + *g1 + *g2 + *g3);
        const float ascv = *asc, abiv = *abi;
        const int bb = bh >> 4, hh = bh & 15;
        #pragma unroll
        for (int u = 0; u < 2; ++u) {
            const int m = bb * PS + q0 + 16 * u + lq;
            const unsigned short* mp = modh + (size_t)m * PE + hh * 64 + 4 * lg;
            unsigned short* op = afh + (size_t)m * PE + hh * 64 + 4 * lg;
            const float inv = 1.f / lacc[u][0];
            #pragma unroll
            for (int mt = 0; mt < 4; ++mt) {
                ushort4 mv = *(const ushort4*)(mp + 16 * mt);
                ushort4 ov;
                ov.x = h16((ot[u][mt][0] * inv * ascv + abiv) * (1.f + f16tof(mv.x) * gain));
                ov.y = h16((ot[u][mt][1] * inv * ascv + abiv) * (1.f + f16tof(mv.y) * gain));
                ov.z = h16((ot[u][mt][2] * inv * ascv + abiv) * (1.f + f16tof(mv.z) * gain));
                ov.w = h16((ot[u][mt][3] * inv * ascv + abiv) * (1.f + f16tof(mv.w) * gain));
                *(ushort4*)(op + 16 * mt) = ov;
            }
        }
    } else {
        #pragma unroll
        for (int u = 0; u < 2; ++u) {
            const float inv = 1.f / lacc[u][0];
            float* op = attn + ((size_t)bh * PS + q0 + 16 * u + lq) * PD + 4 * lg;
            #pragma unroll
            for (int mt = 0; mt < 4; ++mt) {
                float4 o;
                o.x = ot[u][mt][0] * inv; o.y = ot[u][mt][1] * inv;
                o.z = ot[u][mt][2] * inv; o.w = ot[u][mt][3] * inv;
                *(float4*)(op + 16 * mt) = o;
            }
        }
    }
}

// ---------------------------------------------------------------------------
extern "C" void kernel_launch(void* const* d_in, const int* in_sizes, int n_in,
                              void* d_out, int out_size, void* d_ws, size_t ws_size,
                              hipStream_t stream)
{
    const float* query = (const float*)d_in[0];
    const float* Wq  = (const float*)d_in[1];  const float* bq  = (const float*)d_in[2];
    const float* Wk  = (const float*)d_in[3];  const float* bk  = (const float*)d_in[4];
    const float* Wv  = (const float*)d_in[5];  const float* bv  = (const float*)d_in[6];
    const float* Wo  = (const float*)d_in[7];  const float* bo  = (const float*)d_in[8];
    const float* Wm1 = (const float*)d_in[9];  const float* bm1 = (const float*)d_in[10];
    const float* Wm2 = (const float*)d_in[11]; const float* bm2 = (const float*)d_in[12];
    const float* dop = (const float*)d_in[13];
    const float* ser = (const float*)d_in[14];
    const float* nor = (const float*)d_in[15];
    const float* ach = (const float*)d_in[16];
    const float* asc = (const float*)d_in[17];
    const float* abi = (const float*)d_in[18];
    float* out = (float*)d_out;

    char* wsb = (char*)d_ws;
    // Common: attn fp32 [0,32M) (fallback), kf [32M,48M), vtf [48M,64M)
    float*          attnb = (float*)wsb;
    unsigned short* kf    = (unsigned short*)(wsb + (32u << 20));
    unsigned short* vtf   = (unsigned short*)(wsb + (48u << 20));

    dim3 blk(256);
    const bool presplit = (ws_size >= 161480704ull);             // 154 MB

    if (presplit) {
        unsigned short* h1h   = (unsigned short*)(wsb + (64u << 20));  // 4MB
        unsigned short* afh   = (unsigned short*)(wsb + (72u << 20));  // 16MB
        unsigned short* qh16  = (unsigned short*)(wsb + (88u << 20));  // 16MB
        unsigned short* qh    = (unsigned short*)(wsb + (104u << 20)); // 16MB
        unsigned short* modh  = (unsigned short*)(wsb + (120u << 20)); // 16MB
        unsigned short* wqh   = (unsigned short*)(wsb + (136u << 20)); // 2MB
        unsigned short* wkh   = (unsigned short*)(wsb + (138u << 20));
        unsigned short* wvh   = (unsigned short*)(wsb + (140u << 20));
        unsigned short* woh   = (unsigned short*)(wsb + (142u << 20));
        unsigned short* m1h   = (unsigned short*)(wsb + (144u << 20)); // 0.5MB
        unsigned short* m2h   = (unsigned short*)(wsb + (145u << 20));

        split_all<<<12800, blk, 0, stream>>>(
            query, Wq, Wk, Wv, Wo, Wm1, Wm2,
            qh, wqh, wkh, wvh, woh, m1h, m2h);

        // Fused Q/K/V projections; Q emitted fp16 pre-scaled
        gemm_qkv<<<dim3(PM / 128, PE / 128), dim3(512), 0, stream>>>(
            qh, wqh, wkh, wvh, bq, bk, bv, qh16, kf, vtf);

        // MLP (independent of attention): h1 then mod plane
        gemm_pl<5, true><<<dim3(PM / 128, 256 / 128), blk, 0, stream>>>(
            qh, m1h, bm1, nullptr, h1h, PM, 256, PE);
        gemm_pl<5, false><<<dim3(PM / 128, PE / 128), blk, 0, stream>>>(
            h1h, m2h, bm2, nullptr, modh, PM, PE, 256);

        // Flash with fused neuromod combine -> fp16 attnf plane
        flash_mfma<1><<<dim3(PS / 128, PH, PB), blk, 0, stream>>>(
            qh16, kf, vtf, modh, dop, ser, nor, ach, asc, abi,
            afh, nullptr);

        // Output projection
        gemm_pl<0, false><<<dim3(PM / 128, PE / 128), blk, 0, stream>>>(
            afh, woh, bo, out, nullptr, PM, PE, PE);
    } else {
        // fallback: fp32-fed bf16 3-term GEMMs + fp16 flash (round-17 flow)
        float* h1    = (float*)(wsb + (64u << 20));   // 8MB
        float* attnf = (float*)(wsb + (72u << 20));   // 32MB
        unsigned short* qh16 = (unsigned short*)(wsb + (72u << 20)); // 16MB

        gemm_nt<1, false><<<dim3(PM / 128, PE / 128), blk, 0, stream>>>(
            query, Wq, bq, nullptr, qh16, PM, PE, PE,
            nullptr, nullptr, nullptr, nullptr, nullptr, nullptr, nullptr);
        gemm_nt<3, false><<<dim3(PM / 128, PE / 128), blk, 0, stream>>>(
            query, Wk, bk, nullptr, kf, PM, PE, PE,
            nullptr, nullptr, nullptr, nullptr, nullptr, nullptr, nullptr);
        gemm_nt<4, false><<<dim3(PM / 128, PE / 128), blk, 0, stream>>>(
            query, Wv, bv, nullptr, vtf, PM, PE, PE,
            nullptr, nullptr, nullptr, nullptr, nullptr, nullptr, nullptr);
        gemm_nt<0, true><<<dim3(PM / 128, 256 / 128), blk, 0, stream>>>(
            query, Wm1, bm1, h1, nullptr, PM, 256, PE,
            nullptr, nullptr, nullptr, nullptr, nullptr, nullptr, nullptr);

        flash_mfma<0><<<dim3(PS / 128, PH, PB), blk, 0, stream>>>(
            qh16, kf, vtf, nullptr, nullptr, nullptr, nullptr, nullptr,
            nullptr, nullptr, nullptr, attnb);

        gemm_nt<2, false><<<dim3(PM / 128, PE / 128), blk, 0, stream>>>(
            h1, Wm2, bm2, attnf, nullptr, PM, PE, 256,
            attnb, dop, ser, nor, ach, asc, abi);
        gemm_nt<0, false><<<dim3(PM / 128, PE / 128), blk, 0, stream>>>(
            attnf, Wo, bo, out, nullptr, PM, PE, PE,
            nullptr, nullptr, nullptr, nullptr, nullptr, nullptr, nullptr);
    }
}

// Round 19
// 201.240 us; speedup vs baseline: 1.6045x; 1.0321x over previous
//
#include <hip/hip_runtime.h>
#include <hip/hip_bf16.h>
#include <cstdint>

// Problem constants
#define PB 4
#define PS 2048
#define PE 1024
#define PH 16
#define PD 64
#define PM (PB * PS)      // 8192 rows

typedef __attribute__((ext_vector_type(8))) _Float16 half8;  // 8 fp16 (4 VGPR)
typedef __attribute__((ext_vector_type(4))) float f32x4;

#define MFMAH __builtin_amdgcn_mfma_f32_16x16x32_f16

#define GLOAD_LDS(gp, lp) __builtin_amdgcn_global_load_lds(                    \
    (const __attribute__((address_space(1))) void*)(gp),                       \
    (__attribute__((address_space(3))) void*)(lp), 16, 0, 0)

#if __has_builtin(__builtin_amdgcn_exp2f)
#define FAST_EXP2 1
#define QSC (0.125f * 1.4426950408889634f)   // exp2 domain
#define FTHR 11.5415603f                     // 8*log2(e)
#define EXP_P(x) __builtin_amdgcn_exp2f(x)
#else
#define FAST_EXP2 0
#define QSC 0.125f
#define FTHR 8.f
#define EXP_P(x) __expf(x)
#endif

// fp32 -> fp16 RNE bit pattern
__device__ inline unsigned short h16(float x) {
    _Float16 h = (_Float16)x;
    unsigned short u;
    __builtin_memcpy(&u, &h, 2);
    return u;
}
__device__ inline float f16tof(unsigned short u) {
    _Float16 h;
    __builtin_memcpy(&h, &u, 2);
    return (float)h;
}
// packed fp16 pair via v_cvt_pkrtz_f16_f32; returns the 32-bit word
__device__ inline unsigned pkrtz(float a, float b) {
    auto p = __builtin_amdgcn_cvt_pkrtz(a, b);   // __fp16 ext_vector(2)
    unsigned u;
    __builtin_memcpy(&u, &p, 4);
    return u;
}

// ---------------------------------------------------------------------------
// split_all: all 7 fp32 operands -> single fp16 planes, one launch.
// ---------------------------------------------------------------------------
__global__ __launch_bounds__(256)
void split_all(const float* __restrict__ q,   const float* __restrict__ wq,
               const float* __restrict__ wk,  const float* __restrict__ wv,
               const float* __restrict__ wo,  const float* __restrict__ wm1,
               const float* __restrict__ wm2,
               unsigned short* qh,  unsigned short* wqh, unsigned short* wkh,
               unsigned short* wvh, unsigned short* woh,
               unsigned short* m1h, unsigned short* m2h)
{
    const int b = blockIdx.x;
    const float* src; unsigned short* dst; int base;
    if      (b <  8192) { src = q;   dst = qh;  base = 0;     }
    else if (b <  9216) { src = wq;  dst = wqh; base = 8192;  }
    else if (b < 10240) { src = wk;  dst = wkh; base = 9216;  }
    else if (b < 11264) { src = wv;  dst = wvh; base = 10240; }
    else if (b < 12288) { src = wo;  dst = woh; base = 11264; }
    else if (b < 12544) { src = wm1; dst = m1h; base = 12288; }
    else                { src = wm2; dst = m2h; base = 12544; }
    const int i = (b - base) * 256 + threadIdx.x;
    float4 f = ((const float4*)src)[i];
    ushort4 h;
    h.x = h16(f.x); h.y = h16(f.y); h.z = h16(f.z); h.w = h16(f.w);
    ((ushort4*)dst)[i] = h;
}

// ---------------------------------------------------------------------------
// Fused QKV projection (round-16 proven): 512 threads, 128KB dbuf LDS,
// stages A once for Q/K/V. Epilogues: Q fp16 PRE-SCALED at BHSD, K fp16
// BHSD, V fp16 BHDS with PV seq permutation.
// ---------------------------------------------------------------------------
__global__ __launch_bounds__(512, 2)
void gemm_qkv(const unsigned short* __restrict__ Ah,
              const unsigned short* __restrict__ Wqh,
              const unsigned short* __restrict__ Wkh,
              const unsigned short* __restrict__ Wvh,
              const float* __restrict__ bq, const float* __restrict__ bk,
              const float* __restrict__ bv,
              unsigned short* __restrict__ qh16, unsigned short* __restrict__ kf,
              unsigned short* __restrict__ vtf)
{
    __shared__ int4 ldsq[8192];                 // 128 KB = 2 bufs x 4 planes
    char* const lds = (char*)ldsq;
    const int K = PE;

    const int tid  = threadIdx.x;
    const int lane = tid & 63;
    const int w    = tid >> 6;
    const int lq   = lane & 15;
    const int lg   = lane >> 4;
    const int wr   = w >> 2;
    const int wc   = w & 3;
    const int m0   = blockIdx.x * 128;
    const int n0   = blockIdx.y * 128;

    const int plane = w >> 1;
    const unsigned short* const gp =
        (plane == 0) ? Ah  + (size_t)m0 * K :
        (plane == 1) ? Wqh + (size_t)n0 * K :
        (plane == 2) ? Wkh + (size_t)n0 * K :
                       Wvh + (size_t)n0 * K;
    const int pbase = plane * 16384;
    const int ch0   = (w & 1) * 8;
    const int scol8 = (((lane & 7) ^ (lane >> 3)) << 3);
    const int lrow8 = lane >> 3;

    auto ISSUE = [&](int k0, int bufn) {
        #pragma unroll
        for (int r = 0; r < 8; ++r) {
            const int c   = ch0 + r;
            const int row = c * 8 + lrow8;
            GLOAD_LDS(gp + (size_t)row * K + k0 + scol8,
                      lds + bufn * 65536 + pbase + c * 1024 + 16 * lane);
        }
    };

    f32x4 acc[3][4][2];
    #pragma unroll
    for (int o = 0; o < 3; ++o)
        #pragma unroll
        for (int mt = 0; mt < 4; ++mt)
            #pragma unroll
            for (int nt = 0; nt < 2; ++nt)
                acc[o][mt][nt] = (f32x4){0.f, 0.f, 0.f, 0.f};

    ISSUE(0, 0);
    __syncthreads();

    int buf = 0;
    for (int k0 = 0; k0 < K; k0 += 64) {
        if (k0 + 64 < K) ISSUE(k0 + 64, buf ^ 1);

        const char* const L = lds + buf * 65536;
        #pragma unroll
        for (int kh = 0; kh < 2; ++kh) {
            half8 af[4];
            #pragma unroll
            for (int mt = 0; mt < 4; ++mt) {
                const int row = 64 * wr + 16 * mt + lq;
                const int off = row * 128 + ((kh * 64 + 16 * lg) ^ ((row & 7) << 4));
                af[mt] = *(const half8*)(L + off);
            }
            #pragma unroll
            for (int o = 0; o < 3; ++o) {
                #pragma unroll
                for (int nt = 0; nt < 2; ++nt) {
                    const int row = 32 * wc + 16 * nt + lq;
                    const int off = row * 128 + ((kh * 64 + 16 * lg) ^ ((row & 7) << 4));
                    half8 bf = *(const half8*)(L + 16384 * (o + 1) + off);
                    #pragma unroll
                    for (int mt = 0; mt < 4; ++mt)
                        acc[o][mt][nt] = MFMAH(af[mt], bf, acc[o][mt][nt], 0, 0, 0);
                }
            }
        }
        __syncthreads();
        buf ^= 1;
    }

    #pragma unroll
    for (int nt = 0; nt < 2; ++nt) {
        const int n = n0 + 32 * wc + 16 * nt + lq;
        const int h = n >> 6, d = n & 63;
        const float bqv = bq[n], bkv = bk[n], bvv = bv[n];
        #pragma unroll
        for (int mt = 0; mt < 4; ++mt) {
            #pragma unroll
            for (int j = 0; j < 4; ++j) {
                const int m = m0 + 64 * wr + 16 * mt + 4 * lg + j;
                const int b = m >> 11, s = m & 2047;
                qh16[((size_t)(b * PH + h) * PS + s) * PD + d] =
                    h16((acc[0][mt][nt][j] + bqv) * QSC);
                kf[((size_t)(b * PH + h) * PS + s) * PD + d] =
                    h16(acc[1][mt][nt][j] + bkv);
                const int scol = (s & ~63) + ((mt & 1) << 5) + (lg << 3)
                               + ((mt >> 1) << 2) + j;
                vtf[((size_t)(b * PH + h) * PD + d) * PS + scol] =
                    h16(acc[2][mt][nt][j] + bvv);
            }
        }
    }
}

// ---------------------------------------------------------------------------
// Plane-fed single-fp16 MFMA NT GEMM (round-15 proven engine, unchanged).
// MODE 0: fp32 C[m*N+n] (optional RELU) | MODE 5: fp16 plane [M][N]
// ---------------------------------------------------------------------------
template<int MODE, bool RELU>
__global__ __launch_bounds__(256, 2)
void gemm_pl(const unsigned short* __restrict__ Ah,
             const unsigned short* __restrict__ Bh,
             const float* __restrict__ bias, float* __restrict__ C,
             unsigned short* __restrict__ Oh,
             int M, int N, int K)
{
    __shared__ int4 ldsq[4096];                 // 64 KB = 2 bufs x 32 KB
    char* const lds = (char*)ldsq;

    const int tid  = threadIdx.x;
    const int lane = tid & 63;
    const int w    = tid >> 6;
    const int lq   = lane & 15;
    const int lg   = lane >> 4;
    const int wm   = (w >> 1) * 64;
    const int wn   = (w & 1) * 64;
    const int m0   = blockIdx.x * 128;
    const int n0   = blockIdx.y * 128;

    const unsigned short* const gp =
        (w < 2) ? Ah + (size_t)m0 * K : Bh + (size_t)n0 * K;
    const int pb    = (w < 2) ? 0 : 16384;
    const int ch0   = (w & 1) * 8;
    const int scol8 = (((lane & 7) ^ (lane >> 3)) << 3);
    const int lrow8 = lane >> 3;

    auto ISSUE = [&](int k0, int bufn) {
        #pragma unroll
        for (int r = 0; r < 8; ++r) {
            const int c   = ch0 + r;
            const int row = c * 8 + lrow8;
            GLOAD_LDS(gp + (size_t)row * K + k0 + scol8,
                      lds + bufn * 32768 + pb + c * 1024 + 16 * lane);
        }
    };

    f32x4 acc[4][4];
    #pragma unroll
    for (int mt = 0; mt < 4; ++mt)
        #pragma unroll
        for (int nt = 0; nt < 4; ++nt)
            acc[mt][nt] = (f32x4){0.f, 0.f, 0.f, 0.f};

    ISSUE(0, 0);
    __syncthreads();

    int buf = 0;
    for (int k0 = 0; k0 < K; k0 += 64) {
        if (k0 + 64 < K) ISSUE(k0 + 64, buf ^ 1);

        const char* const L = lds + buf * 32768;
        #pragma unroll
        for (int kh = 0; kh < 2; ++kh) {
            half8 af[4];
            #pragma unroll
            for (int mt = 0; mt < 4; ++mt) {
                const int row = wm + 16 * mt + lq;
                const int off = row * 128 + ((kh * 64 + 16 * lg) ^ ((row & 7) << 4));
                af[mt] = *(const half8*)(L + off);
            }
            #pragma unroll
            for (int nt = 0; nt < 4; ++nt) {
                const int row = wn + 16 * nt + lq;
                const int off = row * 128 + ((kh * 64 + 16 * lg) ^ ((row & 7) << 4));
                half8 bf = *(const half8*)(L + 16384 + off);
                #pragma unroll
                for (int mt = 0; mt < 4; ++mt)
                    acc[mt][nt] = MFMAH(af[mt], bf, acc[mt][nt], 0, 0, 0);
            }
        }
        __syncthreads();
        buf ^= 1;
    }

    #pragma unroll
    for (int nt = 0; nt < 4; ++nt) {
        const int n  = n0 + wn + 16 * nt + lq;
        const float bv = bias[n];
        #pragma unroll
        for (int mt = 0; mt < 4; ++mt) {
            #pragma unroll
            for (int j = 0; j < 4; ++j) {
                const int m = m0 + wm + 16 * mt + 4 * lg + j;
                float v = acc[mt][nt][j] + bv;
                if (RELU) v = fmaxf(v, 0.f);
                if (MODE == 0) {
                    C[(size_t)m * N + n] = v;
                } else { // MODE 5
                    Oh[(size_t)m * N + n] = h16(v);
                }
            }
        }
    }
}

// ---------------------------------------------------------------------------
// fp32-fed fallback GEMM (bf16 3-term internally, round-5 proven skeleton);
// MODE 1 emits PRE-SCALED fp16 Q; MODE 3/4 emit fp16 planes.
// ---------------------------------------------------------------------------
typedef __attribute__((ext_vector_type(8))) short short8;
#define MFMA16 __builtin_amdgcn_mfma_f32_16x16x32_bf16
__device__ inline unsigned short bf16rn(float x) {
    unsigned u = __builtin_bit_cast(unsigned, x);
    u += 0x7FFFu + ((u >> 16) & 1u);
    return (unsigned short)(u >> 16);
}
__device__ inline float bf16tof(unsigned short h) {
    unsigned u = ((unsigned)h) << 16;
    return __builtin_bit_cast(float, u);
}
__device__ inline void split2(float x, unsigned short& h, unsigned short& l) {
    h = bf16rn(x);
    l = bf16rn(x - bf16tof(h));
}

template<int MODE, bool RELU>
__global__ __launch_bounds__(256, 2)
void gemm_nt(const float* __restrict__ A, const float* __restrict__ Bw,
             const float* __restrict__ bias, float* __restrict__ C,
             unsigned short* __restrict__ Ohi,
             int M, int N, int K,
             const float* __restrict__ attn,
             const float* __restrict__ g0, const float* __restrict__ g1,
             const float* __restrict__ g2, const float* __restrict__ g3,
             const float* __restrict__ asc, const float* __restrict__ abi)
{
    __shared__ int4 ldsq[4096];
    char* const lds = (char*)ldsq;

    const int tid  = threadIdx.x;
    const int lane = tid & 63;
    const int w    = tid >> 6;
    const int lq   = lane & 15;
    const int lg   = lane >> 4;
    const int wm   = (w >> 1) * 64;
    const int wn   = (w & 1) * 64;
    const int m0   = blockIdx.x * 128;
    const int n0   = blockIdx.y * 128;

    const int irow = tid >> 3;
    const int ic8  = (tid & 7) * 8;
    const int woff = (ic8 * 2);

    f32x4 acc[4][4];
    #pragma unroll
    for (int mt = 0; mt < 4; ++mt)
        #pragma unroll
        for (int nt = 0; nt < 4; ++nt)
            acc[mt][nt] = (f32x4){0.f, 0.f, 0.f, 0.f};

    for (int k0 = 0; k0 < K; k0 += 64) {
        #pragma unroll
        for (int mat = 0; mat < 2; ++mat) {
            const float* const src = mat ? Bw : A;
            const int rbase = mat ? n0 : m0;
            const int pbase = mat ? 32768 : 0;
            #pragma unroll
            for (int r = 0; r < 4; ++r) {
                const int row = irow + 32 * r;
                const float* p = src + (size_t)(rbase + row) * K + k0 + ic8;
                float4 f0 = *(const float4*)p;
                float4 f1 = *(const float4*)(p + 4);
                short8 vh, vl;
                {
                    unsigned short h, l;
                    split2(f0.x, h, l); vh[0] = (short)h; vl[0] = (short)l;
                    split2(f0.y, h, l); vh[1] = (short)h; vl[1] = (short)l;
                    split2(f0.z, h, l); vh[2] = (short)h; vl[2] = (short)l;
                    split2(f0.w, h, l); vh[3] = (short)h; vl[3] = (short)l;
                    split2(f1.x, h, l); vh[4] = (short)h; vl[4] = (short)l;
                    split2(f1.y, h, l); vh[5] = (short)h; vl[5] = (short)l;
                    split2(f1.z, h, l); vh[6] = (short)h; vl[6] = (short)l;
                    split2(f1.w, h, l); vh[7] = (short)h; vl[7] = (short)l;
                }
                const int off = row * 128 + (woff ^ ((row & 7) << 4));
                *(short8*)(lds + pbase + off)         = vh;
                *(short8*)(lds + pbase + 16384 + off) = vl;
            }
        }
        __syncthreads();

        #pragma unroll
        for (int kh = 0; kh < 2; ++kh) {
            short8 afh[4], afl[4];
            #pragma unroll
            for (int mt = 0; mt < 4; ++mt) {
                const int row = wm + 16 * mt + lq;
                const int off = row * 128 + ((kh * 64 + 16 * lg) ^ ((row & 7) << 4));
                afh[mt] = *(const short8*)(lds + off);
                afl[mt] = *(const short8*)(lds + 16384 + off);
            }
            #pragma unroll
            for (int nt = 0; nt < 4; ++nt) {
                const int row = wn + 16 * nt + lq;
                const int off = row * 128 + ((kh * 64 + 16 * lg) ^ ((row & 7) << 4));
                short8 bfh = *(const short8*)(lds + 32768 + off);
                short8 bfl = *(const short8*)(lds + 49152 + off);
                #pragma unroll
                for (int mt = 0; mt < 4; ++mt) {
                    acc[mt][nt] = MFMA16(afh[mt], bfh, acc[mt][nt], 0, 0, 0);
                    acc[mt][nt] = MFMA16(afh[mt], bfl, acc[mt][nt], 0, 0, 0);
                    acc[mt][nt] = MFMA16(afl[mt], bfh, acc[mt][nt], 0, 0, 0);
                }
            }
        }
        __syncthreads();
    }

    float gain = 0.f, ascv = 0.f, abiv = 0.f;
    if (MODE == 2) {
        gain = 0.25f * (*g0 + *g1 + *g2 + *g3);
        ascv = *asc;
        abiv = *abi;
    }

    #pragma unroll
    for (int nt = 0; nt < 4; ++nt) {
        const int n  = n0 + wn + 16 * nt + lq;
        const float bv = bias[n];
        #pragma unroll
        for (int mt = 0; mt < 4; ++mt) {
            #pragma unroll
            for (int j = 0; j < 4; ++j) {
                const int m = m0 + wm + 16 * mt + 4 * lg + j;
                float v = acc[mt][nt][j] + bv;
                if (RELU) v = fmaxf(v, 0.f);
                if (MODE == 0) {
                    C[(size_t)m * N + n] = v;
                } else if (MODE == 1) {
                    const int b = m >> 11, s = m & 2047;
                    const int h = n >> 6, d = n & 63;
                    Ohi[((size_t)(b * PH + h) * PS + s) * PD + d] = h16(v * QSC);
                } else if (MODE == 3) {
                    const int b = m >> 11, s = m & 2047;
                    const int h = n >> 6, d = n & 63;
                    Ohi[((size_t)(b * PH + h) * PS + s) * PD + d] = h16(v);
                } else if (MODE == 4) {
                    const int b = m >> 11;
                    const int h = n >> 6, d = n & 63;
                    const int scol = (m & 2047 & ~63) + ((mt & 1) << 5)
                                   + (lg << 3) + ((mt >> 1) << 2) + j;
                    Ohi[((size_t)(b * PH + h) * PD + d) * PS + scol] = h16(v);
                } else { // MODE 2
                    const int b = m >> 11, s = m & 2047;
                    const int h = n >> 6, d = n & 63;
                    const float av = attn[((size_t)(b * PH + h) * PS + s) * PD + d];
                    C[(size_t)m * N + n] = (av * ascv + abiv) * (1.f + v * gain);
                }
            }
        }
    }
}

// ---------------------------------------------------------------------------
// MFMA flash attention v12 = v11 with issue-slot cuts:
//  - QK^T accumulator initialized to -m_run (biased C-init): st = S - m
//    comes out of the matrix pipe, removing 32 v_sub per tile. m_run
//    starts at 0 (scores bounded; P <= 2^THR fits fp16/fp32 easily).
//  - Defer check uses the LOCAL max only (__all covers all lanes); the
//    cross-lane shfl reduce runs only on the rare rescale path.
//  - s_setprio(1/0) around the QK^T and PV MFMA clusters (T5).
// FUSE=1: epilogue applies neuromod combine -> fp16 attnf plane.
// FUSE=0: fp32 attn BHSD (fallback path).
// ---------------------------------------------------------------------------
template<int FUSE>
__global__ __launch_bounds__(256, 4)
void flash_mfma(const unsigned short* __restrict__ qh16,
                const unsigned short* __restrict__ kf,
                const unsigned short* __restrict__ vtf,
                const unsigned short* __restrict__ modh,
                const float* __restrict__ g0, const float* __restrict__ g1,
                const float* __restrict__ g2, const float* __restrict__ g3,
                const float* __restrict__ asc, const float* __restrict__ abi,
                unsigned short* __restrict__ afh, float* __restrict__ attn)
{
    __shared__ int4 ldsv[2048];                    // 32 KB: 2 bufs x (K8K + V8K)
    char* const ldsb = (char*)ldsv;

    const int tid  = threadIdx.x;
    const int lane = tid & 63;
    const int w    = tid >> 6;
    const int lq   = lane & 15;
    const int lg   = lane >> 4;

    // XCD swizzle: each XCD owns 128 consecutive logical blocks (= 8 bh).
    const int L  = blockIdx.x + (blockIdx.y << 4) + (blockIdx.z << 8);
    const int nL = ((L & 7) << 7) + (L >> 3);
    const int bh = nL >> 4;
    const int q0 = (nL & 15) * 128 + w * 32;

    const size_t kbase = (size_t)bh * PS * PD;   // K rows   [S][D]
    const size_t vbase = (size_t)bh * PD * PS;   // V^T rows [D][S] (permuted)

    const unsigned short* const gp = (w < 2) ? kf + kbase : vtf + vbase;
    const bool isK = (w < 2);
    const int ch0   = (w & 1) * 4;
    const int scol8 = (((lane & 7) ^ (lane >> 3)) << 3);   // pre-swizzled col
    const int lrow8 = lane >> 3;

    auto ISSUE = [&](int kt, int bufn) {
        #pragma unroll
        for (int r = 0; r < 4; ++r) {
            const int c   = ch0 + r;
            const int row = c * 8 + lrow8;
            const size_t goff = isK ? (size_t)(kt + row) * PD + scol8
                                    : (size_t)row * PS + kt + scol8;
            GLOAD_LDS(gp + goff,
                      ldsb + bufn * 16384 + (isK ? 0 : 8192) + c * 1024 + 16 * lane);
        }
    };

    const half8 onesh = {(_Float16)1.f, (_Float16)1.f, (_Float16)1.f,
                         (_Float16)1.f, (_Float16)1.f, (_Float16)1.f,
                         (_Float16)1.f, (_Float16)1.f};

    // ---- Q fragments: pre-scaled fp16 plane, direct vector loads
    half8 qh[2][2];
    #pragma unroll
    for (int u = 0; u < 2; ++u) {
        const unsigned short* qp =
            qh16 + ((size_t)bh * PS + q0 + 16 * u + lq) * PD + 8 * lg;
        qh[u][0] = *(const half8*)(qp);
        qh[u][1] = *(const half8*)(qp + 32);
    }

    f32x4 ot[2][4];
    #pragma unroll
    for (int u = 0; u < 2; ++u)
        #pragma unroll
        for (int mt = 0; mt < 4; ++mt)
            ot[u][mt] = (f32x4){0.f, 0.f, 0.f, 0.f};
    f32x4 lacc[2] = {{0.f,0.f,0.f,0.f}, {0.f,0.f,0.f,0.f}};
    float m_run[2] = {0.f, 0.f};           // absolute running max (biased init)

    ISSUE(0, 0);
    __syncthreads();

    int buf = 0;
    for (int kti = 0; kti < PS / 64; ++kti) {
        const bool pf = (kti + 1 < PS / 64);
        if (pf) ISSUE((kti + 1) * 64, buf ^ 1);

        const char* const L2 = ldsb + buf * 16384;

        // ---- S^T tiles with biased C-init: st = S - m_run (no subs later)
        f32x4 st[2][4];
        __builtin_amdgcn_s_setprio(1);
        #pragma unroll
        for (int mt = 0; mt < 4; ++mt) {
            const int row = 16 * mt + lq;
            const int swz = (row & 7) << 4;
            const char* kr = L2 + row * 128;
            half8 a0 = *(const half8*)(kr + ((16 * lg) ^ swz));
            half8 a1 = *(const half8*)(kr + ((64 + 16 * lg) ^ swz));
            #pragma unroll
            for (int u = 0; u < 2; ++u) {
                const float nm = -m_run[u];
                f32x4 acc = {nm, nm, nm, nm};
                acc = MFMAH(a0, qh[u][0], acc, 0, 0, 0);
                acc = MFMAH(a1, qh[u][1], acc, 0, 0, 0);
                st[u][mt] = acc;
            }
        }
        __builtin_amdgcn_s_setprio(0);

        // ---- online softmax (defer-max, biased) + P pack + l via MFMA
        half8 pb[2][2];
        #pragma unroll
        for (int u = 0; u < 2; ++u) {
            float a0 = fmaxf(fmaxf(st[u][0][0], st[u][0][1]), st[u][0][2]);
            float a1 = fmaxf(fmaxf(st[u][0][3], st[u][1][0]), st[u][1][1]);
            float a2 = fmaxf(fmaxf(st[u][1][2], st[u][1][3]), st[u][2][0]);
            float a3 = fmaxf(fmaxf(st[u][2][1], st[u][2][2]), st[u][2][3]);
            float a4 = fmaxf(fmaxf(st[u][3][0], st[u][3][1]), st[u][3][2]);
            float b0 = fmaxf(fmaxf(a0, a1), a2);
            float b1 = fmaxf(fmaxf(a3, a4), st[u][3][3]);
            float lmax = fmaxf(b0, b1);
            if (!__all(lmax <= FTHR)) {            // rare: rescale path
                float pmax = fmaxf(lmax, __shfl_xor(lmax, 16));
                pmax = fmaxf(pmax, __shfl_xor(pmax, 32));
                float corr = EXP_P(-pmax);
                m_run[u] += pmax;
                #pragma unroll
                for (int j = 0; j < 4; ++j)
                    lacc[u][j] *= corr;
                #pragma unroll
                for (int mt = 0; mt < 4; ++mt)
                    #pragma unroll
                    for (int j = 0; j < 4; ++j) {
                        ot[u][mt][j] *= corr;
                        st[u][mt][j] -= pmax;
                    }
            }
            #pragma unroll
            for (int mt = 0; mt < 4; ++mt)
                #pragma unroll
                for (int j = 0; j < 4; ++j)
                    st[u][mt][j] = EXP_P(st[u][mt][j]);
            #pragma unroll
            for (int t = 0; t < 2; ++t) {
                unsigned w0 = pkrtz(st[u][t][0],     st[u][t][1]);
                unsigned w1 = pkrtz(st[u][t][2],     st[u][t][3]);
                unsigned w2 = pkrtz(st[u][t + 2][0], st[u][t + 2][1]);
                unsigned w3 = pkrtz(st[u][t + 2][2], st[u][t + 2][3]);
                uint4 pw = make_uint4(w0, w1, w2, w3);
                __builtin_memcpy(&pb[u][t], &pw, 16);
            }
            lacc[u] = MFMAH(onesh, pb[u][0], lacc[u], 0, 0, 0);
            lacc[u] = MFMAH(onesh, pb[u][1], lacc[u], 0, 0, 0);
        }

        // ---- O^T += V^T . P^T   (V single fp16, P fp16: 1 MFMA each)
        __builtin_amdgcn_s_setprio(1);
        #pragma unroll
        for (int t = 0; t < 2; ++t) {
            #pragma unroll
            for (int mt = 0; mt < 4; ++mt) {
                const int row = 16 * mt + lq;
                const int swz = (row & 7) << 4;
                const char* vr = L2 + 8192 + row * 128;
                half8 vv = *(const half8*)(vr + ((t * 64 + 16 * lg) ^ swz));
                #pragma unroll
                for (int u = 0; u < 2; ++u)
                    ot[u][mt] = MFMAH(vv, pb[u][t], ot[u][mt], 0, 0, 0);
            }
        }
        __builtin_amdgcn_s_setprio(0);

        __syncthreads();        // drains prefetch vmcnt + protects LDS reuse
        buf ^= 1;
    }

    // ---- epilogue
    if (FUSE) {
        const float gain = 0.25f * (*g0 + *g1 + *g2 + *g3);
        const float ascv = *asc, abiv = *abi;
        const int bb = bh >> 4, hh = bh & 15;
        #pragma unroll
        for (int u = 0; u < 2; ++u) {
            const int m = bb * PS + q0 + 16 * u + lq;
            const unsigned short* mp = modh + (size_t)m * PE + hh * 64 + 4 * lg;
            unsigned short* op = afh + (size_t)m * PE + hh * 64 + 4 * lg;
            const float inv = 1.f / lacc[u][0];
            #pragma unroll
            for (int mt = 0; mt < 4; ++mt) {
                ushort4 mv = *(const ushort4*)(mp + 16 * mt);
                ushort4 ov;
                ov.x = h16((ot[u][mt][0] * inv * ascv + abiv) * (1.f + f16tof(mv.x) * gain));
                ov.y = h16((ot[u][mt][1] * inv * ascv + abiv) * (1.f + f16tof(mv.y) * gain));
                ov.z = h16((ot[u][mt][2] * inv * ascv + abiv) * (1.f + f16tof(mv.z) * gain));
                ov.w = h16((ot[u][mt][3] * inv * ascv + abiv) * (1.f + f16tof(mv.w) * gain));
                *(ushort4*)(op + 16 * mt) = ov;
            }
        }
    } else {
        #pragma unroll
        for (int u = 0; u < 2; ++u) {
            const float inv = 1.f / lacc[u][0];
            float* op = attn + ((size_t)bh * PS + q0 + 16 * u + lq) * PD + 4 * lg;
            #pragma unroll
            for (int mt = 0; mt < 4; ++mt) {
                float4 o;
                o.x = ot[u][mt][0] * inv; o.y = ot[u][mt][1] * inv;
                o.z = ot[u][mt][2] * inv; o.w = ot[u][mt][3] * inv;
                *(float4*)(op + 16 * mt) = o;
            }
        }
    }
}

// ---------------------------------------------------------------------------
extern "C" void kernel_launch(void* const* d_in, const int* in_sizes, int n_in,
                              void* d_out, int out_size, void* d_ws, size_t ws_size,
                              hipStream_t stream)
{
    const float* query = (const float*)d_in[0];
    const float* Wq  = (const float*)d_in[1];  const float* bq  = (const float*)d_in[2];
    const float* Wk  = (const float*)d_in[3];  const float* bk  = (const float*)d_in[4];
    const float* Wv  = (const float*)d_in[5];  const float* bv  = (const float*)d_in[6];
    const float* Wo  = (const float*)d_in[7];  const float* bo  = (const float*)d_in[8];
    const float* Wm1 = (const float*)d_in[9];  const float* bm1 = (const float*)d_in[10];
    const float* Wm2 = (const float*)d_in[11]; const float* bm2 = (const float*)d_in[12];
    const float* dop = (const float*)d_in[13];
    const float* ser = (const float*)d_in[14];
    const float* nor = (const float*)d_in[15];
    const float* ach = (const float*)d_in[16];
    const float* asc = (const float*)d_in[17];
    const float* abi = (const float*)d_in[18];
    float* out = (float*)d_out;

    char* wsb = (char*)d_ws;
    // Common: attn fp32 [0,32M) (fallback), kf [32M,48M), vtf [48M,64M)
    float*          attnb = (float*)wsb;
    unsigned short* kf    = (unsigned short*)(wsb + (32u << 20));
    unsigned short* vtf   = (unsigned short*)(wsb + (48u << 20));

    dim3 blk(256);
    const bool presplit = (ws_size >= 161480704ull);             // 154 MB

    if (presplit) {
        unsigned short* h1h   = (unsigned short*)(wsb + (64u << 20));  // 4MB
        unsigned short* afh   = (unsigned short*)(wsb + (72u << 20));  // 16MB
        unsigned short* qh16  = (unsigned short*)(wsb + (88u << 20));  // 16MB
        unsigned short* qh    = (unsigned short*)(wsb + (104u << 20)); // 16MB
        unsigned short* modh  = (unsigned short*)(wsb + (120u << 20)); // 16MB
        unsigned short* wqh   = (unsigned short*)(wsb + (136u << 20)); // 2MB
        unsigned short* wkh   = (unsigned short*)(wsb + (138u << 20));
        unsigned short* wvh   = (unsigned short*)(wsb + (140u << 20));
        unsigned short* woh   = (unsigned short*)(wsb + (142u << 20));
        unsigned short* m1h   = (unsigned short*)(wsb + (144u << 20)); // 0.5MB
        unsigned short* m2h   = (unsigned short*)(wsb + (145u << 20));

        split_all<<<12800, blk, 0, stream>>>(
            query, Wq, Wk, Wv, Wo, Wm1, Wm2,
            qh, wqh, wkh, wvh, woh, m1h, m2h);

        // Fused Q/K/V projections; Q emitted fp16 pre-scaled
        gemm_qkv<<<dim3(PM / 128, PE / 128), dim3(512), 0, stream>>>(
            qh, wqh, wkh, wvh, bq, bk, bv, qh16, kf, vtf);

        // MLP (independent of attention): h1 then mod plane
        gemm_pl<5, true><<<dim3(PM / 128, 256 / 128), blk, 0, stream>>>(
            qh, m1h, bm1, nullptr, h1h, PM, 256, PE);
        gemm_pl<5, false><<<dim3(PM / 128, PE / 128), blk, 0, stream>>>(
            h1h, m2h, bm2, nullptr, modh, PM, PE, 256);

        // Flash with fused neuromod combine -> fp16 attnf plane
        flash_mfma<1><<<dim3(PS / 128, PH, PB), blk, 0, stream>>>(
            qh16, kf, vtf, modh, dop, ser, nor, ach, asc, abi,
            afh, nullptr);

        // Output projection
        gemm_pl<0, false><<<dim3(PM / 128, PE / 128), blk, 0, stream>>>(
            afh, woh, bo, out, nullptr, PM, PE, PE);
    } else {
        // fallback: fp32-fed bf16 3-term GEMMs + fp16 flash (round-17 flow)
        float* h1    = (float*)(wsb + (64u << 20));   // 8MB
        float* attnf = (float*)(wsb + (72u << 20));   // 32MB
        unsigned short* qh16 = (unsigned short*)(wsb + (72u << 20)); // 16MB

        gemm_nt<1, false><<<dim3(PM / 128, PE / 128), blk, 0, stream>>>(
            query, Wq, bq, nullptr, qh16, PM, PE, PE,
            nullptr, nullptr, nullptr, nullptr, nullptr, nullptr, nullptr);
        gemm_nt<3, false><<<dim3(PM / 128, PE / 128), blk, 0, stream>>>(
            query, Wk, bk, nullptr, kf, PM, PE, PE,
            nullptr, nullptr, nullptr, nullptr, nullptr, nullptr, nullptr);
        gemm_nt<4, false><<<dim3(PM / 128, PE / 128), blk, 0, stream>>>(
            query, Wv, bv, nullptr, vtf, PM, PE, PE,
            nullptr, nullptr, nullptr, nullptr, nullptr, nullptr, nullptr);
        gemm_nt<0, true><<<dim3(PM / 128, 256 / 128), blk, 0, stream>>>(
            query, Wm1, bm1, h1, nullptr, PM, 256, PE,
            nullptr, nullptr, nullptr, nullptr, nullptr, nullptr, nullptr);

        flash_mfma<0><<<dim3(PS / 128, PH, PB), blk, 0, stream>>>(
            qh16, kf, vtf, nullptr, nullptr, nullptr, nullptr, nullptr,
            nullptr, nullptr, nullptr, attnb);

        gemm_nt<2, false><<<dim3(PM / 128, PE / 128), blk, 0, stream>>>(
            h1, Wm2, bm2, attnf, nullptr, PM, PE, 256,
            attnb, dop, ser, nor, ach, asc, abi);
        gemm_nt<0, false><<<dim3(PM / 128, PE / 128), blk, 0, stream>>>(
            attnf, Wo, bo, out, nullptr, PM, PE, PE,
            nullptr, nullptr, nullptr, nullptr, nullptr, nullptr, nullptr);
    }
}